// Round 10
// baseline (119.320 us; speedup 1.0000x reference)
//
#include <hip/hip_runtime.h>
#include <hip/hip_bf16.h>
#include <stdint.h>

typedef __hip_bfloat16 bf16;
typedef __attribute__((ext_vector_type(8))) short short8;
typedef __attribute__((ext_vector_type(4))) short short4v;
typedef __attribute__((ext_vector_type(4))) float f32x4;
typedef __attribute__((ext_vector_type(16))) float f32x16;
typedef __attribute__((ext_vector_type(4))) unsigned uint4v;
typedef __attribute__((ext_vector_type(2))) unsigned uint2v;

#define AS1 __attribute__((address_space(1)))
#define AS3 __attribute__((address_space(3)))

static constexpr int SEQ = 2048, DM = 1024, DHD = 64;
static constexpr int MROWS = 2 * SEQ;  // 4096

__device__ __forceinline__ short f2b(float f) {
  __hip_bfloat16 h = __float2bfloat16(f);
  return *reinterpret_cast<short*>(&h);
}

__device__ __forceinline__ unsigned pack2(float lo, float hi) {
  float2 fv; fv.x = lo; fv.y = hi;
  union { __hip_bfloat162 h; unsigned u; } cv;
  cv.h = __float22bfloat162_rn(fv);
  return cv.u;
}

// raw v_exp_f32 (1-inst exp2) — libm exp2f carries range-check bloat
__device__ __forceinline__ float fexp2(float x) {
#if __has_builtin(__builtin_amdgcn_exp2f)
  return __builtin_amdgcn_exp2f(x);
#else
  return exp2f(x);
#endif
}

union U8 { uint4v u; short8 s; };

// volatile asm 16B global load with literal byte offset — cannot be sunk/reordered
#define GL16(dst, ptr, off) \
  asm volatile("global_load_dwordx4 %0, %1, off offset:" #off : "=v"(dst) : "v"(ptr))
// counted wait + scheduling fence (rule #18)
#define WAITV(n) do { asm volatile("s_waitcnt vmcnt(" #n ")"); __builtin_amdgcn_sched_barrier(0); } while (0)

__device__ __forceinline__ float xmax32(float v) {
#if __has_builtin(__builtin_amdgcn_permlane32_swap)
  uint2v r = __builtin_amdgcn_permlane32_swap(__float_as_uint(v), __float_as_uint(v), false, false);
  return fmaxf(__uint_as_float(r[0]), __uint_as_float(r[1]));
#else
  return fmaxf(v, __shfl_xor(v, 32));
#endif
}
__device__ __forceinline__ float xsum32(float v) {
#if __has_builtin(__builtin_amdgcn_permlane32_swap)
  uint2v r = __builtin_amdgcn_permlane32_swap(__float_as_uint(v), __float_as_uint(v), false, false);
  return __uint_as_float(r[0]) + __uint_as_float(r[1]);
#else
  return v + __shfl_xor(v, 32);
#endif
}

// ---------------- prep: x -> bf16, x+pos -> bf16 ----------------
__global__ __launch_bounds__(256) void prep_inputs(const float* __restrict__ x,
                                                   const float* __restrict__ pos,
                                                   bf16* __restrict__ xb,
                                                   bf16* __restrict__ aib) {
  int i = blockIdx.x * 256 + threadIdx.x;
  const int n4 = MROWS * DM / 4;
  if (i >= n4) return;
  f32x4 xv = ((const f32x4*)x)[i];
  f32x4 pv = ((const f32x4*)pos)[i];
  short4v xo, ao;
#pragma unroll
  for (int j = 0; j < 4; ++j) {
    xo[j] = f2b(xv[j]);
    ao[j] = f2b(xv[j] + pv[j]);
  }
  ((short4v*)xb)[i] = xo;
  ((short4v*)aib)[i] = ao;
}

// ---------------- weight transpose: [R][C] f32 -> [C][R] bf16 (per z-slice) --
__global__ __launch_bounds__(256) void transpose_w(const float* __restrict__ in,
                                                   bf16* __restrict__ out, int R, int C) {
  __shared__ float t[64][65];
  int ct = blockIdx.x, rt = blockIdx.y, z = blockIdx.z;
  in += (size_t)z * R * C;
  out += (size_t)z * R * C;
  int c = threadIdx.x & 63, g = threadIdx.x >> 6;
#pragma unroll
  for (int j = 0; j < 16; ++j) {
    int r = g * 16 + j;
    t[r][c] = in[(size_t)(rt * 64 + r) * C + (ct * 64 + c)];
  }
  __syncthreads();
#pragma unroll
  for (int j = 0; j < 16; ++j) {
    int rr = g * 16 + j;
    out[(size_t)(ct * 64 + rr) * R + (rt * 64 + c)] = __float2bfloat16(t[c][rr]);
  }
}

// ---------------- 128x128 GEMM body, BK=64 (A[M][1024], Bt[N][1024] bf16) ---
// 16 K-iterations with 32 MFMA per barrier pair (vs 32 iters x 16 MFMA at
// BK=32) — halves the vmcnt(0)+barrier drain events that dominate.
// MODE 1: f32 row-major out. MODE 3: bf16 fragment-major FQ/FK. MODE 4: FV.
template <int MODE, typename OutT>
__device__ __forceinline__ void gemm128_body(const bf16* __restrict__ A,
                                             const bf16* __restrict__ Bt,
                                             const float* __restrict__ bias,
                                             OutT* __restrict__ C, int mt, int nt,
                                             float scale) {
  __shared__ alignas(16) bf16 Al[128 * 64];
  __shared__ alignas(16) bf16 Bl[128 * 64];
  const int lane = threadIdx.x & 63, wv = threadIdx.x >> 6;
  const int wr = wv >> 1, wc = wv & 1;
  const bf16* Ab = A + (size_t)mt * 128 * DM;
  const bf16* Bb = Bt + (size_t)nt * 128 * DM;

  f32x4 acc[4][4];
#pragma unroll
  for (int i = 0; i < 4; ++i)
#pragma unroll
    for (int j = 0; j < 4; ++j) acc[i][j] = (f32x4){0.f, 0.f, 0.f, 0.f};

  for (int kt = 0; kt < DM / 64; ++kt) {
    int k0 = kt * 64;
    // stage A tile 128x64 (16KB): 4 passes x 256 lanes x 16B
#pragma unroll
    for (int c = 0; c < 4; ++c) {
      int li0 = wv * 64 + c * 256;
      int li = li0 + lane;
      int row = li >> 3, sl = li & 7;
      int gs = sl ^ (row & 7);
      __builtin_amdgcn_global_load_lds((const AS1 void*)(Ab + (size_t)row * DM + k0 + gs * 8),
                                       (AS3 void*)(&Al[li0 * 8]), 16, 0, 0);
    }
#pragma unroll
    for (int c = 0; c < 4; ++c) {
      int li0 = wv * 64 + c * 256;
      int li = li0 + lane;
      int row = li >> 3, sl = li & 7;
      int gs = sl ^ (row & 7);
      __builtin_amdgcn_global_load_lds((const AS1 void*)(Bb + (size_t)row * DM + k0 + gs * 8),
                                       (AS3 void*)(&Bl[li0 * 8]), 16, 0, 0);
    }
    __syncthreads();

    short8 af[2][4], bfr[2][4];
    const int kb = lane >> 4;
#pragma unroll
    for (int kk = 0; kk < 2; ++kk) {
#pragma unroll
      for (int mi = 0; mi < 4; ++mi) {
        int r = wr * 64 + mi * 16 + (lane & 15);
        af[kk][mi] = *(const short8*)(&Al[r * 64 + (((kb + 4 * kk) ^ (r & 7)) << 3)]);
      }
#pragma unroll
      for (int ni = 0; ni < 4; ++ni) {
        int r = wc * 64 + ni * 16 + (lane & 15);
        bfr[kk][ni] = *(const short8*)(&Bl[r * 64 + (((kb + 4 * kk) ^ (r & 7)) << 3)]);
      }
    }
#pragma unroll
    for (int kk = 0; kk < 2; ++kk)
#pragma unroll
      for (int mi = 0; mi < 4; ++mi)
#pragma unroll
        for (int ni = 0; ni < 4; ++ni)
          acc[mi][ni] = __builtin_amdgcn_mfma_f32_16x16x32_bf16(af[kk][mi], bfr[kk][ni], acc[mi][ni], 0, 0, 0);
    __syncthreads();
  }

#pragma unroll
  for (int mi = 0; mi < 4; ++mi) {
#pragma unroll
    for (int ni = 0; ni < 4; ++ni) {
      int row0 = mt * 128 + wr * 64 + mi * 16 + (lane >> 4) * 4;
      int col = nt * 128 + wc * 64 + ni * 16 + (lane & 15);
      float bv = bias[col];
      if constexpr (MODE == 1) {
#pragma unroll
        for (int j = 0; j < 4; ++j)
          C[(size_t)(row0 + j) * DM + col] = (acc[mi][ni][j] + bv) * scale;
      } else {
        int bb = row0 >> 11, s0 = row0 & 2047;
        int hh = col >> 6, d0 = col & 63;
        size_t bhb = (size_t)(bb * 16 + hh) * 131072;
        if constexpr (MODE == 3) {
          // FQ/FK[bh][g][kc]: slot (r32+32*hi)*8 + e, from row s, col d0
          int kc = d0 >> 4, hi = (d0 >> 3) & 1, e = d0 & 7;
          int g = s0 >> 5, r0 = s0 & 31;
          size_t bbase = bhb + g * 2048 + kc * 512 + e;
#pragma unroll
          for (int j = 0; j < 4; ++j)
            ((bf16*)C)[bbase + (size_t)(r0 + j + 32 * hi) * 8] =
                __float2bfloat16((acc[mi][ni][j] + bv) * scale);
        } else {  // MODE 4
          // FV[bh][dj][ks]: slot (d32+32*((s>>3)&1))*8 + (s&7), d on slot axis
          int dj = d0 >> 5, d32 = d0 & 31;
          int ks = s0 >> 4, hi2 = (s0 >> 3) & 1, e0 = s0 & 7;
          short4v o;
#pragma unroll
          for (int j = 0; j < 4; ++j) o[j] = f2b(acc[mi][ni][j] + bv);
          *(short4v*)((bf16*)C + bhb + dj * 65536 + ks * 512 + (size_t)(d32 + 32 * hi2) * 8 + e0) = o;
        }
      }
    }
  }
}

// Q prescale: (1/sqrt(64)) * log2(e) so attention uses exp2
static constexpr float QSCALE = 0.125f * 1.4426950408889634f;

__global__ __launch_bounds__(256) void qkv_gemm(const bf16* __restrict__ aib,
                                                const bf16* __restrict__ xb,
                                                const bf16* __restrict__ wqt,
                                                const bf16* __restrict__ wkt,
                                                const bf16* __restrict__ wvt,
                                                const float* __restrict__ bq,
                                                const float* __restrict__ bk,
                                                const float* __restrict__ bv,
                                                bf16* __restrict__ FQ, bf16* __restrict__ FK,
                                                bf16* __restrict__ FV) {
  int mt = blockIdx.x & 31;
  int nt = (blockIdx.x >> 5) & 7;
  int mat = blockIdx.x >> 8;
  if (mat == 0) {
    gemm128_body<3>(aib, wqt, bq, FQ, mt, nt, QSCALE);
  } else if (mat == 1) {
    gemm128_body<3>(aib, wkt, bk, FK, mt, nt, 1.0f);
  } else {
    gemm128_body<4>(xb, wvt, bv, FV, mt, nt, 1.0f);
  }
}

// ---------------- o_gemm: 64x128 tiles -> 512 blocks (2 blocks/CU) ----------
__global__ __launch_bounds__(256) void o_gemm64(const bf16* __restrict__ A,
                                                const bf16* __restrict__ Bt,
                                                const float* __restrict__ bias,
                                                float* __restrict__ out) {
  __shared__ alignas(16) bf16 Al[64 * 32];
  __shared__ alignas(16) bf16 Bl[128 * 32];
  const int mt = blockIdx.x & 63, nt = blockIdx.x >> 6;
  const int lane = threadIdx.x & 63, wv = threadIdx.x >> 6;
  const int wr = wv >> 1, wc = wv & 1;  // wave: 32 rows x 64 cols quadrant
  const bf16* Ab = A + (size_t)mt * 64 * DM;
  const bf16* Bb = Bt + (size_t)nt * 128 * DM;

  f32x4 acc[2][4];
#pragma unroll
  for (int i = 0; i < 2; ++i)
#pragma unroll
    for (int j = 0; j < 4; ++j) acc[i][j] = (f32x4){0.f, 0.f, 0.f, 0.f};

  for (int kt = 0; kt < DM / 32; ++kt) {
    int k0 = kt * 32;
    {  // A: 64x32 = 4KB, one chunk
      int li0 = wv * 64;
      int li = li0 + lane;
      int row = li >> 2, sl = li & 3;
      int gs = sl ^ ((row >> 1) & 3);
      __builtin_amdgcn_global_load_lds((const AS1 void*)(Ab + (size_t)row * DM + k0 + gs * 8),
                                       (AS3 void*)(&Al[li0 * 8]), 16, 0, 0);
    }
#pragma unroll
    for (int c = 0; c < 2; ++c) {  // B: 128x32 = 8KB, two chunks
      int li0 = wv * 64 + c * 256;
      int li = li0 + lane;
      int row = li >> 2, sl = li & 3;
      int gs = sl ^ ((row >> 1) & 3);
      __builtin_amdgcn_global_load_lds((const AS1 void*)(Bb + (size_t)row * DM + k0 + gs * 8),
                                       (AS3 void*)(&Bl[li0 * 8]), 16, 0, 0);
    }
    __syncthreads();

    short8 af[2], bfr[4];
    const int kb = lane >> 4;
#pragma unroll
    for (int mi = 0; mi < 2; ++mi) {
      int r = wr * 32 + mi * 16 + (lane & 15);
      af[mi] = *(const short8*)(&Al[r * 32 + ((kb ^ ((r >> 1) & 3)) << 3)]);
    }
#pragma unroll
    for (int ni = 0; ni < 4; ++ni) {
      int r = wc * 64 + ni * 16 + (lane & 15);
      bfr[ni] = *(const short8*)(&Bl[r * 32 + ((kb ^ ((r >> 1) & 3)) << 3)]);
    }
#pragma unroll
    for (int mi = 0; mi < 2; ++mi)
#pragma unroll
      for (int ni = 0; ni < 4; ++ni)
        acc[mi][ni] = __builtin_amdgcn_mfma_f32_16x16x32_bf16(af[mi], bfr[ni], acc[mi][ni], 0, 0, 0);
    __syncthreads();
  }

#pragma unroll
  for (int mi = 0; mi < 2; ++mi) {
#pragma unroll
    for (int ni = 0; ni < 4; ++ni) {
      int row0 = mt * 64 + wr * 32 + mi * 16 + (lane >> 4) * 4;
      int col = nt * 128 + wc * 64 + ni * 16 + (lane & 15);
      float bv = bias[col];
#pragma unroll
      for (int j = 0; j < 4; ++j)
        out[(size_t)(row0 + j) * DM + col] = acc[mi][ni][j] + bv;
    }
  }
}

// ---------------- flash attention: split-KV x2, swapped-QK^T ----------------
// 128-thread block = 2 waves on one (bh, q-tile); wave0 tiles [0,hsp), wave1
// [hsp,nt); exact merge via LDS. Fragment-major operands -> coalesced 1KB
// loads with counted-vmcnt pipelining. THR=8 defer-max. T5 setprio on MFMA.
__global__ __launch_bounds__(128, 2) void flash_attn(const bf16* __restrict__ FQ,
                                                     const bf16* __restrict__ FK,
                                                     const bf16* __restrict__ FV,
                                                     bf16* __restrict__ Zb) {
  __shared__ float Zm[64][33];   // wave1 partial Z^T (padded)
  __shared__ float Ml[64], Ll[64];
  __shared__ unsigned Zl[32 * 32];  // wave0 final ZT->Z transpose

  const int lane = threadIdx.x & 63;
  const int wvi = threadIdx.x >> 6;
  const int qln = lane & 31;
  const bool hib = lane >= 32;
  const int bh = blockIdx.x & 31;           // bh%8 -> XCD affinity
  const int wq = 63 - (blockIdx.x >> 5);    // heavy blocks dispatch first
  const int bb = bh >> 4, h = bh & 15;
  const int q0 = wq * 32;
  const int nt = wq / 2 + 1;
  const int hsp = (nt + 1) >> 1;
  const int t0 = wvi ? hsp : 0;
  const int t1 = wvi ? nt : hsp;

  const size_t fb = (size_t)bh * 131072;
  const bf16* qp = FQ + fb + wq * 2048 + lane * 8;
  const bf16* kpt = FK + fb + (size_t)t0 * 4096 + lane * 8;
  const bf16* vp0 = FV + fb + (size_t)t0 * 2048 + lane * 8;
  const bf16* vp1 = vp0 + 65536;

  f32x16 zacc[2];
#pragma unroll
  for (int i = 0; i < 16; ++i) { zacc[0][i] = 0.f; zacc[1][i] = 0.f; }
  float mrun = -1e30f, lrun = 0.f;

  short8 qf[4];
  short8 kfA[2][4], kfB[2][4];

  if (t0 < t1) {
    // prologue: Q (4 loads) then K(t0) (8 coalesced loads)
    GL16(qf[0], qp, 0); GL16(qf[1], qp, 1024); GL16(qf[2], qp, 2048); GL16(qf[3], qp, 3072);
    {
      const bf16* k1 = kpt + 2048;
      GL16(kfA[0][0], kpt, 0); GL16(kfA[0][1], kpt, 1024); GL16(kfA[0][2], kpt, 2048); GL16(kfA[0][3], kpt, 3072);
      GL16(kfA[1][0], k1, 0);  GL16(kfA[1][1], k1, 1024);  GL16(kfA[1][2], k1, 2048);  GL16(kfA[1][3], k1, 3072);
      kpt += 4096;
    }

    auto computeT = [&](short8(&kf)[2][4], short8(&kfn)[2][4], int t) {
      const int kv0 = t * 64;
      const bool pref = (t + 1 < t1);

      // issue V(t) — consumed at PV below
      short8 vf[2][4];
      GL16(vf[0][0], vp0, 0); GL16(vf[0][1], vp0, 1024); GL16(vf[0][2], vp0, 2048); GL16(vf[0][3], vp0, 3072);
      GL16(vf[1][0], vp1, 0); GL16(vf[1][1], vp1, 1024); GL16(vf[1][2], vp1, 2048); GL16(vf[1][3], vp1, 3072);
      vp0 += 2048; vp1 += 2048;

      WAITV(8);  // K(t) (and Q on first tile) complete; V(t) stays in flight

      f32x16 s[2];
#pragma unroll
      for (int i = 0; i < 16; ++i) { s[0][i] = 0.f; s[1][i] = 0.f; }
      __builtin_amdgcn_s_setprio(1);
#pragma unroll
      for (int kc = 0; kc < 4; ++kc) {
        s[0] = __builtin_amdgcn_mfma_f32_32x32x16_bf16(kf[0][kc], qf[kc], s[0], 0, 0, 0);
        s[1] = __builtin_amdgcn_mfma_f32_32x32x16_bf16(kf[1][kc], qf[kc], s[1], 0, 0, 0);
      }
      __builtin_amdgcn_s_setprio(0);

      if (pref) {  // issue K(t+1)
        const bf16* k1 = kpt + 2048;
        GL16(kfn[0][0], kpt, 0); GL16(kfn[0][1], kpt, 1024); GL16(kfn[0][2], kpt, 2048); GL16(kfn[0][3], kpt, 3072);
        GL16(kfn[1][0], k1, 0);  GL16(kfn[1][1], k1, 1024);  GL16(kfn[1][2], k1, 2048);  GL16(kfn[1][3], k1, 3072);
        kpt += 4096;
      }

      if (t == nt - 1) {  // causal mask, diagonal tile only
        const int qg = q0 + qln;
#pragma unroll
        for (int ni = 0; ni < 2; ++ni)
#pragma unroll
          for (int rr = 0; rr < 16; ++rr) {
            int kv = kv0 + 32 * ni + (rr & 3) + 8 * (rr >> 2) + (hib ? 4 : 0);
            if (kv > qg) s[ni][rr] = -1e30f;
          }
      }

      // row max: in-register tree + cross-half swap
      float t8[8];
#pragma unroll
      for (int i = 0; i < 8; ++i)
        t8[i] = fmaxf(fmaxf(s[0][i], s[0][i + 8]), fmaxf(s[1][i], s[1][i + 8]));
      float tm = fmaxf(fmaxf(fmaxf(t8[0], t8[1]), fmaxf(t8[2], t8[3])),
                       fmaxf(fmaxf(t8[4], t8[5]), fmaxf(t8[6], t8[7])));
      tm = xmax32(tm);

      // defer-max (T13): rescale only when max grew by >8; P bounded by 2^8,
      // math stays exact (mrun is just the reference point).
      if (__ballot(tm > mrun + 8.0f)) {
        float mn = fmaxf(mrun, tm);
        float al = fexp2(mrun - mn);
        mrun = mn;
        lrun *= al;
#pragma unroll
        for (int i = 0; i < 16; ++i) { zacc[0][i] *= al; zacc[1][i] *= al; }
      }

      float pacc[4] = {0.f, 0.f, 0.f, 0.f};
#pragma unroll
      for (int ni = 0; ni < 2; ++ni)
#pragma unroll
        for (int rr = 0; rr < 16; ++rr) {
          float p = fexp2(s[ni][rr] - mrun);
          s[ni][rr] = p;
          pacc[rr & 3] += p;
        }
      lrun += xsum32((pacc[0] + pacc[1]) + (pacc[2] + pacc[3]));

      // P -> bf16 B-fragments: pack pairs, permlane32_swap fills both halves
      unsigned su32[2][8];
#pragma unroll
      for (int ni = 0; ni < 2; ++ni)
#pragma unroll
        for (int tt = 0; tt < 8; ++tt)
          su32[ni][tt] = pack2(s[ni][2 * tt], s[ni][2 * tt + 1]);

      short8 pa[4];
#if __has_builtin(__builtin_amdgcn_permlane32_swap)
#pragma unroll
      for (int c = 0; c < 4; ++c) {
        int ni = c >> 1, b4 = 4 * (c & 1);
        uint2v r0 = __builtin_amdgcn_permlane32_swap(su32[ni][b4 + 0], su32[ni][b4 + 2], false, false);
        uint2v r1 = __builtin_amdgcn_permlane32_swap(su32[ni][b4 + 1], su32[ni][b4 + 3], false, false);
        U8 w;
        w.u[0] = r0[0]; w.u[1] = r1[0]; w.u[2] = r0[1]; w.u[3] = r1[1];
        pa[c] = w.s;
      }
#else
      unsigned X[2][8];
#pragma unroll
      for (int ni = 0; ni < 2; ++ni)
#pragma unroll
        for (int tt = 0; tt < 8; ++tt)
          X[ni][tt] = (unsigned)__shfl_xor((int)su32[ni][tt], 32);
#pragma unroll
      for (int c = 0; c < 4; ++c) {
        int ni = c >> 1, b4 = 4 * (c & 1);
        U8 w;
        w.u[0] = hib ? X[ni][b4 + 2] : su32[ni][b4 + 0];
        w.u[1] = hib ? X[ni][b4 + 3] : su32[ni][b4 + 1];
        w.u[2] = hib ? su32[ni][b4 + 2] : X[ni][b4 + 0];
        w.u[3] = hib ? su32[ni][b4 + 3] : X[ni][b4 + 1];
        pa[c] = w.s;
      }
#endif

      if (pref) { WAITV(8); } else { WAITV(0); }  // V(t) done; K(t+1) in flight

      __builtin_amdgcn_s_setprio(1);
#pragma unroll
      for (int c = 0; c < 4; ++c) {
        zacc[0] = __builtin_amdgcn_mfma_f32_32x32x16_bf16(vf[0][c], pa[c], zacc[0], 0, 0, 0);
        zacc[1] = __builtin_amdgcn_mfma_f32_32x32x16_bf16(vf[1][c], pa[c], zacc[1], 0, 0, 0);
      }
      __builtin_amdgcn_s_setprio(0);
    };

    int t = t0;
    while (true) {
      computeT(kfA, kfB, t);
      if (++t >= t1) break;
      computeT(kfB, kfA, t);
      if (++t >= t1) break;
    }
  }

  // ---- merge wave1 into wave0 (exact online-softmax combine) ----
  if (wvi == 1) {
#pragma unroll
    for (int i = 0; i < 16; ++i) {
      Zm[lane][i] = zacc[0][i];
      Zm[lane][16 + i] = zacc[1][i];
    }
    Ml[lane] = mrun;
    Ll[lane] = lrun;
  }
  __syncthreads();
  if (wvi == 0) {
    float m1 = Ml[lane], l1 = Ll[lane];
    float mn = fmaxf(mrun, m1);
    float a0 = fexp2(mrun - mn);
    float a1 = fexp2(m1 - mn);
    float lm = lrun * a0 + l1 * a1;
#pragma unroll
    for (int i = 0; i < 16; ++i) {
      zacc[0][i] = zacc[0][i] * a0 + Zm[lane][i] * a1;
      zacc[1][i] = zacc[1][i] * a0 + Zm[lane][16 + i] * a1;
    }

    // normalize + transpose Z^T -> Z via swizzled LDS, coalesced store
    const float rl = 1.0f / lm;
    const int W8[8] = {0, 1, 4, 5, 8, 9, 12, 13};
#pragma unroll
    for (int dj = 0; dj < 2; ++dj)
#pragma unroll
      for (int tt = 0; tt < 8; ++tt) {
        unsigned v = pack2(zacc[dj][2 * tt] * rl, zacc[dj][2 * tt + 1] * rl);
        int x = 16 * dj + (hib ? 2 : 0) + W8[tt];
        Zl[qln * 32 + (((x >> 2) ^ (qln & 7)) << 2) + (x & 3)] = v;
      }
    asm volatile("s_waitcnt lgkmcnt(0)" ::: "memory");
    __builtin_amdgcn_sched_barrier(0);
    const size_t base = ((size_t)bb * SEQ) * DM + h * DHD;
    int q2 = lane >> 1, hf = lane & 1;
#pragma unroll
    for (int u = 0; u < 4; ++u) {
      int sl = (hf * 4 + u) ^ (q2 & 7);
      U8 w;
      w.u = *(const uint4v*)&Zl[q2 * 32 + sl * 4];
      *(short8*)(Zb + base + (size_t)(q0 + q2) * DM + hf * 32 + u * 8) = w.s;
    }
  }
}

extern "C" void kernel_launch(void* const* d_in, const int* in_sizes, int n_in,
                              void* d_out, int out_size, void* d_ws, size_t ws_size,
                              hipStream_t stream) {
  (void)in_sizes; (void)n_in; (void)out_size; (void)ws_size;
  const float* x = (const float*)d_in[0];
  const float* pos = (const float*)d_in[1];
  const float* WQ = (const float*)d_in[2];
  const float* bQ = (const float*)d_in[3];
  const float* WK = (const float*)d_in[4];
  const float* bK = (const float*)d_in[5];
  const float* WV = (const float*)d_in[6];
  const float* bV = (const float*)d_in[7];
  const float* WO = (const float*)d_in[8];
  const float* bO = (const float*)d_in[9];
  float* out = (float*)d_out;

  bf16* ws = (bf16*)d_ws;
  size_t off = 0;
  bf16* aib = ws + off; off += (size_t)MROWS * DM;
  bf16* xb  = ws + off; off += (size_t)MROWS * DM;
  bf16* wqt = ws + off; off += (size_t)DM * DM;
  bf16* wkt = ws + off; off += (size_t)DM * DM;
  bf16* wvt = ws + off; off += (size_t)DM * DM;
  bf16* wot = ws + off; off += (size_t)DM * DM;
  bf16* FQ  = ws + off; off += (size_t)MROWS * DM;  // fragment-major [bh][g][kc]
  bf16* FK  = ws + off; off += (size_t)MROWS * DM;
  bf16* FV  = ws + off; off += (size_t)MROWS * DM;  // fragment-major [bh][dj][ks]
  bf16* Zb  = ws + off; off += (size_t)MROWS * DM;

  prep_inputs<<<(MROWS * DM / 4 + 255) / 256, 256, 0, stream>>>(x, pos, xb, aib);
  dim3 gq(1, 16, 16);
  transpose_w<<<gq, 256, 0, stream>>>(WQ, wqt, 1024, 64);
  transpose_w<<<gq, 256, 0, stream>>>(WK, wkt, 1024, 64);
  transpose_w<<<gq, 256, 0, stream>>>(WV, wvt, 1024, 64);
  dim3 go(16, 16, 1);
  transpose_w<<<go, 256, 0, stream>>>(WO, wot, 1024, 1024);
  qkv_gemm<<<768, 256, 0, stream>>>(aib, xb, wqt, wkt, wvt, bQ, bK, bV, FQ, FK, FV);
  flash_attn<<<2048, 128, 0, stream>>>(FQ, FK, FV, Zb);
  o_gemm64<<<512, 256, 0, stream>>>(Zb, wot, bO, out);
}

// Round 11
// 116.483 us; speedup vs baseline: 1.0244x; 1.0244x over previous
//
#include <hip/hip_runtime.h>
#include <hip/hip_bf16.h>
#include <stdint.h>

typedef __hip_bfloat16 bf16;
typedef __attribute__((ext_vector_type(8))) short short8;
typedef __attribute__((ext_vector_type(4))) short short4v;
typedef __attribute__((ext_vector_type(4))) float f32x4;
typedef __attribute__((ext_vector_type(16))) float f32x16;
typedef __attribute__((ext_vector_type(4))) unsigned uint4v;
typedef __attribute__((ext_vector_type(2))) unsigned uint2v;

#define AS1 __attribute__((address_space(1)))
#define AS3 __attribute__((address_space(3)))

static constexpr int SEQ = 2048, DM = 1024, DHD = 64;
static constexpr int MROWS = 2 * SEQ;  // 4096

__device__ __forceinline__ short f2b(float f) {
  __hip_bfloat16 h = __float2bfloat16(f);
  return *reinterpret_cast<short*>(&h);
}

__device__ __forceinline__ unsigned pack2(float lo, float hi) {
  float2 fv; fv.x = lo; fv.y = hi;
  union { __hip_bfloat162 h; unsigned u; } cv;
  cv.h = __float22bfloat162_rn(fv);
  return cv.u;
}

// raw v_exp_f32 (1-inst exp2) — libm exp2f carries range-check bloat
__device__ __forceinline__ float fexp2(float x) {
#if __has_builtin(__builtin_amdgcn_exp2f)
  return __builtin_amdgcn_exp2f(x);
#else
  return exp2f(x);
#endif
}

union U8 { uint4v u; short8 s; };

// volatile asm 16B global load with literal byte offset — cannot be sunk/reordered
#define GL16(dst, ptr, off) \
  asm volatile("global_load_dwordx4 %0, %1, off offset:" #off : "=v"(dst) : "v"(ptr))
// counted wait + scheduling fence (rule #18)
#define WAITV(n) do { asm volatile("s_waitcnt vmcnt(" #n ")"); __builtin_amdgcn_sched_barrier(0); } while (0)

__device__ __forceinline__ float xmax32(float v) {
#if __has_builtin(__builtin_amdgcn_permlane32_swap)
  uint2v r = __builtin_amdgcn_permlane32_swap(__float_as_uint(v), __float_as_uint(v), false, false);
  return fmaxf(__uint_as_float(r[0]), __uint_as_float(r[1]));
#else
  return fmaxf(v, __shfl_xor(v, 32));
#endif
}
__device__ __forceinline__ float xsum32(float v) {
#if __has_builtin(__builtin_amdgcn_permlane32_swap)
  uint2v r = __builtin_amdgcn_permlane32_swap(__float_as_uint(v), __float_as_uint(v), false, false);
  return __uint_as_float(r[0]) + __uint_as_float(r[1]);
#else
  return v + __shfl_xor(v, 32);
#endif
}

// ---------------- prep: x -> bf16, x+pos -> bf16 ----------------
__global__ __launch_bounds__(256) void prep_inputs(const float* __restrict__ x,
                                                   const float* __restrict__ pos,
                                                   bf16* __restrict__ xb,
                                                   bf16* __restrict__ aib) {
  int i = blockIdx.x * 256 + threadIdx.x;
  const int n4 = MROWS * DM / 4;
  if (i >= n4) return;
  f32x4 xv = ((const f32x4*)x)[i];
  f32x4 pv = ((const f32x4*)pos)[i];
  short4v xo, ao;
#pragma unroll
  for (int j = 0; j < 4; ++j) {
    xo[j] = f2b(xv[j]);
    ao[j] = f2b(xv[j] + pv[j]);
  }
  ((short4v*)xb)[i] = xo;
  ((short4v*)aib)[i] = ao;
}

// ---------------- weight transpose: [R][C] f32 -> [C][R] bf16 (per z-slice) --
__global__ __launch_bounds__(256) void transpose_w(const float* __restrict__ in,
                                                   bf16* __restrict__ out, int R, int C) {
  __shared__ float t[64][65];
  int ct = blockIdx.x, rt = blockIdx.y, z = blockIdx.z;
  in += (size_t)z * R * C;
  out += (size_t)z * R * C;
  int c = threadIdx.x & 63, g = threadIdx.x >> 6;
#pragma unroll
  for (int j = 0; j < 16; ++j) {
    int r = g * 16 + j;
    t[r][c] = in[(size_t)(rt * 64 + r) * C + (ct * 64 + c)];
  }
  __syncthreads();
#pragma unroll
  for (int j = 0; j < 16; ++j) {
    int rr = g * 16 + j;
    out[(size_t)(ct * 64 + rr) * R + (rt * 64 + c)] = __float2bfloat16(t[c][rr]);
  }
}

// ---------------- 128x128 GEMM body, BK=32 (round-9 proven config) ----------
// BK=64 regressed (m132 mechanism: 64KB LDS halves blocks/CU).
// MODE 1: f32 row-major out. MODE 3: bf16 fragment-major FQ/FK. MODE 4: FV.
template <int MODE, typename OutT>
__device__ __forceinline__ void gemm128_body(const bf16* __restrict__ A,
                                             const bf16* __restrict__ Bt,
                                             const float* __restrict__ bias,
                                             OutT* __restrict__ C, int mt, int nt,
                                             float scale) {
  __shared__ alignas(16) bf16 Al[128 * 32];
  __shared__ alignas(16) bf16 Bl[128 * 32];
  const int lane = threadIdx.x & 63, wv = threadIdx.x >> 6;
  const int wr = wv >> 1, wc = wv & 1;
  const bf16* Ab = A + (size_t)mt * 128 * DM;
  const bf16* Bb = Bt + (size_t)nt * 128 * DM;

  f32x4 acc[4][4];
#pragma unroll
  for (int i = 0; i < 4; ++i)
#pragma unroll
    for (int j = 0; j < 4; ++j) acc[i][j] = (f32x4){0.f, 0.f, 0.f, 0.f};

  for (int kt = 0; kt < DM / 32; ++kt) {
    int k0 = kt * 32;
#pragma unroll
    for (int c = 0; c < 2; ++c) {
      int li0 = wv * 64 + c * 256;
      int li = li0 + lane;
      int row = li >> 2, sl = li & 3;
      int gs = sl ^ ((row >> 1) & 3);
      __builtin_amdgcn_global_load_lds((const AS1 void*)(Ab + (size_t)row * DM + k0 + gs * 8),
                                       (AS3 void*)(&Al[li0 * 8]), 16, 0, 0);
    }
#pragma unroll
    for (int c = 0; c < 2; ++c) {
      int li0 = wv * 64 + c * 256;
      int li = li0 + lane;
      int row = li >> 2, sl = li & 3;
      int gs = sl ^ ((row >> 1) & 3);
      __builtin_amdgcn_global_load_lds((const AS1 void*)(Bb + (size_t)row * DM + k0 + gs * 8),
                                       (AS3 void*)(&Bl[li0 * 8]), 16, 0, 0);
    }
    __syncthreads();

    short8 af[4], bfr[4];
    const int kb = lane >> 4;
#pragma unroll
    for (int mi = 0; mi < 4; ++mi) {
      int r = wr * 64 + mi * 16 + (lane & 15);
      af[mi] = *(const short8*)(&Al[r * 32 + ((kb ^ ((r >> 1) & 3)) << 3)]);
    }
#pragma unroll
    for (int ni = 0; ni < 4; ++ni) {
      int r = wc * 64 + ni * 16 + (lane & 15);
      bfr[ni] = *(const short8*)(&Bl[r * 32 + ((kb ^ ((r >> 1) & 3)) << 3)]);
    }
#pragma unroll
    for (int mi = 0; mi < 4; ++mi)
#pragma unroll
      for (int ni = 0; ni < 4; ++ni)
        acc[mi][ni] = __builtin_amdgcn_mfma_f32_16x16x32_bf16(af[mi], bfr[ni], acc[mi][ni], 0, 0, 0);
    __syncthreads();
  }

#pragma unroll
  for (int mi = 0; mi < 4; ++mi) {
#pragma unroll
    for (int ni = 0; ni < 4; ++ni) {
      int row0 = mt * 128 + wr * 64 + mi * 16 + (lane >> 4) * 4;
      int col = nt * 128 + wc * 64 + ni * 16 + (lane & 15);
      float bv = bias[col];
      if constexpr (MODE == 1) {
#pragma unroll
        for (int j = 0; j < 4; ++j)
          C[(size_t)(row0 + j) * DM + col] = (acc[mi][ni][j] + bv) * scale;
      } else {
        int bb = row0 >> 11, s0 = row0 & 2047;
        int hh = col >> 6, d0 = col & 63;
        size_t bhb = (size_t)(bb * 16 + hh) * 131072;
        if constexpr (MODE == 3) {
          // FQ/FK[bh][g][kc]: slot (r32+32*hi)*8 + e, from row s, col d0
          int kc = d0 >> 4, hi = (d0 >> 3) & 1, e = d0 & 7;
          int g = s0 >> 5, r0 = s0 & 31;
          size_t bbase = bhb + g * 2048 + kc * 512 + e;
#pragma unroll
          for (int j = 0; j < 4; ++j)
            ((bf16*)C)[bbase + (size_t)(r0 + j + 32 * hi) * 8] =
                __float2bfloat16((acc[mi][ni][j] + bv) * scale);
        } else {  // MODE 4
          // FV[bh][dj][ks]: slot (d32+32*((s>>3)&1))*8 + (s&7), d on slot axis
          int dj = d0 >> 5, d32 = d0 & 31;
          int ks = s0 >> 4, hi2 = (s0 >> 3) & 1, e0 = s0 & 7;
          short4v o;
#pragma unroll
          for (int j = 0; j < 4; ++j) o[j] = f2b(acc[mi][ni][j] + bv);
          *(short4v*)((bf16*)C + bhb + dj * 65536 + ks * 512 + (size_t)(d32 + 32 * hi2) * 8 + e0) = o;
        }
      }
    }
  }
}

// Q prescale: (1/sqrt(64)) * log2(e) so attention uses exp2
static constexpr float QSCALE = 0.125f * 1.4426950408889634f;

__global__ __launch_bounds__(256) void qkv_gemm(const bf16* __restrict__ aib,
                                                const bf16* __restrict__ xb,
                                                const bf16* __restrict__ wqt,
                                                const bf16* __restrict__ wkt,
                                                const bf16* __restrict__ wvt,
                                                const float* __restrict__ bq,
                                                const float* __restrict__ bk,
                                                const float* __restrict__ bv,
                                                bf16* __restrict__ FQ, bf16* __restrict__ FK,
                                                bf16* __restrict__ FV) {
  int mt = blockIdx.x & 31;
  int nt = (blockIdx.x >> 5) & 7;
  int mat = blockIdx.x >> 8;
  if (mat == 0) {
    gemm128_body<3>(aib, wqt, bq, FQ, mt, nt, QSCALE);
  } else if (mat == 1) {
    gemm128_body<3>(aib, wkt, bk, FK, mt, nt, 1.0f);
  } else {
    gemm128_body<4>(xb, wvt, bv, FV, mt, nt, 1.0f);
  }
}

// ---------------- o_gemm: 64x128 tiles -> 512 blocks (2 blocks/CU) ----------
__global__ __launch_bounds__(256) void o_gemm64(const bf16* __restrict__ A,
                                                const bf16* __restrict__ Bt,
                                                const float* __restrict__ bias,
                                                float* __restrict__ out) {
  __shared__ alignas(16) bf16 Al[64 * 32];
  __shared__ alignas(16) bf16 Bl[128 * 32];
  const int mt = blockIdx.x & 63, nt = blockIdx.x >> 6;
  const int lane = threadIdx.x & 63, wv = threadIdx.x >> 6;
  const int wr = wv >> 1, wc = wv & 1;  // wave: 32 rows x 64 cols quadrant
  const bf16* Ab = A + (size_t)mt * 64 * DM;
  const bf16* Bb = Bt + (size_t)nt * 128 * DM;

  f32x4 acc[2][4];
#pragma unroll
  for (int i = 0; i < 2; ++i)
#pragma unroll
    for (int j = 0; j < 4; ++j) acc[i][j] = (f32x4){0.f, 0.f, 0.f, 0.f};

  for (int kt = 0; kt < DM / 32; ++kt) {
    int k0 = kt * 32;
    {  // A: 64x32 = 4KB, one chunk
      int li0 = wv * 64;
      int li = li0 + lane;
      int row = li >> 2, sl = li & 3;
      int gs = sl ^ ((row >> 1) & 3);
      __builtin_amdgcn_global_load_lds((const AS1 void*)(Ab + (size_t)row * DM + k0 + gs * 8),
                                       (AS3 void*)(&Al[li0 * 8]), 16, 0, 0);
    }
#pragma unroll
    for (int c = 0; c < 2; ++c) {  // B: 128x32 = 8KB, two chunks
      int li0 = wv * 64 + c * 256;
      int li = li0 + lane;
      int row = li >> 2, sl = li & 3;
      int gs = sl ^ ((row >> 1) & 3);
      __builtin_amdgcn_global_load_lds((const AS1 void*)(Bb + (size_t)row * DM + k0 + gs * 8),
                                       (AS3 void*)(&Bl[li0 * 8]), 16, 0, 0);
    }
    __syncthreads();

    short8 af[2], bfr[4];
    const int kb = lane >> 4;
#pragma unroll
    for (int mi = 0; mi < 2; ++mi) {
      int r = wr * 32 + mi * 16 + (lane & 15);
      af[mi] = *(const short8*)(&Al[r * 32 + ((kb ^ ((r >> 1) & 3)) << 3)]);
    }
#pragma unroll
    for (int ni = 0; ni < 4; ++ni) {
      int r = wc * 64 + ni * 16 + (lane & 15);
      bfr[ni] = *(const short8*)(&Bl[r * 32 + ((kb ^ ((r >> 1) & 3)) << 3)]);
    }
#pragma unroll
    for (int mi = 0; mi < 2; ++mi)
#pragma unroll
      for (int ni = 0; ni < 4; ++ni)
        acc[mi][ni] = __builtin_amdgcn_mfma_f32_16x16x32_bf16(af[mi], bfr[ni], acc[mi][ni], 0, 0, 0);
    __syncthreads();
  }

#pragma unroll
  for (int mi = 0; mi < 2; ++mi) {
#pragma unroll
    for (int ni = 0; ni < 4; ++ni) {
      int row0 = mt * 64 + wr * 32 + mi * 16 + (lane >> 4) * 4;
      int col = nt * 128 + wc * 64 + ni * 16 + (lane & 15);
      float bv = bias[col];
#pragma unroll
      for (int j = 0; j < 4; ++j)
        out[(size_t)(row0 + j) * DM + col] = acc[mi][ni][j] + bv;
    }
  }
}

// ---------------- flash attention: split-KV x4, swapped-QK^T ----------------
// 256-thread block = 4 waves on one (bh, q-tile). Wave w computes KV tiles
// [w*nt/4, (w+1)*nt/4), each with private online softmax; exact 4-way merge
// via LDS. Fragment-major operands -> coalesced 1KB loads, counted vmcnt.
__global__ __launch_bounds__(256, 2) void flash_attn(const bf16* __restrict__ FQ,
                                                     const bf16* __restrict__ FK,
                                                     const bf16* __restrict__ FV,
                                                     bf16* __restrict__ Zb) {
  __shared__ float Zm[3][64][33];   // waves 1-3 partial Z^T (padded)
  __shared__ float Ml[3][64], Ll[3][64];
  __shared__ unsigned Zl[32 * 32];  // wave0 final ZT->Z transpose

  const int lane = threadIdx.x & 63;
  const int wvi = threadIdx.x >> 6;
  const int qln = lane & 31;
  const bool hib = lane >= 32;
  const int bh = blockIdx.x & 31;           // bh%8 -> XCD affinity
  const int wq = 63 - (blockIdx.x >> 5);    // heavy blocks dispatch first
  const int bb = bh >> 4, h = bh & 15;
  const int q0 = wq * 32;
  const int nt = wq / 2 + 1;
  const int t0 = (wvi * nt) >> 2;
  const int t1 = ((wvi + 1) * nt) >> 2;

  const size_t fb = (size_t)bh * 131072;
  const bf16* qp = FQ + fb + wq * 2048 + lane * 8;
  const bf16* kpt = FK + fb + (size_t)t0 * 4096 + lane * 8;
  const bf16* vp0 = FV + fb + (size_t)t0 * 2048 + lane * 8;
  const bf16* vp1 = vp0 + 65536;

  f32x16 zacc[2];
#pragma unroll
  for (int i = 0; i < 16; ++i) { zacc[0][i] = 0.f; zacc[1][i] = 0.f; }
  float mrun = -1e30f, lrun = 0.f;

  short8 qf[4];
  short8 kfA[2][4], kfB[2][4];

  if (t0 < t1) {
    // prologue: Q (4 loads) then K(t0) (8 coalesced loads)
    GL16(qf[0], qp, 0); GL16(qf[1], qp, 1024); GL16(qf[2], qp, 2048); GL16(qf[3], qp, 3072);
    {
      const bf16* k1 = kpt + 2048;
      GL16(kfA[0][0], kpt, 0); GL16(kfA[0][1], kpt, 1024); GL16(kfA[0][2], kpt, 2048); GL16(kfA[0][3], kpt, 3072);
      GL16(kfA[1][0], k1, 0);  GL16(kfA[1][1], k1, 1024);  GL16(kfA[1][2], k1, 2048);  GL16(kfA[1][3], k1, 3072);
      kpt += 4096;
    }

    auto computeT = [&](short8(&kf)[2][4], short8(&kfn)[2][4], int t) {
      const int kv0 = t * 64;
      const bool pref = (t + 1 < t1);

      // issue V(t) — consumed at PV below
      short8 vf[2][4];
      GL16(vf[0][0], vp0, 0); GL16(vf[0][1], vp0, 1024); GL16(vf[0][2], vp0, 2048); GL16(vf[0][3], vp0, 3072);
      GL16(vf[1][0], vp1, 0); GL16(vf[1][1], vp1, 1024); GL16(vf[1][2], vp1, 2048); GL16(vf[1][3], vp1, 3072);
      vp0 += 2048; vp1 += 2048;

      WAITV(8);  // K(t) (and Q on first tile) complete; V(t) stays in flight

      f32x16 s[2];
#pragma unroll
      for (int i = 0; i < 16; ++i) { s[0][i] = 0.f; s[1][i] = 0.f; }
      __builtin_amdgcn_s_setprio(1);
#pragma unroll
      for (int kc = 0; kc < 4; ++kc) {
        s[0] = __builtin_amdgcn_mfma_f32_32x32x16_bf16(kf[0][kc], qf[kc], s[0], 0, 0, 0);
        s[1] = __builtin_amdgcn_mfma_f32_32x32x16_bf16(kf[1][kc], qf[kc], s[1], 0, 0, 0);
      }
      __builtin_amdgcn_s_setprio(0);

      if (pref) {  // issue K(t+1)
        const bf16* k1 = kpt + 2048;
        GL16(kfn[0][0], kpt, 0); GL16(kfn[0][1], kpt, 1024); GL16(kfn[0][2], kpt, 2048); GL16(kfn[0][3], kpt, 3072);
        GL16(kfn[1][0], k1, 0);  GL16(kfn[1][1], k1, 1024);  GL16(kfn[1][2], k1, 2048);  GL16(kfn[1][3], k1, 3072);
        kpt += 4096;
      }

      if (t == nt - 1) {  // causal mask, diagonal tile only
        const int qg = q0 + qln;
#pragma unroll
        for (int ni = 0; ni < 2; ++ni)
#pragma unroll
          for (int rr = 0; rr < 16; ++rr) {
            int kv = kv0 + 32 * ni + (rr & 3) + 8 * (rr >> 2) + (hib ? 4 : 0);
            if (kv > qg) s[ni][rr] = -1e30f;
          }
      }

      // row max: in-register tree + cross-half swap
      float t8[8];
#pragma unroll
      for (int i = 0; i < 8; ++i)
        t8[i] = fmaxf(fmaxf(s[0][i], s[0][i + 8]), fmaxf(s[1][i], s[1][i + 8]));
      float tm = fmaxf(fmaxf(fmaxf(t8[0], t8[1]), fmaxf(t8[2], t8[3])),
                       fmaxf(fmaxf(t8[4], t8[5]), fmaxf(t8[6], t8[7])));
      tm = xmax32(tm);

      // defer-max (T13): rescale only when max grew by >8; P bounded by 2^8.
      if (__ballot(tm > mrun + 8.0f)) {
        float mn = fmaxf(mrun, tm);
        float al = fexp2(mrun - mn);
        mrun = mn;
        lrun *= al;
#pragma unroll
        for (int i = 0; i < 16; ++i) { zacc[0][i] *= al; zacc[1][i] *= al; }
      }

      float pacc[4] = {0.f, 0.f, 0.f, 0.f};
#pragma unroll
      for (int ni = 0; ni < 2; ++ni)
#pragma unroll
        for (int rr = 0; rr < 16; ++rr) {
          float p = fexp2(s[ni][rr] - mrun);
          s[ni][rr] = p;
          pacc[rr & 3] += p;
        }
      lrun += xsum32((pacc[0] + pacc[1]) + (pacc[2] + pacc[3]));

      // P -> bf16 B-fragments: pack pairs, permlane32_swap fills both halves
      unsigned su32[2][8];
#pragma unroll
      for (int ni = 0; ni < 2; ++ni)
#pragma unroll
        for (int tt = 0; tt < 8; ++tt)
          su32[ni][tt] = pack2(s[ni][2 * tt], s[ni][2 * tt + 1]);

      short8 pa[4];
#if __has_builtin(__builtin_amdgcn_permlane32_swap)
#pragma unroll
      for (int c = 0; c < 4; ++c) {
        int ni = c >> 1, b4 = 4 * (c & 1);
        uint2v r0 = __builtin_amdgcn_permlane32_swap(su32[ni][b4 + 0], su32[ni][b4 + 2], false, false);
        uint2v r1 = __builtin_amdgcn_permlane32_swap(su32[ni][b4 + 1], su32[ni][b4 + 3], false, false);
        U8 w;
        w.u[0] = r0[0]; w.u[1] = r1[0]; w.u[2] = r0[1]; w.u[3] = r1[1];
        pa[c] = w.s;
      }
#else
      unsigned X[2][8];
#pragma unroll
      for (int ni = 0; ni < 2; ++ni)
#pragma unroll
        for (int tt = 0; tt < 8; ++tt)
          X[ni][tt] = (unsigned)__shfl_xor((int)su32[ni][tt], 32);
#pragma unroll
      for (int c = 0; c < 4; ++c) {
        int ni = c >> 1, b4 = 4 * (c & 1);
        U8 w;
        w.u[0] = hib ? X[ni][b4 + 2] : su32[ni][b4 + 0];
        w.u[1] = hib ? X[ni][b4 + 3] : su32[ni][b4 + 1];
        w.u[2] = hib ? su32[ni][b4 + 2] : X[ni][b4 + 0];
        w.u[3] = hib ? su32[ni][b4 + 3] : X[ni][b4 + 1];
        pa[c] = w.s;
      }
#endif

      if (pref) { WAITV(8); } else { WAITV(0); }  // V(t) done; K(t+1) in flight

      __builtin_amdgcn_s_setprio(1);
#pragma unroll
      for (int c = 0; c < 4; ++c) {
        zacc[0] = __builtin_amdgcn_mfma_f32_32x32x16_bf16(vf[0][c], pa[c], zacc[0], 0, 0, 0);
        zacc[1] = __builtin_amdgcn_mfma_f32_32x32x16_bf16(vf[1][c], pa[c], zacc[1], 0, 0, 0);
      }
      __builtin_amdgcn_s_setprio(0);
    };

    int t = t0;
    while (true) {
      computeT(kfA, kfB, t);
      if (++t >= t1) break;
      computeT(kfB, kfA, t);
      if (++t >= t1) break;
    }
  }

  // ---- 4-way merge into wave0 (exact online-softmax combine) ----
  if (wvi != 0) {
#pragma unroll
    for (int i = 0; i < 16; ++i) {
      Zm[wvi - 1][lane][i] = zacc[0][i];
      Zm[wvi - 1][lane][16 + i] = zacc[1][i];
    }
    Ml[wvi - 1][lane] = mrun;
    Ll[wvi - 1][lane] = lrun;
  }
  __syncthreads();
  if (wvi == 0) {
    float mo[3], lo[3];
#pragma unroll
    for (int w = 0; w < 3; ++w) { mo[w] = Ml[w][lane]; lo[w] = Ll[w][lane]; }
    float mn = fmaxf(fmaxf(mrun, mo[0]), fmaxf(mo[1], mo[2]));
    float a0 = fexp2(mrun - mn);
    float aw[3];
#pragma unroll
    for (int w = 0; w < 3; ++w) aw[w] = fexp2(mo[w] - mn);
    float lm = lrun * a0 + lo[0] * aw[0] + lo[1] * aw[1] + lo[2] * aw[2];
#pragma unroll
    for (int i = 0; i < 16; ++i) {
      float z0 = zacc[0][i] * a0, z1 = zacc[1][i] * a0;
#pragma unroll
      for (int w = 0; w < 3; ++w) {
        z0 += Zm[w][lane][i] * aw[w];
        z1 += Zm[w][lane][16 + i] * aw[w];
      }
      zacc[0][i] = z0; zacc[1][i] = z1;
    }

    // normalize + transpose Z^T -> Z via swizzled LDS, coalesced store
    const float rl = 1.0f / lm;
    const int W8[8] = {0, 1, 4, 5, 8, 9, 12, 13};
#pragma unroll
    for (int dj = 0; dj < 2; ++dj)
#pragma unroll
      for (int tt = 0; tt < 8; ++tt) {
        unsigned v = pack2(zacc[dj][2 * tt] * rl, zacc[dj][2 * tt + 1] * rl);
        int x = 16 * dj + (hib ? 2 : 0) + W8[tt];
        Zl[qln * 32 + (((x >> 2) ^ (qln & 7)) << 2) + (x & 3)] = v;
      }
    asm volatile("s_waitcnt lgkmcnt(0)" ::: "memory");
    __builtin_amdgcn_sched_barrier(0);
    const size_t base = ((size_t)bb * SEQ) * DM + h * DHD;
    int q2 = lane >> 1, hf = lane & 1;
#pragma unroll
    for (int u = 0; u < 4; ++u) {
      int sl = (hf * 4 + u) ^ (q2 & 7);
      U8 w;
      w.u = *(const uint4v*)&Zl[q2 * 32 + sl * 4];
      *(short8*)(Zb + base + (size_t)(q0 + q2) * DM + hf * 32 + u * 8) = w.s;
    }
  }
}

extern "C" void kernel_launch(void* const* d_in, const int* in_sizes, int n_in,
                              void* d_out, int out_size, void* d_ws, size_t ws_size,
                              hipStream_t stream) {
  (void)in_sizes; (void)n_in; (void)out_size; (void)ws_size;
  const float* x = (const float*)d_in[0];
  const float* pos = (const float*)d_in[1];
  const float* WQ = (const float*)d_in[2];
  const float* bQ = (const float*)d_in[3];
  const float* WK = (const float*)d_in[4];
  const float* bK = (const float*)d_in[5];
  const float* WV = (const float*)d_in[6];
  const float* bV = (const float*)d_in[7];
  const float* WO = (const float*)d_in[8];
  const float* bO = (const float*)d_in[9];
  float* out = (float*)d_out;

  bf16* ws = (bf16*)d_ws;
  size_t off = 0;
  bf16* aib = ws + off; off += (size_t)MROWS * DM;
  bf16* xb  = ws + off; off += (size_t)MROWS * DM;
  bf16* wqt = ws + off; off += (size_t)DM * DM;
  bf16* wkt = ws + off; off += (size_t)DM * DM;
  bf16* wvt = ws + off; off += (size_t)DM * DM;
  bf16* wot = ws + off; off += (size_t)DM * DM;
  bf16* FQ  = ws + off; off += (size_t)MROWS * DM;  // fragment-major [bh][g][kc]
  bf16* FK  = ws + off; off += (size_t)MROWS * DM;
  bf16* FV  = ws + off; off += (size_t)MROWS * DM;  // fragment-major [bh][dj][ks]
  bf16* Zb  = ws + off; off += (size_t)MROWS * DM;

  prep_inputs<<<(MROWS * DM / 4 + 255) / 256, 256, 0, stream>>>(x, pos, xb, aib);
  dim3 gq(1, 16, 16);
  transpose_w<<<gq, 256, 0, stream>>>(WQ, wqt, 1024, 64);
  transpose_w<<<gq, 256, 0, stream>>>(WK, wkt, 1024, 64);
  transpose_w<<<gq, 256, 0, stream>>>(WV, wvt, 1024, 64);
  dim3 go(16, 16, 1);
  transpose_w<<<go, 256, 0, stream>>>(WO, wot, 1024, 1024);
  qkv_gemm<<<768, 256, 0, stream>>>(aib, xb, wqt, wkt, wvt, bQ, bK, bV, FQ, FK, FV);
  flash_attn<<<2048, 256, 0, stream>>>(FQ, FK, FV, Zb);
  o_gemm64<<<512, 256, 0, stream>>>(Zb, wot, bO, out);
}

// Round 12
// 110.700 us; speedup vs baseline: 1.0779x; 1.0522x over previous
//
#include <hip/hip_runtime.h>
#include <hip/hip_bf16.h>
#include <stdint.h>

typedef __hip_bfloat16 bf16;
typedef __attribute__((ext_vector_type(8))) short short8;
typedef __attribute__((ext_vector_type(4))) short short4v;
typedef __attribute__((ext_vector_type(4))) float f32x4;
typedef __attribute__((ext_vector_type(16))) float f32x16;
typedef __attribute__((ext_vector_type(4))) unsigned uint4v;
typedef __attribute__((ext_vector_type(2))) unsigned uint2v;

#define AS1 __attribute__((address_space(1)))
#define AS3 __attribute__((address_space(3)))

static constexpr int SEQ = 2048, DM = 1024, DHD = 64;
static constexpr int MROWS = 2 * SEQ;  // 4096

__device__ __forceinline__ short f2b(float f) {
  __hip_bfloat16 h = __float2bfloat16(f);
  return *reinterpret_cast<short*>(&h);
}

__device__ __forceinline__ unsigned pack2(float lo, float hi) {
  float2 fv; fv.x = lo; fv.y = hi;
  union { __hip_bfloat162 h; unsigned u; } cv;
  cv.h = __float22bfloat162_rn(fv);
  return cv.u;
}

// raw v_exp_f32 (1-inst exp2) — libm exp2f carries range-check bloat
__device__ __forceinline__ float fexp2(float x) {
#if __has_builtin(__builtin_amdgcn_exp2f)
  return __builtin_amdgcn_exp2f(x);
#else
  return exp2f(x);
#endif
}

union U8 { uint4v u; short8 s; };

// volatile asm 16B global load with literal byte offset — cannot be sunk/reordered
#define GL16(dst, ptr, off) \
  asm volatile("global_load_dwordx4 %0, %1, off offset:" #off : "=v"(dst) : "v"(ptr))
// counted wait + scheduling fence (rule #18)
#define WAITV(n) do { asm volatile("s_waitcnt vmcnt(" #n ")"); __builtin_amdgcn_sched_barrier(0); } while (0)

__device__ __forceinline__ float xmax32(float v) {
#if __has_builtin(__builtin_amdgcn_permlane32_swap)
  uint2v r = __builtin_amdgcn_permlane32_swap(__float_as_uint(v), __float_as_uint(v), false, false);
  return fmaxf(__uint_as_float(r[0]), __uint_as_float(r[1]));
#else
  return fmaxf(v, __shfl_xor(v, 32));
#endif
}
__device__ __forceinline__ float xsum32(float v) {
#if __has_builtin(__builtin_amdgcn_permlane32_swap)
  uint2v r = __builtin_amdgcn_permlane32_swap(__float_as_uint(v), __float_as_uint(v), false, false);
  return __uint_as_float(r[0]) + __uint_as_float(r[1]);
#else
  return v + __shfl_xor(v, 32);
#endif
}

// ---------------- prep: x -> bf16, x+pos -> bf16 ----------------
__global__ __launch_bounds__(256) void prep_inputs(const float* __restrict__ x,
                                                   const float* __restrict__ pos,
                                                   bf16* __restrict__ xb,
                                                   bf16* __restrict__ aib) {
  int i = blockIdx.x * 256 + threadIdx.x;
  const int n4 = MROWS * DM / 4;
  if (i >= n4) return;
  f32x4 xv = ((const f32x4*)x)[i];
  f32x4 pv = ((const f32x4*)pos)[i];
  short4v xo, ao;
#pragma unroll
  for (int j = 0; j < 4; ++j) {
    xo[j] = f2b(xv[j]);
    ao[j] = f2b(xv[j] + pv[j]);
  }
  ((short4v*)xb)[i] = xo;
  ((short4v*)aib)[i] = ao;
}

// ---------------- weight transpose: [R][C] f32 -> [C][R] bf16 (per z-slice) --
__global__ __launch_bounds__(256) void transpose_w(const float* __restrict__ in,
                                                   bf16* __restrict__ out, int R, int C) {
  __shared__ float t[64][65];
  int ct = blockIdx.x, rt = blockIdx.y, z = blockIdx.z;
  in += (size_t)z * R * C;
  out += (size_t)z * R * C;
  int c = threadIdx.x & 63, g = threadIdx.x >> 6;
#pragma unroll
  for (int j = 0; j < 16; ++j) {
    int r = g * 16 + j;
    t[r][c] = in[(size_t)(rt * 64 + r) * C + (ct * 64 + c)];
  }
  __syncthreads();
#pragma unroll
  for (int j = 0; j < 16; ++j) {
    int rr = g * 16 + j;
    out[(size_t)(ct * 64 + rr) * R + (rt * 64 + c)] = __float2bfloat16(t[c][rr]);
  }
}

// combined QKV weight transpose: z 0..47 selects WQ/WK/WV head-slice
__global__ __launch_bounds__(256) void transpose_w3(const float* __restrict__ wq,
                                                    const float* __restrict__ wk,
                                                    const float* __restrict__ wv,
                                                    bf16* __restrict__ oq,
                                                    bf16* __restrict__ ok,
                                                    bf16* __restrict__ ov) {
  __shared__ float t[64][65];
  const int R = 1024, C = 64;
  int rt = blockIdx.y, z = blockIdx.z;
  const float* in = (z < 16) ? wq : (z < 32) ? wk : wv;
  bf16* out = (z < 16) ? oq : (z < 32) ? ok : ov;
  int zz = z & 15;
  in += (size_t)zz * R * C;
  out += (size_t)zz * R * C;
  int c = threadIdx.x & 63, g = threadIdx.x >> 6;
#pragma unroll
  for (int j = 0; j < 16; ++j) {
    int r = g * 16 + j;
    t[r][c] = in[(size_t)(rt * 64 + r) * C + c];
  }
  __syncthreads();
#pragma unroll
  for (int j = 0; j < 16; ++j) {
    int rr = g * 16 + j;
    out[(size_t)rr * R + (rt * 64 + c)] = __float2bfloat16(t[c][rr]);
  }
}

// ---------------- qkv GEMM body: BM=128 x BN=256, 512 thr / 8 waves --------
// Staged bytes per output cut 25% vs 128x128 (fewer blocks share each input
// slice). BK=32 (m132: bigger BK costs occupancy). MODE 3: fragment-major
// FQ/FK. MODE 4: fragment-major FV.
template <int MODE>
__device__ __forceinline__ void qkv256_body(const bf16* __restrict__ A,
                                            const bf16* __restrict__ Bt,
                                            const float* __restrict__ bias,
                                            bf16* __restrict__ C, int mt, int nt,
                                            float scale) {
  __shared__ alignas(16) bf16 Al[128 * 32];   // 8 KB
  __shared__ alignas(16) bf16 Bl[256 * 32];   // 16 KB
  const int lane = threadIdx.x & 63, wv = threadIdx.x >> 6;
  const int wr = wv >> 2, wc = wv & 3;  // 2 x 4 wave grid, 64x64 each
  const bf16* Ab = A + (size_t)mt * 128 * DM;
  const bf16* Bb = Bt + (size_t)nt * 256 * DM;

  f32x4 acc[4][4];
#pragma unroll
  for (int i = 0; i < 4; ++i)
#pragma unroll
    for (int j = 0; j < 4; ++j) acc[i][j] = (f32x4){0.f, 0.f, 0.f, 0.f};

  for (int kt = 0; kt < DM / 32; ++kt) {
    int k0 = kt * 32;
    {  // A: 128x32 = 8 KB, one 512-lane pass
      int li0 = wv * 64;
      int li = li0 + lane;
      int row = li >> 2, sl = li & 3;
      int gs = sl ^ ((row >> 1) & 3);
      __builtin_amdgcn_global_load_lds((const AS1 void*)(Ab + (size_t)row * DM + k0 + gs * 8),
                                       (AS3 void*)(&Al[li0 * 8]), 16, 0, 0);
    }
#pragma unroll
    for (int c = 0; c < 2; ++c) {  // B: 256x32 = 16 KB, two passes
      int li0 = wv * 64 + c * 512;
      int li = li0 + lane;
      int row = li >> 2, sl = li & 3;
      int gs = sl ^ ((row >> 1) & 3);
      __builtin_amdgcn_global_load_lds((const AS1 void*)(Bb + (size_t)row * DM + k0 + gs * 8),
                                       (AS3 void*)(&Bl[li0 * 8]), 16, 0, 0);
    }
    __syncthreads();

    short8 af[4], bfr[4];
    const int kb = lane >> 4;
#pragma unroll
    for (int mi = 0; mi < 4; ++mi) {
      int r = wr * 64 + mi * 16 + (lane & 15);
      af[mi] = *(const short8*)(&Al[r * 32 + ((kb ^ ((r >> 1) & 3)) << 3)]);
    }
#pragma unroll
    for (int ni = 0; ni < 4; ++ni) {
      int r = wc * 64 + ni * 16 + (lane & 15);
      bfr[ni] = *(const short8*)(&Bl[r * 32 + ((kb ^ ((r >> 1) & 3)) << 3)]);
    }
#pragma unroll
    for (int mi = 0; mi < 4; ++mi)
#pragma unroll
      for (int ni = 0; ni < 4; ++ni)
        acc[mi][ni] = __builtin_amdgcn_mfma_f32_16x16x32_bf16(af[mi], bfr[ni], acc[mi][ni], 0, 0, 0);
    __syncthreads();
  }

#pragma unroll
  for (int mi = 0; mi < 4; ++mi) {
#pragma unroll
    for (int ni = 0; ni < 4; ++ni) {
      int row0 = mt * 128 + wr * 64 + mi * 16 + (lane >> 4) * 4;
      int col = nt * 256 + wc * 64 + ni * 16 + (lane & 15);
      float bv = bias[col];
      int bb = row0 >> 11, s0 = row0 & 2047;
      int hh = col >> 6, d0 = col & 63;
      size_t bhb = (size_t)(bb * 16 + hh) * 131072;
      if constexpr (MODE == 3) {
        // FQ/FK[bh][g][kc]: slot (r32+32*hi)*8 + e, from row s, col d0
        int kc = d0 >> 4, hi = (d0 >> 3) & 1, e = d0 & 7;
        int g = s0 >> 5, r0 = s0 & 31;
        size_t bbase = bhb + g * 2048 + kc * 512 + e;
#pragma unroll
        for (int j = 0; j < 4; ++j)
          C[bbase + (size_t)(r0 + j + 32 * hi) * 8] =
              __float2bfloat16((acc[mi][ni][j] + bv) * scale);
      } else {  // MODE 4
        // FV[bh][dj][ks]: slot (d32+32*((s>>3)&1))*8 + (s&7), d on slot axis
        int dj = d0 >> 5, d32 = d0 & 31;
        int ks = s0 >> 4, hi2 = (s0 >> 3) & 1, e0 = s0 & 7;
        short4v o;
#pragma unroll
        for (int j = 0; j < 4; ++j) o[j] = f2b(acc[mi][ni][j] + bv);
        *(short4v*)(C + bhb + dj * 65536 + ks * 512 + (size_t)(d32 + 32 * hi2) * 8 + e0) = o;
      }
    }
  }
}

// Q prescale: (1/sqrt(64)) * log2(e) so attention uses exp2
static constexpr float QSCALE = 0.125f * 1.4426950408889634f;

__global__ __launch_bounds__(512) void qkv_gemm(const bf16* __restrict__ aib,
                                                const bf16* __restrict__ xb,
                                                const bf16* __restrict__ wqt,
                                                const bf16* __restrict__ wkt,
                                                const bf16* __restrict__ wvt,
                                                const float* __restrict__ bq,
                                                const float* __restrict__ bk,
                                                const float* __restrict__ bv,
                                                bf16* __restrict__ FQ, bf16* __restrict__ FK,
                                                bf16* __restrict__ FV) {
  int mt = blockIdx.x & 31;
  int nt = (blockIdx.x >> 5) & 3;
  int mat = blockIdx.x >> 7;
  if (mat == 0) {
    qkv256_body<3>(aib, wqt, bq, FQ, mt, nt, QSCALE);
  } else if (mat == 1) {
    qkv256_body<3>(aib, wkt, bk, FK, mt, nt, 1.0f);
  } else {
    qkv256_body<4>(xb, wvt, bv, FV, mt, nt, 1.0f);
  }
}

// ---------------- o_gemm: 64x128 tiles -> 512 blocks (2 blocks/CU) ----------
__global__ __launch_bounds__(256) void o_gemm64(const bf16* __restrict__ A,
                                                const bf16* __restrict__ Bt,
                                                const float* __restrict__ bias,
                                                float* __restrict__ out) {
  __shared__ alignas(16) bf16 Al[64 * 32];
  __shared__ alignas(16) bf16 Bl[128 * 32];
  const int mt = blockIdx.x & 63, nt = blockIdx.x >> 6;
  const int lane = threadIdx.x & 63, wv = threadIdx.x >> 6;
  const int wr = wv >> 1, wc = wv & 1;  // wave: 32 rows x 64 cols quadrant
  const bf16* Ab = A + (size_t)mt * 64 * DM;
  const bf16* Bb = Bt + (size_t)nt * 128 * DM;

  f32x4 acc[2][4];
#pragma unroll
  for (int i = 0; i < 2; ++i)
#pragma unroll
    for (int j = 0; j < 4; ++j) acc[i][j] = (f32x4){0.f, 0.f, 0.f, 0.f};

  for (int kt = 0; kt < DM / 32; ++kt) {
    int k0 = kt * 32;
    {  // A: 64x32 = 4KB, one chunk
      int li0 = wv * 64;
      int li = li0 + lane;
      int row = li >> 2, sl = li & 3;
      int gs = sl ^ ((row >> 1) & 3);
      __builtin_amdgcn_global_load_lds((const AS1 void*)(Ab + (size_t)row * DM + k0 + gs * 8),
                                       (AS3 void*)(&Al[li0 * 8]), 16, 0, 0);
    }
#pragma unroll
    for (int c = 0; c < 2; ++c) {  // B: 128x32 = 8KB, two chunks
      int li0 = wv * 64 + c * 256;
      int li = li0 + lane;
      int row = li >> 2, sl = li & 3;
      int gs = sl ^ ((row >> 1) & 3);
      __builtin_amdgcn_global_load_lds((const AS1 void*)(Bb + (size_t)row * DM + k0 + gs * 8),
                                       (AS3 void*)(&Bl[li0 * 8]), 16, 0, 0);
    }
    __syncthreads();

    short8 af[2], bfr[4];
    const int kb = lane >> 4;
#pragma unroll
    for (int mi = 0; mi < 2; ++mi) {
      int r = wr * 32 + mi * 16 + (lane & 15);
      af[mi] = *(const short8*)(&Al[r * 32 + ((kb ^ ((r >> 1) & 3)) << 3)]);
    }
#pragma unroll
    for (int ni = 0; ni < 4; ++ni) {
      int r = wc * 64 + ni * 16 + (lane & 15);
      bfr[ni] = *(const short8*)(&Bl[r * 32 + ((kb ^ ((r >> 1) & 3)) << 3)]);
    }
#pragma unroll
    for (int mi = 0; mi < 2; ++mi)
#pragma unroll
      for (int ni = 0; ni < 4; ++ni)
        acc[mi][ni] = __builtin_amdgcn_mfma_f32_16x16x32_bf16(af[mi], bfr[ni], acc[mi][ni], 0, 0, 0);
    __syncthreads();
  }

#pragma unroll
  for (int mi = 0; mi < 2; ++mi) {
#pragma unroll
    for (int ni = 0; ni < 4; ++ni) {
      int row0 = mt * 64 + wr * 32 + mi * 16 + (lane >> 4) * 4;
      int col = nt * 128 + wc * 64 + ni * 16 + (lane & 15);
      float bv = bias[col];
#pragma unroll
      for (int j = 0; j < 4; ++j)
        out[(size_t)(row0 + j) * DM + col] = acc[mi][ni][j] + bv;
    }
  }
}

// ---------------- flash attention: split-KV x2, swapped-QK^T ----------------
// (round-10 proven config) 128-thread block = 2 waves on one (bh, q-tile);
// wave0 tiles [0,hsp), wave1 [hsp,nt); exact merge via LDS. Fragment-major
// operands -> coalesced 1KB loads with counted-vmcnt pipelining. THR=8
// defer-max. T5 setprio on MFMA clusters.
__global__ __launch_bounds__(128, 2) void flash_attn(const bf16* __restrict__ FQ,
                                                     const bf16* __restrict__ FK,
                                                     const bf16* __restrict__ FV,
                                                     bf16* __restrict__ Zb) {
  __shared__ float Zm[64][33];   // wave1 partial Z^T (padded)
  __shared__ float Ml[64], Ll[64];
  __shared__ unsigned Zl[32 * 32];  // wave0 final ZT->Z transpose

  const int lane = threadIdx.x & 63;
  const int wvi = threadIdx.x >> 6;
  const int qln = lane & 31;
  const bool hib = lane >= 32;
  const int bh = blockIdx.x & 31;           // bh%8 -> XCD affinity
  const int wq = 63 - (blockIdx.x >> 5);    // heavy blocks dispatch first
  const int bb = bh >> 4, h = bh & 15;
  const int q0 = wq * 32;
  const int nt = wq / 2 + 1;
  const int hsp = (nt + 1) >> 1;
  const int t0 = wvi ? hsp : 0;
  const int t1 = wvi ? nt : hsp;

  const size_t fb = (size_t)bh * 131072;
  const bf16* qp = FQ + fb + wq * 2048 + lane * 8;
  const bf16* kpt = FK + fb + (size_t)t0 * 4096 + lane * 8;
  const bf16* vp0 = FV + fb + (size_t)t0 * 2048 + lane * 8;
  const bf16* vp1 = vp0 + 65536;

  f32x16 zacc[2];
#pragma unroll
  for (int i = 0; i < 16; ++i) { zacc[0][i] = 0.f; zacc[1][i] = 0.f; }
  float mrun = -1e30f, lrun = 0.f;

  short8 qf[4];
  short8 kfA[2][4], kfB[2][4];

  if (t0 < t1) {
    // prologue: Q (4 loads) then K(t0) (8 coalesced loads)
    GL16(qf[0], qp, 0); GL16(qf[1], qp, 1024); GL16(qf[2], qp, 2048); GL16(qf[3], qp, 3072);
    {
      const bf16* k1 = kpt + 2048;
      GL16(kfA[0][0], kpt, 0); GL16(kfA[0][1], kpt, 1024); GL16(kfA[0][2], kpt, 2048); GL16(kfA[0][3], kpt, 3072);
      GL16(kfA[1][0], k1, 0);  GL16(kfA[1][1], k1, 1024);  GL16(kfA[1][2], k1, 2048);  GL16(kfA[1][3], k1, 3072);
      kpt += 4096;
    }

    auto computeT = [&](short8(&kf)[2][4], short8(&kfn)[2][4], int t) {
      const int kv0 = t * 64;
      const bool pref = (t + 1 < t1);

      // issue V(t) — consumed at PV below
      short8 vf[2][4];
      GL16(vf[0][0], vp0, 0); GL16(vf[0][1], vp0, 1024); GL16(vf[0][2], vp0, 2048); GL16(vf[0][3], vp0, 3072);
      GL16(vf[1][0], vp1, 0); GL16(vf[1][1], vp1, 1024); GL16(vf[1][2], vp1, 2048); GL16(vf[1][3], vp1, 3072);
      vp0 += 2048; vp1 += 2048;

      WAITV(8);  // K(t) (and Q on first tile) complete; V(t) stays in flight

      f32x16 s[2];
#pragma unroll
      for (int i = 0; i < 16; ++i) { s[0][i] = 0.f; s[1][i] = 0.f; }
      __builtin_amdgcn_s_setprio(1);
#pragma unroll
      for (int kc = 0; kc < 4; ++kc) {
        s[0] = __builtin_amdgcn_mfma_f32_32x32x16_bf16(kf[0][kc], qf[kc], s[0], 0, 0, 0);
        s[1] = __builtin_amdgcn_mfma_f32_32x32x16_bf16(kf[1][kc], qf[kc], s[1], 0, 0, 0);
      }
      __builtin_amdgcn_s_setprio(0);

      if (pref) {  // issue K(t+1)
        const bf16* k1 = kpt + 2048;
        GL16(kfn[0][0], kpt, 0); GL16(kfn[0][1], kpt, 1024); GL16(kfn[0][2], kpt, 2048); GL16(kfn[0][3], kpt, 3072);
        GL16(kfn[1][0], k1, 0);  GL16(kfn[1][1], k1, 1024);  GL16(kfn[1][2], k1, 2048);  GL16(kfn[1][3], k1, 3072);
        kpt += 4096;
      }

      if (t == nt - 1) {  // causal mask, diagonal tile only
        const int qg = q0 + qln;
#pragma unroll
        for (int ni = 0; ni < 2; ++ni)
#pragma unroll
          for (int rr = 0; rr < 16; ++rr) {
            int kv = kv0 + 32 * ni + (rr & 3) + 8 * (rr >> 2) + (hib ? 4 : 0);
            if (kv > qg) s[ni][rr] = -1e30f;
          }
      }

      // row max: in-register tree + cross-half swap
      float t8[8];
#pragma unroll
      for (int i = 0; i < 8; ++i)
        t8[i] = fmaxf(fmaxf(s[0][i], s[0][i + 8]), fmaxf(s[1][i], s[1][i + 8]));
      float tm = fmaxf(fmaxf(fmaxf(t8[0], t8[1]), fmaxf(t8[2], t8[3])),
                       fmaxf(fmaxf(t8[4], t8[5]), fmaxf(t8[6], t8[7])));
      tm = xmax32(tm);

      // defer-max (T13): rescale only when max grew by >8; P bounded by 2^8.
      if (__ballot(tm > mrun + 8.0f)) {
        float mn = fmaxf(mrun, tm);
        float al = fexp2(mrun - mn);
        mrun = mn;
        lrun *= al;
#pragma unroll
        for (int i = 0; i < 16; ++i) { zacc[0][i] *= al; zacc[1][i] *= al; }
      }

      float pacc[4] = {0.f, 0.f, 0.f, 0.f};
#pragma unroll
      for (int ni = 0; ni < 2; ++ni)
#pragma unroll
        for (int rr = 0; rr < 16; ++rr) {
          float p = fexp2(s[ni][rr] - mrun);
          s[ni][rr] = p;
          pacc[rr & 3] += p;
        }
      lrun += xsum32((pacc[0] + pacc[1]) + (pacc[2] + pacc[3]));

      // P -> bf16 B-fragments: pack pairs, permlane32_swap fills both halves
      unsigned su32[2][8];
#pragma unroll
      for (int ni = 0; ni < 2; ++ni)
#pragma unroll
        for (int tt = 0; tt < 8; ++tt)
          su32[ni][tt] = pack2(s[ni][2 * tt], s[ni][2 * tt + 1]);

      short8 pa[4];
#if __has_builtin(__builtin_amdgcn_permlane32_swap)
#pragma unroll
      for (int c = 0; c < 4; ++c) {
        int ni = c >> 1, b4 = 4 * (c & 1);
        uint2v r0 = __builtin_amdgcn_permlane32_swap(su32[ni][b4 + 0], su32[ni][b4 + 2], false, false);
        uint2v r1 = __builtin_amdgcn_permlane32_swap(su32[ni][b4 + 1], su32[ni][b4 + 3], false, false);
        U8 w;
        w.u[0] = r0[0]; w.u[1] = r1[0]; w.u[2] = r0[1]; w.u[3] = r1[1];
        pa[c] = w.s;
      }
#else
      unsigned X[2][8];
#pragma unroll
      for (int ni = 0; ni < 2; ++ni)
#pragma unroll
        for (int tt = 0; tt < 8; ++tt)
          X[ni][tt] = (unsigned)__shfl_xor((int)su32[ni][tt], 32);
#pragma unroll
      for (int c = 0; c < 4; ++c) {
        int ni = c >> 1, b4 = 4 * (c & 1);
        U8 w;
        w.u[0] = hib ? X[ni][b4 + 2] : su32[ni][b4 + 0];
        w.u[1] = hib ? X[ni][b4 + 3] : su32[ni][b4 + 1];
        w.u[2] = hib ? su32[ni][b4 + 2] : X[ni][b4 + 0];
        w.u[3] = hib ? su32[ni][b4 + 3] : X[ni][b4 + 1];
        pa[c] = w.s;
      }
#endif

      if (pref) { WAITV(8); } else { WAITV(0); }  // V(t) done; K(t+1) in flight

      __builtin_amdgcn_s_setprio(1);
#pragma unroll
      for (int c = 0; c < 4; ++c) {
        zacc[0] = __builtin_amdgcn_mfma_f32_32x32x16_bf16(vf[0][c], pa[c], zacc[0], 0, 0, 0);
        zacc[1] = __builtin_amdgcn_mfma_f32_32x32x16_bf16(vf[1][c], pa[c], zacc[1], 0, 0, 0);
      }
      __builtin_amdgcn_s_setprio(0);
    };

    int t = t0;
    while (true) {
      computeT(kfA, kfB, t);
      if (++t >= t1) break;
      computeT(kfB, kfA, t);
      if (++t >= t1) break;
    }
  }

  // ---- merge wave1 into wave0 (exact online-softmax combine) ----
  if (wvi == 1) {
#pragma unroll
    for (int i = 0; i < 16; ++i) {
      Zm[lane][i] = zacc[0][i];
      Zm[lane][16 + i] = zacc[1][i];
    }
    Ml[lane] = mrun;
    Ll[lane] = lrun;
  }
  __syncthreads();
  if (wvi == 0) {
    float m1 = Ml[lane], l1 = Ll[lane];
    float mn = fmaxf(mrun, m1);
    float a0 = fexp2(mrun - mn);
    float a1 = fexp2(m1 - mn);
    float lm = lrun * a0 + l1 * a1;
#pragma unroll
    for (int i = 0; i < 16; ++i) {
      zacc[0][i] = zacc[0][i] * a0 + Zm[lane][i] * a1;
      zacc[1][i] = zacc[1][i] * a0 + Zm[lane][16 + i] * a1;
    }

    // normalize + transpose Z^T -> Z via swizzled LDS, coalesced store
    const float rl = 1.0f / lm;
    const int W8[8] = {0, 1, 4, 5, 8, 9, 12, 13};
#pragma unroll
    for (int dj = 0; dj < 2; ++dj)
#pragma unroll
      for (int tt = 0; tt < 8; ++tt) {
        unsigned v = pack2(zacc[dj][2 * tt] * rl, zacc[dj][2 * tt + 1] * rl);
        int x = 16 * dj + (hib ? 2 : 0) + W8[tt];
        Zl[qln * 32 + (((x >> 2) ^ (qln & 7)) << 2) + (x & 3)] = v;
      }
    asm volatile("s_waitcnt lgkmcnt(0)" ::: "memory");
    __builtin_amdgcn_sched_barrier(0);
    const size_t base = ((size_t)bb * SEQ) * DM + h * DHD;
    int q2 = lane >> 1, hf = lane & 1;
#pragma unroll
    for (int u = 0; u < 4; ++u) {
      int sl = (hf * 4 + u) ^ (q2 & 7);
      U8 w;
      w.u = *(const uint4v*)&Zl[q2 * 32 + sl * 4];
      *(short8*)(Zb + base + (size_t)(q0 + q2) * DM + hf * 32 + u * 8) = w.s;
    }
  }
}

extern "C" void kernel_launch(void* const* d_in, const int* in_sizes, int n_in,
                              void* d_out, int out_size, void* d_ws, size_t ws_size,
                              hipStream_t stream) {
  (void)in_sizes; (void)n_in; (void)out_size; (void)ws_size;
  const float* x = (const float*)d_in[0];
  const float* pos = (const float*)d_in[1];
  const float* WQ = (const float*)d_in[2];
  const float* bQ = (const float*)d_in[3];
  const float* WK = (const float*)d_in[4];
  const float* bK = (const float*)d_in[5];
  const float* WV = (const float*)d_in[6];
  const float* bV = (const float*)d_in[7];
  const float* WO = (const float*)d_in[8];
  const float* bO = (const float*)d_in[9];
  float* out = (float*)d_out;

  bf16* ws = (bf16*)d_ws;
  size_t off = 0;
  bf16* aib = ws + off; off += (size_t)MROWS * DM;
  bf16* xb  = ws + off; off += (size_t)MROWS * DM;
  bf16* wqt = ws + off; off += (size_t)DM * DM;
  bf16* wkt = ws + off; off += (size_t)DM * DM;
  bf16* wvt = ws + off; off += (size_t)DM * DM;
  bf16* wot = ws + off; off += (size_t)DM * DM;
  bf16* FQ  = ws + off; off += (size_t)MROWS * DM;  // fragment-major [bh][g][kc]
  bf16* FK  = ws + off; off += (size_t)MROWS * DM;
  bf16* FV  = ws + off; off += (size_t)MROWS * DM;  // fragment-major [bh][dj][ks]
  bf16* Zb  = ws + off; off += (size_t)MROWS * DM;

  prep_inputs<<<(MROWS * DM / 4 + 255) / 256, 256, 0, stream>>>(x, pos, xb, aib);
  dim3 g3(1, 16, 48);
  transpose_w3<<<g3, 256, 0, stream>>>(WQ, WK, WV, wqt, wkt, wvt);
  dim3 go(16, 16, 1);
  transpose_w<<<go, 256, 0, stream>>>(WO, wot, 1024, 1024);
  qkv_gemm<<<384, 512, 0, stream>>>(aib, xb, wqt, wkt, wvt, bQ, bK, bV, FQ, FK, FV);
  flash_attn<<<2048, 128, 0, stream>>>(FQ, FK, FV, Zb);
  o_gemm64<<<512, 256, 0, stream>>>(Zb, wot, bO, out);
}

// Round 13
// 109.809 us; speedup vs baseline: 1.0866x; 1.0081x over previous
//
#include <hip/hip_runtime.h>
#include <hip/hip_bf16.h>
#include <stdint.h>

typedef __hip_bfloat16 bf16;
typedef __attribute__((ext_vector_type(8))) short short8;
typedef __attribute__((ext_vector_type(4))) short short4v;
typedef __attribute__((ext_vector_type(4))) float f32x4;
typedef __attribute__((ext_vector_type(16))) float f32x16;
typedef __attribute__((ext_vector_type(4))) unsigned uint4v;
typedef __attribute__((ext_vector_type(2))) unsigned uint2v;

#define AS1 __attribute__((address_space(1)))
#define AS3 __attribute__((address_space(3)))

static constexpr int SEQ = 2048, DM = 1024, DHD = 64;
static constexpr int MROWS = 2 * SEQ;  // 4096

__device__ __forceinline__ short f2b(float f) {
  __hip_bfloat16 h = __float2bfloat16(f);
  return *reinterpret_cast<short*>(&h);
}

__device__ __forceinline__ unsigned pack2(float lo, float hi) {
  float2 fv; fv.x = lo; fv.y = hi;
  union { __hip_bfloat162 h; unsigned u; } cv;
  cv.h = __float22bfloat162_rn(fv);
  return cv.u;
}

// raw v_exp_f32 (1-inst exp2) — libm exp2f carries range-check bloat
__device__ __forceinline__ float fexp2(float x) {
#if __has_builtin(__builtin_amdgcn_exp2f)
  return __builtin_amdgcn_exp2f(x);
#else
  return exp2f(x);
#endif
}

union U8 { uint4v u; short8 s; };

// volatile asm 16B global load with literal byte offset — cannot be sunk/reordered
#define GL16(dst, ptr, off) \
  asm volatile("global_load_dwordx4 %0, %1, off offset:" #off : "=v"(dst) : "v"(ptr))
// counted wait + scheduling fence (rule #18)
#define WAITV(n) do { asm volatile("s_waitcnt vmcnt(" #n ")"); __builtin_amdgcn_sched_barrier(0); } while (0)

__device__ __forceinline__ float xmax32(float v) {
#if __has_builtin(__builtin_amdgcn_permlane32_swap)
  uint2v r = __builtin_amdgcn_permlane32_swap(__float_as_uint(v), __float_as_uint(v), false, false);
  return fmaxf(__uint_as_float(r[0]), __uint_as_float(r[1]));
#else
  return fmaxf(v, __shfl_xor(v, 32));
#endif
}
__device__ __forceinline__ float xsum32(float v) {
#if __has_builtin(__builtin_amdgcn_permlane32_swap)
  uint2v r = __builtin_amdgcn_permlane32_swap(__float_as_uint(v), __float_as_uint(v), false, false);
  return __uint_as_float(r[0]) + __uint_as_float(r[1]);
#else
  return v + __shfl_xor(v, 32);
#endif
}

// ---------------- prep: x -> bf16, x+pos -> bf16 ----------------
__global__ __launch_bounds__(256) void prep_inputs(const float* __restrict__ x,
                                                   const float* __restrict__ pos,
                                                   bf16* __restrict__ xb,
                                                   bf16* __restrict__ aib) {
  int i = blockIdx.x * 256 + threadIdx.x;
  const int n4 = MROWS * DM / 4;
  if (i >= n4) return;
  f32x4 xv = ((const f32x4*)x)[i];
  f32x4 pv = ((const f32x4*)pos)[i];
  short4v xo, ao;
#pragma unroll
  for (int j = 0; j < 4; ++j) {
    xo[j] = f2b(xv[j]);
    ao[j] = f2b(xv[j] + pv[j]);
  }
  ((short4v*)xb)[i] = xo;
  ((short4v*)aib)[i] = ao;
}

// ---------------- weight transpose: [R][C] f32 -> [C][R] bf16 (per z-slice) --
__global__ __launch_bounds__(256) void transpose_w(const float* __restrict__ in,
                                                   bf16* __restrict__ out, int R, int C) {
  __shared__ float t[64][65];
  int ct = blockIdx.x, rt = blockIdx.y, z = blockIdx.z;
  in += (size_t)z * R * C;
  out += (size_t)z * R * C;
  int c = threadIdx.x & 63, g = threadIdx.x >> 6;
#pragma unroll
  for (int j = 0; j < 16; ++j) {
    int r = g * 16 + j;
    t[r][c] = in[(size_t)(rt * 64 + r) * C + (ct * 64 + c)];
  }
  __syncthreads();
#pragma unroll
  for (int j = 0; j < 16; ++j) {
    int rr = g * 16 + j;
    out[(size_t)(ct * 64 + rr) * R + (rt * 64 + c)] = __float2bfloat16(t[c][rr]);
  }
}

// combined QKV weight transpose: z 0..47 selects WQ/WK/WV head-slice
__global__ __launch_bounds__(256) void transpose_w3(const float* __restrict__ wq,
                                                    const float* __restrict__ wk,
                                                    const float* __restrict__ wv,
                                                    bf16* __restrict__ oq,
                                                    bf16* __restrict__ ok,
                                                    bf16* __restrict__ ov) {
  __shared__ float t[64][65];
  const int R = 1024, C = 64;
  int rt = blockIdx.y, z = blockIdx.z;
  const float* in = (z < 16) ? wq : (z < 32) ? wk : wv;
  bf16* out = (z < 16) ? oq : (z < 32) ? ok : ov;
  int zz = z & 15;
  in += (size_t)zz * R * C;
  out += (size_t)zz * R * C;
  int c = threadIdx.x & 63, g = threadIdx.x >> 6;
#pragma unroll
  for (int j = 0; j < 16; ++j) {
    int r = g * 16 + j;
    t[r][c] = in[(size_t)(rt * 64 + r) * C + c];
  }
  __syncthreads();
#pragma unroll
  for (int j = 0; j < 16; ++j) {
    int rr = g * 16 + j;
    out[(size_t)rr * R + (rt * 64 + c)] = __float2bfloat16(t[c][rr]);
  }
}

// ---------------- 128x128 GEMM body, BK=32 (round-9 proven config) ----------
// MODE 3: bf16 fragment-major FQ/FK. MODE 4: fragment-major FV.
template <int MODE>
__device__ __forceinline__ void gemm128_body(const bf16* __restrict__ A,
                                             const bf16* __restrict__ Bt,
                                             const float* __restrict__ bias,
                                             bf16* __restrict__ C, int mt, int nt,
                                             float scale) {
  __shared__ alignas(16) bf16 Al[128 * 32];
  __shared__ alignas(16) bf16 Bl[128 * 32];
  const int lane = threadIdx.x & 63, wv = threadIdx.x >> 6;
  const int wr = wv >> 1, wc = wv & 1;
  const bf16* Ab = A + (size_t)mt * 128 * DM;
  const bf16* Bb = Bt + (size_t)nt * 128 * DM;

  f32x4 acc[4][4];
#pragma unroll
  for (int i = 0; i < 4; ++i)
#pragma unroll
    for (int j = 0; j < 4; ++j) acc[i][j] = (f32x4){0.f, 0.f, 0.f, 0.f};

  for (int kt = 0; kt < DM / 32; ++kt) {
    int k0 = kt * 32;
#pragma unroll
    for (int c = 0; c < 2; ++c) {
      int li0 = wv * 64 + c * 256;
      int li = li0 + lane;
      int row = li >> 2, sl = li & 3;
      int gs = sl ^ ((row >> 1) & 3);
      __builtin_amdgcn_global_load_lds((const AS1 void*)(Ab + (size_t)row * DM + k0 + gs * 8),
                                       (AS3 void*)(&Al[li0 * 8]), 16, 0, 0);
    }
#pragma unroll
    for (int c = 0; c < 2; ++c) {
      int li0 = wv * 64 + c * 256;
      int li = li0 + lane;
      int row = li >> 2, sl = li & 3;
      int gs = sl ^ ((row >> 1) & 3);
      __builtin_amdgcn_global_load_lds((const AS1 void*)(Bb + (size_t)row * DM + k0 + gs * 8),
                                       (AS3 void*)(&Bl[li0 * 8]), 16, 0, 0);
    }
    __syncthreads();

    short8 af[4], bfr[4];
    const int kb = lane >> 4;
#pragma unroll
    for (int mi = 0; mi < 4; ++mi) {
      int r = wr * 64 + mi * 16 + (lane & 15);
      af[mi] = *(const short8*)(&Al[r * 32 + ((kb ^ ((r >> 1) & 3)) << 3)]);
    }
#pragma unroll
    for (int ni = 0; ni < 4; ++ni) {
      int r = wc * 64 + ni * 16 + (lane & 15);
      bfr[ni] = *(const short8*)(&Bl[r * 32 + ((kb ^ ((r >> 1) & 3)) << 3)]);
    }
#pragma unroll
    for (int mi = 0; mi < 4; ++mi)
#pragma unroll
      for (int ni = 0; ni < 4; ++ni)
        acc[mi][ni] = __builtin_amdgcn_mfma_f32_16x16x32_bf16(af[mi], bfr[ni], acc[mi][ni], 0, 0, 0);
    __syncthreads();
  }

#pragma unroll
  for (int mi = 0; mi < 4; ++mi) {
#pragma unroll
    for (int ni = 0; ni < 4; ++ni) {
      int row0 = mt * 128 + wr * 64 + mi * 16 + (lane >> 4) * 4;
      int col = nt * 128 + wc * 64 + ni * 16 + (lane & 15);
      float bv = bias[col];
      int bb = row0 >> 11, s0 = row0 & 2047;
      int hh = col >> 6, d0 = col & 63;
      size_t bhb = (size_t)(bb * 16 + hh) * 131072;
      if constexpr (MODE == 3) {
        // FQ/FK[bh][g][kc]: slot (r32+32*hi)*8 + e, from row s, col d0
        int kc = d0 >> 4, hi = (d0 >> 3) & 1, e = d0 & 7;
        int g = s0 >> 5, r0 = s0 & 31;
        size_t bbase = bhb + g * 2048 + kc * 512 + e;
#pragma unroll
        for (int j = 0; j < 4; ++j)
          C[bbase + (size_t)(r0 + j + 32 * hi) * 8] =
              __float2bfloat16((acc[mi][ni][j] + bv) * scale);
      } else {  // MODE 4
        // FV[bh][dj][ks]: slot (d32+32*((s>>3)&1))*8 + (s&7), d on slot axis
        int dj = d0 >> 5, d32 = d0 & 31;
        int ks = s0 >> 4, hi2 = (s0 >> 3) & 1, e0 = s0 & 7;
        short4v o;
#pragma unroll
        for (int j = 0; j < 4; ++j) o[j] = f2b(acc[mi][ni][j] + bv);
        *(short4v*)(C + bhb + dj * 65536 + ks * 512 + (size_t)(d32 + 32 * hi2) * 8 + e0) = o;
      }
    }
  }
}

// Q prescale: (1/sqrt(64)) * log2(e) so attention uses exp2
static constexpr float QSCALE = 0.125f * 1.4426950408889634f;

__global__ __launch_bounds__(256) void qkv_gemm(const bf16* __restrict__ aib,
                                                const bf16* __restrict__ xb,
                                                const bf16* __restrict__ wqt,
                                                const bf16* __restrict__ wkt,
                                                const bf16* __restrict__ wvt,
                                                const float* __restrict__ bq,
                                                const float* __restrict__ bk,
                                                const float* __restrict__ bv,
                                                bf16* __restrict__ FQ, bf16* __restrict__ FK,
                                                bf16* __restrict__ FV) {
  int mt = blockIdx.x & 31;
  int nt = (blockIdx.x >> 5) & 7;
  int mat = blockIdx.x >> 8;
  if (mat == 0) {
    gemm128_body<3>(aib, wqt, bq, FQ, mt, nt, QSCALE);
  } else if (mat == 1) {
    gemm128_body<3>(aib, wkt, bk, FK, mt, nt, 1.0f);
  } else {
    gemm128_body<4>(xb, wvt, bv, FV, mt, nt, 1.0f);
  }
}

// ---------------- o_gemm: 64x128 tiles -> 512 blocks (2 blocks/CU) ----------
__global__ __launch_bounds__(256) void o_gemm64(const bf16* __restrict__ A,
                                                const bf16* __restrict__ Bt,
                                                const float* __restrict__ bias,
                                                float* __restrict__ out) {
  __shared__ alignas(16) bf16 Al[64 * 32];
  __shared__ alignas(16) bf16 Bl[128 * 32];
  const int mt = blockIdx.x & 63, nt = blockIdx.x >> 6;
  const int lane = threadIdx.x & 63, wv = threadIdx.x >> 6;
  const int wr = wv >> 1, wc = wv & 1;  // wave: 32 rows x 64 cols quadrant
  const bf16* Ab = A + (size_t)mt * 64 * DM;
  const bf16* Bb = Bt + (size_t)nt * 128 * DM;

  f32x4 acc[2][4];
#pragma unroll
  for (int i = 0; i < 2; ++i)
#pragma unroll
    for (int j = 0; j < 4; ++j) acc[i][j] = (f32x4){0.f, 0.f, 0.f, 0.f};

  for (int kt = 0; kt < DM / 32; ++kt) {
    int k0 = kt * 32;
    {  // A: 64x32 = 4KB, one chunk
      int li0 = wv * 64;
      int li = li0 + lane;
      int row = li >> 2, sl = li & 3;
      int gs = sl ^ ((row >> 1) & 3);
      __builtin_amdgcn_global_load_lds((const AS1 void*)(Ab + (size_t)row * DM + k0 + gs * 8),
                                       (AS3 void*)(&Al[li0 * 8]), 16, 0, 0);
    }
#pragma unroll
    for (int c = 0; c < 2; ++c) {  // B: 128x32 = 8KB, two chunks
      int li0 = wv * 64 + c * 256;
      int li = li0 + lane;
      int row = li >> 2, sl = li & 3;
      int gs = sl ^ ((row >> 1) & 3);
      __builtin_amdgcn_global_load_lds((const AS1 void*)(Bb + (size_t)row * DM + k0 + gs * 8),
                                       (AS3 void*)(&Bl[li0 * 8]), 16, 0, 0);
    }
    __syncthreads();

    short8 af[2], bfr[4];
    const int kb = lane >> 4;
#pragma unroll
    for (int mi = 0; mi < 2; ++mi) {
      int r = wr * 32 + mi * 16 + (lane & 15);
      af[mi] = *(const short8*)(&Al[r * 32 + ((kb ^ ((r >> 1) & 3)) << 3)]);
    }
#pragma unroll
    for (int ni = 0; ni < 4; ++ni) {
      int r = wc * 64 + ni * 16 + (lane & 15);
      bfr[ni] = *(const short8*)(&Bl[r * 32 + ((kb ^ ((r >> 1) & 3)) << 3)]);
    }
#pragma unroll
    for (int mi = 0; mi < 2; ++mi)
#pragma unroll
      for (int ni = 0; ni < 4; ++ni)
        acc[mi][ni] = __builtin_amdgcn_mfma_f32_16x16x32_bf16(af[mi], bfr[ni], acc[mi][ni], 0, 0, 0);
    __syncthreads();
  }

#pragma unroll
  for (int mi = 0; mi < 2; ++mi) {
#pragma unroll
    for (int ni = 0; ni < 4; ++ni) {
      int row0 = mt * 64 + wr * 32 + mi * 16 + (lane >> 4) * 4;
      int col = nt * 128 + wc * 64 + ni * 16 + (lane & 15);
      float bv = bias[col];
#pragma unroll
      for (int j = 0; j < 4; ++j)
        out[(size_t)(row0 + j) * DM + col] = acc[mi][ni][j] + bv;
    }
  }
}

// ---------------- flash attention: split-KV x2, swapped-QK^T ----------------
// 128-thread block = 2 waves on one (bh, q-tile); wave0 tiles [0,hsp), wave1
// [hsp,nt); exact merge via LDS. Fragment-major operands -> coalesced 1KB
// loads. Pipeline: K(t+1) issued after QK^T (1 tile of cover); V(t+1) issued
// after PV into the SAME vf buffer (dead after PV issues) -> V also gets a
// full tile of cover at zero VGPR cost. Counted vmcnt: drain K at 8, V at 8.
__global__ __launch_bounds__(128, 2) void flash_attn(const bf16* __restrict__ FQ,
                                                     const bf16* __restrict__ FK,
                                                     const bf16* __restrict__ FV,
                                                     bf16* __restrict__ Zb) {
  __shared__ float Zm[64][33];   // wave1 partial Z^T (padded)
  __shared__ float Ml[64], Ll[64];
  __shared__ unsigned Zl[32 * 32];  // wave0 final ZT->Z transpose

  const int lane = threadIdx.x & 63;
  const int wvi = threadIdx.x >> 6;
  const int qln = lane & 31;
  const bool hib = lane >= 32;
  const int bh = blockIdx.x & 31;           // bh%8 -> XCD affinity
  const int wq = 63 - (blockIdx.x >> 5);    // heavy blocks dispatch first
  const int bb = bh >> 4, h = bh & 15;
  const int q0 = wq * 32;
  const int nt = wq / 2 + 1;
  const int hsp = (nt + 1) >> 1;
  const int t0 = wvi ? hsp : 0;
  const int t1 = wvi ? nt : hsp;

  const size_t fb = (size_t)bh * 131072;
  const bf16* qp = FQ + fb + wq * 2048 + lane * 8;
  const bf16* kpt = FK + fb + (size_t)t0 * 4096 + lane * 8;
  const bf16* vp0 = FV + fb + (size_t)t0 * 2048 + lane * 8;
  const bf16* vp1 = vp0 + 65536;

  f32x16 zacc[2];
#pragma unroll
  for (int i = 0; i < 16; ++i) { zacc[0][i] = 0.f; zacc[1][i] = 0.f; }
  float mrun = -1e30f, lrun = 0.f;

  short8 qf[4];
  short8 kfA[2][4], kfB[2][4];
  short8 vf[2][4];  // single V buffer, prefetched one tile ahead

  if (t0 < t1) {
    // prologue: Q (4), K(t0) (8), V(t0) (8) — issue order matters for vmcnt
    GL16(qf[0], qp, 0); GL16(qf[1], qp, 1024); GL16(qf[2], qp, 2048); GL16(qf[3], qp, 3072);
    {
      const bf16* k1 = kpt + 2048;
      GL16(kfA[0][0], kpt, 0); GL16(kfA[0][1], kpt, 1024); GL16(kfA[0][2], kpt, 2048); GL16(kfA[0][3], kpt, 3072);
      GL16(kfA[1][0], k1, 0);  GL16(kfA[1][1], k1, 1024);  GL16(kfA[1][2], k1, 2048);  GL16(kfA[1][3], k1, 3072);
      kpt += 4096;
    }
    GL16(vf[0][0], vp0, 0); GL16(vf[0][1], vp0, 1024); GL16(vf[0][2], vp0, 2048); GL16(vf[0][3], vp0, 3072);
    GL16(vf[1][0], vp1, 0); GL16(vf[1][1], vp1, 1024); GL16(vf[1][2], vp1, 2048); GL16(vf[1][3], vp1, 3072);
    vp0 += 2048; vp1 += 2048;

    auto computeT = [&](short8(&kf)[2][4], short8(&kfn)[2][4], int t) {
      const int kv0 = t * 64;
      const bool pref = (t + 1 < t1);

      WAITV(8);  // drain K(t) (+Q on first tile); V(t)'s 8 stay in flight

      f32x16 s[2];
#pragma unroll
      for (int i = 0; i < 16; ++i) { s[0][i] = 0.f; s[1][i] = 0.f; }
      __builtin_amdgcn_s_setprio(1);
#pragma unroll
      for (int kc = 0; kc < 4; ++kc) {
        s[0] = __builtin_amdgcn_mfma_f32_32x32x16_bf16(kf[0][kc], qf[kc], s[0], 0, 0, 0);
        s[1] = __builtin_amdgcn_mfma_f32_32x32x16_bf16(kf[1][kc], qf[kc], s[1], 0, 0, 0);
      }
      __builtin_amdgcn_s_setprio(0);

      if (pref) {  // issue K(t+1) — covered by softmax + PV + next QK
        const bf16* k1 = kpt + 2048;
        GL16(kfn[0][0], kpt, 0); GL16(kfn[0][1], kpt, 1024); GL16(kfn[0][2], kpt, 2048); GL16(kfn[0][3], kpt, 3072);
        GL16(kfn[1][0], k1, 0);  GL16(kfn[1][1], k1, 1024);  GL16(kfn[1][2], k1, 2048);  GL16(kfn[1][3], k1, 3072);
        kpt += 4096;
      }

      if (t == nt - 1) {  // causal mask, diagonal tile only
        const int qg = q0 + qln;
#pragma unroll
        for (int ni = 0; ni < 2; ++ni)
#pragma unroll
          for (int rr = 0; rr < 16; ++rr) {
            int kv = kv0 + 32 * ni + (rr & 3) + 8 * (rr >> 2) + (hib ? 4 : 0);
            if (kv > qg) s[ni][rr] = -1e30f;
          }
      }

      // row max: in-register tree + cross-half swap
      float t8[8];
#pragma unroll
      for (int i = 0; i < 8; ++i)
        t8[i] = fmaxf(fmaxf(s[0][i], s[0][i + 8]), fmaxf(s[1][i], s[1][i + 8]));
      float tm = fmaxf(fmaxf(fmaxf(t8[0], t8[1]), fmaxf(t8[2], t8[3])),
                       fmaxf(fmaxf(t8[4], t8[5]), fmaxf(t8[6], t8[7])));
      tm = xmax32(tm);

      // defer-max (T13): rescale only when max grew by >8; P bounded by 2^8.
      if (__ballot(tm > mrun + 8.0f)) {
        float mn = fmaxf(mrun, tm);
        float al = fexp2(mrun - mn);
        mrun = mn;
        lrun *= al;
#pragma unroll
        for (int i = 0; i < 16; ++i) { zacc[0][i] *= al; zacc[1][i] *= al; }
      }

      float pacc[4] = {0.f, 0.f, 0.f, 0.f};
#pragma unroll
      for (int ni = 0; ni < 2; ++ni)
#pragma unroll
        for (int rr = 0; rr < 16; ++rr) {
          float p = fexp2(s[ni][rr] - mrun);
          s[ni][rr] = p;
          pacc[rr & 3] += p;
        }
      lrun += xsum32((pacc[0] + pacc[1]) + (pacc[2] + pacc[3]));

      // P -> bf16 B-fragments: pack pairs, permlane32_swap fills both halves
      unsigned su32[2][8];
#pragma unroll
      for (int ni = 0; ni < 2; ++ni)
#pragma unroll
        for (int tt = 0; tt < 8; ++tt)
          su32[ni][tt] = pack2(s[ni][2 * tt], s[ni][2 * tt + 1]);

      short8 pa[4];
#if __has_builtin(__builtin_amdgcn_permlane32_swap)
#pragma unroll
      for (int c = 0; c < 4; ++c) {
        int ni = c >> 1, b4 = 4 * (c & 1);
        uint2v r0 = __builtin_amdgcn_permlane32_swap(su32[ni][b4 + 0], su32[ni][b4 + 2], false, false);
        uint2v r1 = __builtin_amdgcn_permlane32_swap(su32[ni][b4 + 1], su32[ni][b4 + 3], false, false);
        U8 w;
        w.u[0] = r0[0]; w.u[1] = r1[0]; w.u[2] = r0[1]; w.u[3] = r1[1];
        pa[c] = w.s;
      }
#else
      unsigned X[2][8];
#pragma unroll
      for (int ni = 0; ni < 2; ++ni)
#pragma unroll
        for (int tt = 0; tt < 8; ++tt)
          X[ni][tt] = (unsigned)__shfl_xor((int)su32[ni][tt], 32);
#pragma unroll
      for (int c = 0; c < 4; ++c) {
        int ni = c >> 1, b4 = 4 * (c & 1);
        U8 w;
        w.u[0] = hib ? X[ni][b4 + 2] : su32[ni][b4 + 0];
        w.u[1] = hib ? X[ni][b4 + 3] : su32[ni][b4 + 1];
        w.u[2] = hib ? su32[ni][b4 + 2] : X[ni][b4 + 0];
        w.u[3] = hib ? su32[ni][b4 + 3] : X[ni][b4 + 1];
        pa[c] = w.s;
      }
#endif

      if (pref) { WAITV(8); } else { WAITV(0); }  // drain V(t); K(t+1) in flight

      __builtin_amdgcn_s_setprio(1);
#pragma unroll
      for (int c = 0; c < 4; ++c) {
        zacc[0] = __builtin_amdgcn_mfma_f32_32x32x16_bf16(vf[0][c], pa[c], zacc[0], 0, 0, 0);
        zacc[1] = __builtin_amdgcn_mfma_f32_32x32x16_bf16(vf[1][c], pa[c], zacc[1], 0, 0, 0);
      }
      __builtin_amdgcn_s_setprio(0);
      __builtin_amdgcn_sched_barrier(0);  // keep V(t+1) issue below the PV MFMAs

      if (pref) {  // issue V(t+1) into vf (dead after PV issue) — full-tile cover
        GL16(vf[0][0], vp0, 0); GL16(vf[0][1], vp0, 1024); GL16(vf[0][2], vp0, 2048); GL16(vf[0][3], vp0, 3072);
        GL16(vf[1][0], vp1, 0); GL16(vf[1][1], vp1, 1024); GL16(vf[1][2], vp1, 2048); GL16(vf[1][3], vp1, 3072);
        vp0 += 2048; vp1 += 2048;
      }
    };

    int t = t0;
    while (true) {
      computeT(kfA, kfB, t);
      if (++t >= t1) break;
      computeT(kfB, kfA, t);
      if (++t >= t1) break;
    }
  }

  // ---- merge wave1 into wave0 (exact online-softmax combine) ----
  if (wvi == 1) {
#pragma unroll
    for (int i = 0; i < 16; ++i) {
      Zm[lane][i] = zacc[0][i];
      Zm[lane][16 + i] = zacc[1][i];
    }
    Ml[lane] = mrun;
    Ll[lane] = lrun;
  }
  __syncthreads();
  if (wvi == 0) {
    float m1 = Ml[lane], l1 = Ll[lane];
    float mn = fmaxf(mrun, m1);
    float a0 = fexp2(mrun - mn);
    float a1 = fexp2(m1 - mn);
    float lm = lrun * a0 + l1 * a1;
#pragma unroll
    for (int i = 0; i < 16; ++i) {
      zacc[0][i] = zacc[0][i] * a0 + Zm[lane][i] * a1;
      zacc[1][i] = zacc[1][i] * a0 + Zm[lane][16 + i] * a1;
    }

    // normalize + transpose Z^T -> Z via swizzled LDS, coalesced store
    const float rl = 1.0f / lm;
    const int W8[8] = {0, 1, 4, 5, 8, 9, 12, 13};
#pragma unroll
    for (int dj = 0; dj < 2; ++dj)
#pragma unroll
      for (int tt = 0; tt < 8; ++tt) {
        unsigned v = pack2(zacc[dj][2 * tt] * rl, zacc[dj][2 * tt + 1] * rl);
        int x = 16 * dj + (hib ? 2 : 0) + W8[tt];
        Zl[qln * 32 + (((x >> 2) ^ (qln & 7)) << 2) + (x & 3)] = v;
      }
    asm volatile("s_waitcnt lgkmcnt(0)" ::: "memory");
    __builtin_amdgcn_sched_barrier(0);
    const size_t base = ((size_t)bb * SEQ) * DM + h * DHD;
    int q2 = lane >> 1, hf = lane & 1;
#pragma unroll
    for (int u = 0; u < 4; ++u) {
      int sl = (hf * 4 + u) ^ (q2 & 7);
      U8 w;
      w.u = *(const uint4v*)&Zl[q2 * 32 + sl * 4];
      *(short8*)(Zb + base + (size_t)(q0 + q2) * DM + hf * 32 + u * 8) = w.s;
    }
  }
}

extern "C" void kernel_launch(void* const* d_in, const int* in_sizes, int n_in,
                              void* d_out, int out_size, void* d_ws, size_t ws_size,
                              hipStream_t stream) {
  (void)in_sizes; (void)n_in; (void)out_size; (void)ws_size;
  const float* x = (const float*)d_in[0];
  const float* pos = (const float*)d_in[1];
  const float* WQ = (const float*)d_in[2];
  const float* bQ = (const float*)d_in[3];
  const float* WK = (const float*)d_in[4];
  const float* bK = (const float*)d_in[5];
  const float* WV = (const float*)d_in[6];
  const float* bV = (const float*)d_in[7];
  const float* WO = (const float*)d_in[8];
  const float* bO = (const float*)d_in[9];
  float* out = (float*)d_out;

  bf16* ws = (bf16*)d_ws;
  size_t off = 0;
  bf16* aib = ws + off; off += (size_t)MROWS * DM;
  bf16* xb  = ws + off; off += (size_t)MROWS * DM;
  bf16* wqt = ws + off; off += (size_t)DM * DM;
  bf16* wkt = ws + off; off += (size_t)DM * DM;
  bf16* wvt = ws + off; off += (size_t)DM * DM;
  bf16* wot = ws + off; off += (size_t)DM * DM;
  bf16* FQ  = ws + off; off += (size_t)MROWS * DM;  // fragment-major [bh][g][kc]
  bf16* FK  = ws + off; off += (size_t)MROWS * DM;
  bf16* FV  = ws + off; off += (size_t)MROWS * DM;  // fragment-major [bh][dj][ks]
  bf16* Zb  = ws + off; off += (size_t)MROWS * DM;

  prep_inputs<<<(MROWS * DM / 4 + 255) / 256, 256, 0, stream>>>(x, pos, xb, aib);
  dim3 g3(1, 16, 48);
  transpose_w3<<<g3, 256, 0, stream>>>(WQ, WK, WV, wqt, wkt, wvt);
  dim3 go(16, 16, 1);
  transpose_w<<<go, 256, 0, stream>>>(WO, wot, 1024, 1024);
  qkv_gemm<<<768, 256, 0, stream>>>(aib, xb, wqt, wkt, wvt, bQ, bK, bV, FQ, FK, FV);
  flash_attn<<<2048, 128, 0, stream>>>(FQ, FK, FV, Zb);
  o_gemm64<<<512, 256, 0, stream>>>(Zb, wot, bO, out);
}

// Round 14
// 107.024 us; speedup vs baseline: 1.1149x; 1.0260x over previous
//
#include <hip/hip_runtime.h>
#include <hip/hip_bf16.h>
#include <stdint.h>

typedef __hip_bfloat16 bf16;
typedef __attribute__((ext_vector_type(8))) short short8;
typedef __attribute__((ext_vector_type(4))) short short4v;
typedef __attribute__((ext_vector_type(4))) float f32x4;
typedef __attribute__((ext_vector_type(16))) float f32x16;
typedef __attribute__((ext_vector_type(4))) unsigned uint4v;
typedef __attribute__((ext_vector_type(2))) unsigned uint2v;

#define AS1 __attribute__((address_space(1)))
#define AS3 __attribute__((address_space(3)))

static constexpr int SEQ = 2048, DM = 1024, DHD = 64;
static constexpr int MROWS = 2 * SEQ;  // 4096

__device__ __forceinline__ short f2b(float f) {
  __hip_bfloat16 h = __float2bfloat16(f);
  return *reinterpret_cast<short*>(&h);
}

__device__ __forceinline__ unsigned pack2(float lo, float hi) {
  float2 fv; fv.x = lo; fv.y = hi;
  union { __hip_bfloat162 h; unsigned u; } cv;
  cv.h = __float22bfloat162_rn(fv);
  return cv.u;
}

// raw v_exp_f32 (1-inst exp2) — libm exp2f carries range-check bloat
__device__ __forceinline__ float fexp2(float x) {
#if __has_builtin(__builtin_amdgcn_exp2f)
  return __builtin_amdgcn_exp2f(x);
#else
  return exp2f(x);
#endif
}

union U8 { uint4v u; short8 s; };

// volatile asm 16B global load with literal byte offset — cannot be sunk/reordered
#define GL16(dst, ptr, off) \
  asm volatile("global_load_dwordx4 %0, %1, off offset:" #off : "=v"(dst) : "v"(ptr))
// counted wait + scheduling fence (rule #18)
#define WAITV(n) do { asm volatile("s_waitcnt vmcnt(" #n ")"); __builtin_amdgcn_sched_barrier(0); } while (0)

__device__ __forceinline__ float xmax32(float v) {
#if __has_builtin(__builtin_amdgcn_permlane32_swap)
  uint2v r = __builtin_amdgcn_permlane32_swap(__float_as_uint(v), __float_as_uint(v), false, false);
  return fmaxf(__uint_as_float(r[0]), __uint_as_float(r[1]));
#else
  return fmaxf(v, __shfl_xor(v, 32));
#endif
}
__device__ __forceinline__ float xsum32(float v) {
#if __has_builtin(__builtin_amdgcn_permlane32_swap)
  uint2v r = __builtin_amdgcn_permlane32_swap(__float_as_uint(v), __float_as_uint(v), false, false);
  return __uint_as_float(r[0]) + __uint_as_float(r[1]);
#else
  return v + __shfl_xor(v, 32);
#endif
}

// ---------------- prep: x -> bf16, x+pos -> bf16 ----------------
__global__ __launch_bounds__(256) void prep_inputs(const float* __restrict__ x,
                                                   const float* __restrict__ pos,
                                                   bf16* __restrict__ xb,
                                                   bf16* __restrict__ aib) {
  int i = blockIdx.x * 256 + threadIdx.x;
  const int n4 = MROWS * DM / 4;
  if (i >= n4) return;
  f32x4 xv = ((const f32x4*)x)[i];
  f32x4 pv = ((const f32x4*)pos)[i];
  short4v xo, ao;
#pragma unroll
  for (int j = 0; j < 4; ++j) {
    xo[j] = f2b(xv[j]);
    ao[j] = f2b(xv[j] + pv[j]);
  }
  ((short4v*)xb)[i] = xo;
  ((short4v*)aib)[i] = ao;
}

// ---------------- weight transpose: [R][C] f32 -> [C][R] bf16 (per z-slice) --
__global__ __launch_bounds__(256) void transpose_w(const float* __restrict__ in,
                                                   bf16* __restrict__ out, int R, int C) {
  __shared__ float t[64][65];
  int ct = blockIdx.x, rt = blockIdx.y, z = blockIdx.z;
  in += (size_t)z * R * C;
  out += (size_t)z * R * C;
  int c = threadIdx.x & 63, g = threadIdx.x >> 6;
#pragma unroll
  for (int j = 0; j < 16; ++j) {
    int r = g * 16 + j;
    t[r][c] = in[(size_t)(rt * 64 + r) * C + (ct * 64 + c)];
  }
  __syncthreads();
#pragma unroll
  for (int j = 0; j < 16; ++j) {
    int rr = g * 16 + j;
    out[(size_t)(ct * 64 + rr) * R + (rt * 64 + c)] = __float2bfloat16(t[c][rr]);
  }
}

// combined QKV weight transpose: z 0..47 selects WQ/WK/WV head-slice
__global__ __launch_bounds__(256) void transpose_w3(const float* __restrict__ wq,
                                                    const float* __restrict__ wk,
                                                    const float* __restrict__ wv,
                                                    bf16* __restrict__ oq,
                                                    bf16* __restrict__ ok,
                                                    bf16* __restrict__ ov) {
  __shared__ float t[64][65];
  const int R = 1024, C = 64;
  int rt = blockIdx.y, z = blockIdx.z;
  const float* in = (z < 16) ? wq : (z < 32) ? wk : wv;
  bf16* out = (z < 16) ? oq : (z < 32) ? ok : ov;
  int zz = z & 15;
  in += (size_t)zz * R * C;
  out += (size_t)zz * R * C;
  int c = threadIdx.x & 63, g = threadIdx.x >> 6;
#pragma unroll
  for (int j = 0; j < 16; ++j) {
    int r = g * 16 + j;
    t[r][c] = in[(size_t)(rt * 64 + r) * C + c];
  }
  __syncthreads();
#pragma unroll
  for (int j = 0; j < 16; ++j) {
    int rr = g * 16 + j;
    out[(size_t)rr * R + (rt * 64 + c)] = __float2bfloat16(t[c][rr]);
  }
}

// ---------------- 128x128 GEMM body, BK=32 (round-9 proven config) ----------
// MODE 3: bf16 fragment-major FQ/FK. MODE 4: fragment-major FV.
template <int MODE>
__device__ __forceinline__ void gemm128_body(const bf16* __restrict__ A,
                                             const bf16* __restrict__ Bt,
                                             const float* __restrict__ bias,
                                             bf16* __restrict__ C, int mt, int nt,
                                             float scale) {
  __shared__ alignas(16) bf16 Al[128 * 32];
  __shared__ alignas(16) bf16 Bl[128 * 32];
  const int lane = threadIdx.x & 63, wv = threadIdx.x >> 6;
  const int wr = wv >> 1, wc = wv & 1;
  const bf16* Ab = A + (size_t)mt * 128 * DM;
  const bf16* Bb = Bt + (size_t)nt * 128 * DM;

  f32x4 acc[4][4];
#pragma unroll
  for (int i = 0; i < 4; ++i)
#pragma unroll
    for (int j = 0; j < 4; ++j) acc[i][j] = (f32x4){0.f, 0.f, 0.f, 0.f};

  for (int kt = 0; kt < DM / 32; ++kt) {
    int k0 = kt * 32;
#pragma unroll
    for (int c = 0; c < 2; ++c) {
      int li0 = wv * 64 + c * 256;
      int li = li0 + lane;
      int row = li >> 2, sl = li & 3;
      int gs = sl ^ ((row >> 1) & 3);
      __builtin_amdgcn_global_load_lds((const AS1 void*)(Ab + (size_t)row * DM + k0 + gs * 8),
                                       (AS3 void*)(&Al[li0 * 8]), 16, 0, 0);
    }
#pragma unroll
    for (int c = 0; c < 2; ++c) {
      int li0 = wv * 64 + c * 256;
      int li = li0 + lane;
      int row = li >> 2, sl = li & 3;
      int gs = sl ^ ((row >> 1) & 3);
      __builtin_amdgcn_global_load_lds((const AS1 void*)(Bb + (size_t)row * DM + k0 + gs * 8),
                                       (AS3 void*)(&Bl[li0 * 8]), 16, 0, 0);
    }
    __syncthreads();

    short8 af[4], bfr[4];
    const int kb = lane >> 4;
#pragma unroll
    for (int mi = 0; mi < 4; ++mi) {
      int r = wr * 64 + mi * 16 + (lane & 15);
      af[mi] = *(const short8*)(&Al[r * 32 + ((kb ^ ((r >> 1) & 3)) << 3)]);
    }
#pragma unroll
    for (int ni = 0; ni < 4; ++ni) {
      int r = wc * 64 + ni * 16 + (lane & 15);
      bfr[ni] = *(const short8*)(&Bl[r * 32 + ((kb ^ ((r >> 1) & 3)) << 3)]);
    }
#pragma unroll
    for (int mi = 0; mi < 4; ++mi)
#pragma unroll
      for (int ni = 0; ni < 4; ++ni)
        acc[mi][ni] = __builtin_amdgcn_mfma_f32_16x16x32_bf16(af[mi], bfr[ni], acc[mi][ni], 0, 0, 0);
    __syncthreads();
  }

#pragma unroll
  for (int mi = 0; mi < 4; ++mi) {
#pragma unroll
    for (int ni = 0; ni < 4; ++ni) {
      int row0 = mt * 128 + wr * 64 + mi * 16 + (lane >> 4) * 4;
      int col = nt * 128 + wc * 64 + ni * 16 + (lane & 15);
      float bv = bias[col];
      int bb = row0 >> 11, s0 = row0 & 2047;
      int hh = col >> 6, d0 = col & 63;
      size_t bhb = (size_t)(bb * 16 + hh) * 131072;
      if constexpr (MODE == 3) {
        // FQ/FK[bh][g][kc]: slot (r32+32*hi)*8 + e, from row s, col d0
        int kc = d0 >> 4, hi = (d0 >> 3) & 1, e = d0 & 7;
        int g = s0 >> 5, r0 = s0 & 31;
        size_t bbase = bhb + g * 2048 + kc * 512 + e;
#pragma unroll
        for (int j = 0; j < 4; ++j)
          C[bbase + (size_t)(r0 + j + 32 * hi) * 8] =
              __float2bfloat16((acc[mi][ni][j] + bv) * scale);
      } else {  // MODE 4
        // FV[bh][dj][ks]: slot (d32+32*((s>>3)&1))*8 + (s&7), d on slot axis
        int dj = d0 >> 5, d32 = d0 & 31;
        int ks = s0 >> 4, hi2 = (s0 >> 3) & 1, e0 = s0 & 7;
        short4v o;
#pragma unroll
        for (int j = 0; j < 4; ++j) o[j] = f2b(acc[mi][ni][j] + bv);
        *(short4v*)(C + bhb + dj * 65536 + ks * 512 + (size_t)(d32 + 32 * hi2) * 8 + e0) = o;
      }
    }
  }
}

// Q prescale: (1/sqrt(64)) * log2(e) so attention uses exp2
static constexpr float QSCALE = 0.125f * 1.4426950408889634f;

__global__ __launch_bounds__(256) void qkv_gemm(const bf16* __restrict__ aib,
                                                const bf16* __restrict__ xb,
                                                const bf16* __restrict__ wqt,
                                                const bf16* __restrict__ wkt,
                                                const bf16* __restrict__ wvt,
                                                const float* __restrict__ bq,
                                                const float* __restrict__ bk,
                                                const float* __restrict__ bv,
                                                bf16* __restrict__ FQ, bf16* __restrict__ FK,
                                                bf16* __restrict__ FV) {
  int mt = blockIdx.x & 31;
  int nt = (blockIdx.x >> 5) & 7;
  int mat = blockIdx.x >> 8;
  if (mat == 0) {
    gemm128_body<3>(aib, wqt, bq, FQ, mt, nt, QSCALE);
  } else if (mat == 1) {
    gemm128_body<3>(aib, wkt, bk, FK, mt, nt, 1.0f);
  } else {
    gemm128_body<4>(xb, wvt, bv, FV, mt, nt, 1.0f);
  }
}

// ---------------- o_gemm: 64x128 tiles, BK=64 -> 512 blocks (2/CU) ----------
// Occupancy is GRID-capped at 2 blocks/CU, so 24KB LDS is free; BK=64 halves
// the vmcnt(0)+barrier drains and doubles MFMA per barrier pair (16/wave).
__global__ __launch_bounds__(256) void o_gemm64(const bf16* __restrict__ A,
                                                const bf16* __restrict__ Bt,
                                                const float* __restrict__ bias,
                                                float* __restrict__ out) {
  __shared__ alignas(16) bf16 Al[64 * 64];    // 8 KB
  __shared__ alignas(16) bf16 Bl[128 * 64];   // 16 KB
  const int mt = blockIdx.x & 63, nt = blockIdx.x >> 6;
  const int lane = threadIdx.x & 63, wv = threadIdx.x >> 6;
  const int wr = wv >> 1, wc = wv & 1;  // wave: 32 rows x 64 cols quadrant
  const bf16* Ab = A + (size_t)mt * 64 * DM;
  const bf16* Bb = Bt + (size_t)nt * 128 * DM;

  f32x4 acc[2][4];
#pragma unroll
  for (int i = 0; i < 2; ++i)
#pragma unroll
    for (int j = 0; j < 4; ++j) acc[i][j] = (f32x4){0.f, 0.f, 0.f, 0.f};

  for (int kt = 0; kt < DM / 64; ++kt) {
    int k0 = kt * 64;
#pragma unroll
    for (int c = 0; c < 2; ++c) {  // A: 64x64 = 8KB, two passes
      int li0 = wv * 64 + c * 256;
      int li = li0 + lane;
      int row = li >> 3, sl = li & 7;
      int gs = sl ^ (row & 7);
      __builtin_amdgcn_global_load_lds((const AS1 void*)(Ab + (size_t)row * DM + k0 + gs * 8),
                                       (AS3 void*)(&Al[li0 * 8]), 16, 0, 0);
    }
#pragma unroll
    for (int c = 0; c < 4; ++c) {  // B: 128x64 = 16KB, four passes
      int li0 = wv * 64 + c * 256;
      int li = li0 + lane;
      int row = li >> 3, sl = li & 7;
      int gs = sl ^ (row & 7);
      __builtin_amdgcn_global_load_lds((const AS1 void*)(Bb + (size_t)row * DM + k0 + gs * 8),
                                       (AS3 void*)(&Bl[li0 * 8]), 16, 0, 0);
    }
    __syncthreads();

    short8 af[2][2], bfr[2][4];
    const int kb = lane >> 4;
#pragma unroll
    for (int kk = 0; kk < 2; ++kk) {
#pragma unroll
      for (int mi = 0; mi < 2; ++mi) {
        int r = wr * 32 + mi * 16 + (lane & 15);
        af[kk][mi] = *(const short8*)(&Al[r * 64 + (((kb + 4 * kk) ^ (r & 7)) << 3)]);
      }
#pragma unroll
      for (int ni = 0; ni < 4; ++ni) {
        int r = wc * 64 + ni * 16 + (lane & 15);
        bfr[kk][ni] = *(const short8*)(&Bl[r * 64 + (((kb + 4 * kk) ^ (r & 7)) << 3)]);
      }
    }
#pragma unroll
    for (int kk = 0; kk < 2; ++kk)
#pragma unroll
      for (int mi = 0; mi < 2; ++mi)
#pragma unroll
        for (int ni = 0; ni < 4; ++ni)
          acc[mi][ni] = __builtin_amdgcn_mfma_f32_16x16x32_bf16(af[kk][mi], bfr[kk][ni], acc[mi][ni], 0, 0, 0);
    __syncthreads();
  }

#pragma unroll
  for (int mi = 0; mi < 2; ++mi) {
#pragma unroll
    for (int ni = 0; ni < 4; ++ni) {
      int row0 = mt * 64 + wr * 32 + mi * 16 + (lane >> 4) * 4;
      int col = nt * 128 + wc * 64 + ni * 16 + (lane & 15);
      float bv = bias[col];
#pragma unroll
      for (int j = 0; j < 4; ++j)
        out[(size_t)(row0 + j) * DM + col] = acc[mi][ni][j] + bv;
    }
  }
}

// ---------------- flash attention: split-KV x2, swapped-QK^T ----------------
// 128-thread block = 2 waves on one (bh, q-tile); wave0 tiles [0,hsp), wave1
// [hsp,nt); exact merge via LDS. Fragment-major operands -> coalesced 1KB
// loads. K(t+1) issued after QK^T; V(t+1) issued after PV into the same vf
// buffer. Counted vmcnt: drain K at 8, V at 8.
__global__ __launch_bounds__(128, 2) void flash_attn(const bf16* __restrict__ FQ,
                                                     const bf16* __restrict__ FK,
                                                     const bf16* __restrict__ FV,
                                                     bf16* __restrict__ Zb) {
  __shared__ float Zm[64][33];   // wave1 partial Z^T (padded)
  __shared__ float Ml[64], Ll[64];
  __shared__ unsigned Zl[32 * 32];  // wave0 final ZT->Z transpose

  const int lane = threadIdx.x & 63;
  const int wvi = threadIdx.x >> 6;
  const int qln = lane & 31;
  const bool hib = lane >= 32;
  const int bh = blockIdx.x & 31;           // bh%8 -> XCD affinity
  const int wq = 63 - (blockIdx.x >> 5);    // heavy blocks dispatch first
  const int bb = bh >> 4, h = bh & 15;
  const int q0 = wq * 32;
  const int nt = wq / 2 + 1;
  const int hsp = (nt + 1) >> 1;
  const int t0 = wvi ? hsp : 0;
  const int t1 = wvi ? nt : hsp;

  const size_t fb = (size_t)bh * 131072;
  const bf16* qp = FQ + fb + wq * 2048 + lane * 8;
  const bf16* kpt = FK + fb + (size_t)t0 * 4096 + lane * 8;
  const bf16* vp0 = FV + fb + (size_t)t0 * 2048 + lane * 8;
  const bf16* vp1 = vp0 + 65536;

  f32x16 zacc[2];
#pragma unroll
  for (int i = 0; i < 16; ++i) { zacc[0][i] = 0.f; zacc[1][i] = 0.f; }
  float mrun = -1e30f, lrun = 0.f;

  short8 qf[4];
  short8 kfA[2][4], kfB[2][4];
  short8 vf[2][4];  // single V buffer, prefetched one tile ahead

  if (t0 < t1) {
    // prologue: Q (4), K(t0) (8), V(t0) (8) — issue order matters for vmcnt
    GL16(qf[0], qp, 0); GL16(qf[1], qp, 1024); GL16(qf[2], qp, 2048); GL16(qf[3], qp, 3072);
    {
      const bf16* k1 = kpt + 2048;
      GL16(kfA[0][0], kpt, 0); GL16(kfA[0][1], kpt, 1024); GL16(kfA[0][2], kpt, 2048); GL16(kfA[0][3], kpt, 3072);
      GL16(kfA[1][0], k1, 0);  GL16(kfA[1][1], k1, 1024);  GL16(kfA[1][2], k1, 2048);  GL16(kfA[1][3], k1, 3072);
      kpt += 4096;
    }
    GL16(vf[0][0], vp0, 0); GL16(vf[0][1], vp0, 1024); GL16(vf[0][2], vp0, 2048); GL16(vf[0][3], vp0, 3072);
    GL16(vf[1][0], vp1, 0); GL16(vf[1][1], vp1, 1024); GL16(vf[1][2], vp1, 2048); GL16(vf[1][3], vp1, 3072);
    vp0 += 2048; vp1 += 2048;

    auto computeT = [&](short8(&kf)[2][4], short8(&kfn)[2][4], int t) {
      const int kv0 = t * 64;
      const bool pref = (t + 1 < t1);

      WAITV(8);  // drain K(t) (+Q on first tile); V(t)'s 8 stay in flight

      f32x16 s[2];
#pragma unroll
      for (int i = 0; i < 16; ++i) { s[0][i] = 0.f; s[1][i] = 0.f; }
      __builtin_amdgcn_s_setprio(1);
#pragma unroll
      for (int kc = 0; kc < 4; ++kc) {
        s[0] = __builtin_amdgcn_mfma_f32_32x32x16_bf16(kf[0][kc], qf[kc], s[0], 0, 0, 0);
        s[1] = __builtin_amdgcn_mfma_f32_32x32x16_bf16(kf[1][kc], qf[kc], s[1], 0, 0, 0);
      }
      __builtin_amdgcn_s_setprio(0);

      if (pref) {  // issue K(t+1) — covered by softmax + PV + next QK
        const bf16* k1 = kpt + 2048;
        GL16(kfn[0][0], kpt, 0); GL16(kfn[0][1], kpt, 1024); GL16(kfn[0][2], kpt, 2048); GL16(kfn[0][3], kpt, 3072);
        GL16(kfn[1][0], k1, 0);  GL16(kfn[1][1], k1, 1024);  GL16(kfn[1][2], k1, 2048);  GL16(kfn[1][3], k1, 3072);
        kpt += 4096;
      }

      if (t == nt - 1) {  // causal mask, diagonal tile only
        const int qg = q0 + qln;
#pragma unroll
        for (int ni = 0; ni < 2; ++ni)
#pragma unroll
          for (int rr = 0; rr < 16; ++rr) {
            int kv = kv0 + 32 * ni + (rr & 3) + 8 * (rr >> 2) + (hib ? 4 : 0);
            if (kv > qg) s[ni][rr] = -1e30f;
          }
      }

      // row max: in-register tree + cross-half swap
      float t8[8];
#pragma unroll
      for (int i = 0; i < 8; ++i)
        t8[i] = fmaxf(fmaxf(s[0][i], s[0][i + 8]), fmaxf(s[1][i], s[1][i + 8]));
      float tm = fmaxf(fmaxf(fmaxf(t8[0], t8[1]), fmaxf(t8[2], t8[3])),
                       fmaxf(fmaxf(t8[4], t8[5]), fmaxf(t8[6], t8[7])));
      tm = xmax32(tm);

      // defer-max (T13): rescale only when max grew by >8; P bounded by 2^8.
      if (__ballot(tm > mrun + 8.0f)) {
        float mn = fmaxf(mrun, tm);
        float al = fexp2(mrun - mn);
        mrun = mn;
        lrun *= al;
#pragma unroll
        for (int i = 0; i < 16; ++i) { zacc[0][i] *= al; zacc[1][i] *= al; }
      }

      float pacc[4] = {0.f, 0.f, 0.f, 0.f};
#pragma unroll
      for (int ni = 0; ni < 2; ++ni)
#pragma unroll
        for (int rr = 0; rr < 16; ++rr) {
          float p = fexp2(s[ni][rr] - mrun);
          s[ni][rr] = p;
          pacc[rr & 3] += p;
        }
      lrun += xsum32((pacc[0] + pacc[1]) + (pacc[2] + pacc[3]));

      // P -> bf16 B-fragments: pack pairs, permlane32_swap fills both halves
      unsigned su32[2][8];
#pragma unroll
      for (int ni = 0; ni < 2; ++ni)
#pragma unroll
        for (int tt = 0; tt < 8; ++tt)
          su32[ni][tt] = pack2(s[ni][2 * tt], s[ni][2 * tt + 1]);

      short8 pa[4];
#if __has_builtin(__builtin_amdgcn_permlane32_swap)
#pragma unroll
      for (int c = 0; c < 4; ++c) {
        int ni = c >> 1, b4 = 4 * (c & 1);
        uint2v r0 = __builtin_amdgcn_permlane32_swap(su32[ni][b4 + 0], su32[ni][b4 + 2], false, false);
        uint2v r1 = __builtin_amdgcn_permlane32_swap(su32[ni][b4 + 1], su32[ni][b4 + 3], false, false);
        U8 w;
        w.u[0] = r0[0]; w.u[1] = r1[0]; w.u[2] = r0[1]; w.u[3] = r1[1];
        pa[c] = w.s;
      }
#else
      unsigned X[2][8];
#pragma unroll
      for (int ni = 0; ni < 2; ++ni)
#pragma unroll
        for (int tt = 0; tt < 8; ++tt)
          X[ni][tt] = (unsigned)__shfl_xor((int)su32[ni][tt], 32);
#pragma unroll
      for (int c = 0; c < 4; ++c) {
        int ni = c >> 1, b4 = 4 * (c & 1);
        U8 w;
        w.u[0] = hib ? X[ni][b4 + 2] : su32[ni][b4 + 0];
        w.u[1] = hib ? X[ni][b4 + 3] : su32[ni][b4 + 1];
        w.u[2] = hib ? su32[ni][b4 + 2] : X[ni][b4 + 0];
        w.u[3] = hib ? su32[ni][b4 + 3] : X[ni][b4 + 1];
        pa[c] = w.s;
      }
#endif

      if (pref) { WAITV(8); } else { WAITV(0); }  // drain V(t); K(t+1) in flight

      __builtin_amdgcn_s_setprio(1);
#pragma unroll
      for (int c = 0; c < 4; ++c) {
        zacc[0] = __builtin_amdgcn_mfma_f32_32x32x16_bf16(vf[0][c], pa[c], zacc[0], 0, 0, 0);
        zacc[1] = __builtin_amdgcn_mfma_f32_32x32x16_bf16(vf[1][c], pa[c], zacc[1], 0, 0, 0);
      }
      __builtin_amdgcn_s_setprio(0);
      __builtin_amdgcn_sched_barrier(0);  // keep V(t+1) issue below the PV MFMAs

      if (pref) {  // issue V(t+1) into vf (dead after PV issue) — full-tile cover
        GL16(vf[0][0], vp0, 0); GL16(vf[0][1], vp0, 1024); GL16(vf[0][2], vp0, 2048); GL16(vf[0][3], vp0, 3072);
        GL16(vf[1][0], vp1, 0); GL16(vf[1][1], vp1, 1024); GL16(vf[1][2], vp1, 2048); GL16(vf[1][3], vp1, 3072);
        vp0 += 2048; vp1 += 2048;
      }
    };

    int t = t0;
    while (true) {
      computeT(kfA, kfB, t);
      if (++t >= t1) break;
      computeT(kfB, kfA, t);
      if (++t >= t1) break;
    }
  }

  // ---- merge wave1 into wave0 (exact online-softmax combine) ----
  if (wvi == 1) {
#pragma unroll
    for (int i = 0; i < 16; ++i) {
      Zm[lane][i] = zacc[0][i];
      Zm[lane][16 + i] = zacc[1][i];
    }
    Ml[lane] = mrun;
    Ll[lane] = lrun;
  }
  __syncthreads();
  if (wvi == 0) {
    float m1 = Ml[lane], l1 = Ll[lane];
    float mn = fmaxf(mrun, m1);
    float a0 = fexp2(mrun - mn);
    float a1 = fexp2(m1 - mn);
    float lm = lrun * a0 + l1 * a1;
#pragma unroll
    for (int i = 0; i < 16; ++i) {
      zacc[0][i] = zacc[0][i] * a0 + Zm[lane][i] * a1;
      zacc[1][i] = zacc[1][i] * a0 + Zm[lane][16 + i] * a1;
    }

    // normalize + transpose Z^T -> Z via swizzled LDS, coalesced store
    const float rl = 1.0f / lm;
    const int W8[8] = {0, 1, 4, 5, 8, 9, 12, 13};
#pragma unroll
    for (int dj = 0; dj < 2; ++dj)
#pragma unroll
      for (int tt = 0; tt < 8; ++tt) {
        unsigned v = pack2(zacc[dj][2 * tt] * rl, zacc[dj][2 * tt + 1] * rl);
        int x = 16 * dj + (hib ? 2 : 0) + W8[tt];
        Zl[qln * 32 + (((x >> 2) ^ (qln & 7)) << 2) + (x & 3)] = v;
      }
    asm volatile("s_waitcnt lgkmcnt(0)" ::: "memory");
    __builtin_amdgcn_sched_barrier(0);
    const size_t base = ((size_t)bb * SEQ) * DM + h * DHD;
    int q2 = lane >> 1, hf = lane & 1;
#pragma unroll
    for (int u = 0; u < 4; ++u) {
      int sl = (hf * 4 + u) ^ (q2 & 7);
      U8 w;
      w.u = *(const uint4v*)&Zl[q2 * 32 + sl * 4];
      *(short8*)(Zb + base + (size_t)(q0 + q2) * DM + hf * 32 + u * 8) = w.s;
    }
  }
}

extern "C" void kernel_launch(void* const* d_in, const int* in_sizes, int n_in,
                              void* d_out, int out_size, void* d_ws, size_t ws_size,
                              hipStream_t stream) {
  (void)in_sizes; (void)n_in; (void)out_size; (void)ws_size;
  const float* x = (const float*)d_in[0];
  const float* pos = (const float*)d_in[1];
  const float* WQ = (const float*)d_in[2];
  const float* bQ = (const float*)d_in[3];
  const float* WK = (const float*)d_in[4];
  const float* bK = (const float*)d_in[5];
  const float* WV = (const float*)d_in[6];
  const float* bV = (const float*)d_in[7];
  const float* WO = (const float*)d_in[8];
  const float* bO = (const float*)d_in[9];
  float* out = (float*)d_out;

  bf16* ws = (bf16*)d_ws;
  size_t off = 0;
  bf16* aib = ws + off; off += (size_t)MROWS * DM;
  bf16* xb  = ws + off; off += (size_t)MROWS * DM;
  bf16* wqt = ws + off; off += (size_t)DM * DM;
  bf16* wkt = ws + off; off += (size_t)DM * DM;
  bf16* wvt = ws + off; off += (size_t)DM * DM;
  bf16* wot = ws + off; off += (size_t)DM * DM;
  bf16* FQ  = ws + off; off += (size_t)MROWS * DM;  // fragment-major [bh][g][kc]
  bf16* FK  = ws + off; off += (size_t)MROWS * DM;
  bf16* FV  = ws + off; off += (size_t)MROWS * DM;  // fragment-major [bh][dj][ks]
  bf16* Zb  = ws + off; off += (size_t)MROWS * DM;

  prep_inputs<<<(MROWS * DM / 4 + 255) / 256, 256, 0, stream>>>(x, pos, xb, aib);
  dim3 g3(1, 16, 48);
  transpose_w3<<<g3, 256, 0, stream>>>(WQ, WK, WV, wqt, wkt, wvt);
  dim3 go(16, 16, 1);
  transpose_w<<<go, 256, 0, stream>>>(WO, wot, 1024, 1024);
  qkv_gemm<<<768, 256, 0, stream>>>(aib, xb, wqt, wkt, wvt, bQ, bK, bV, FQ, FK, FV);
  flash_attn<<<2048, 128, 0, stream>>>(FQ, FK, FV, Zb);
  o_gemm64<<<512, 256, 0, stream>>>(Zb, wot, bO, out);
}

// Round 15
// 103.552 us; speedup vs baseline: 1.1523x; 1.0335x over previous
//
#include <hip/hip_runtime.h>
#include <hip/hip_bf16.h>
#include <stdint.h>

typedef __hip_bfloat16 bf16;
typedef __attribute__((ext_vector_type(8))) short short8;
typedef __attribute__((ext_vector_type(4))) short short4v;
typedef __attribute__((ext_vector_type(4))) float f32x4;
typedef __attribute__((ext_vector_type(16))) float f32x16;
typedef __attribute__((ext_vector_type(4))) unsigned uint4v;
typedef __attribute__((ext_vector_type(2))) unsigned uint2v;

#define AS1 __attribute__((address_space(1)))
#define AS3 __attribute__((address_space(3)))

static constexpr int SEQ = 2048, DM = 1024, DHD = 64;
static constexpr int MROWS = 2 * SEQ;  // 4096

__device__ __forceinline__ short f2b(float f) {
  __hip_bfloat16 h = __float2bfloat16(f);
  return *reinterpret_cast<short*>(&h);
}

__device__ __forceinline__ unsigned pack2(float lo, float hi) {
  float2 fv; fv.x = lo; fv.y = hi;
  union { __hip_bfloat162 h; unsigned u; } cv;
  cv.h = __float22bfloat162_rn(fv);
  return cv.u;
}

// raw v_exp_f32 (1-inst exp2) — libm exp2f carries range-check bloat
__device__ __forceinline__ float fexp2(float x) {
#if __has_builtin(__builtin_amdgcn_exp2f)
  return __builtin_amdgcn_exp2f(x);
#else
  return exp2f(x);
#endif
}

union U8 { uint4v u; short8 s; };

// volatile asm 16B global load with literal byte offset — cannot be sunk/reordered
#define GL16(dst, ptr, off) \
  asm volatile("global_load_dwordx4 %0, %1, off offset:" #off : "=v"(dst) : "v"(ptr))
// counted wait + scheduling fence (rule #18)
#define WAITV(n) do { asm volatile("s_waitcnt vmcnt(" #n ")"); __builtin_amdgcn_sched_barrier(0); } while (0)

__device__ __forceinline__ float xmax32(float v) {
#if __has_builtin(__builtin_amdgcn_permlane32_swap)
  uint2v r = __builtin_amdgcn_permlane32_swap(__float_as_uint(v), __float_as_uint(v), false, false);
  return fmaxf(__uint_as_float(r[0]), __uint_as_float(r[1]));
#else
  return fmaxf(v, __shfl_xor(v, 32));
#endif
}
__device__ __forceinline__ float xsum32(float v) {
#if __has_builtin(__builtin_amdgcn_permlane32_swap)
  uint2v r = __builtin_amdgcn_permlane32_swap(__float_as_uint(v), __float_as_uint(v), false, false);
  return __uint_as_float(r[0]) + __uint_as_float(r[1]);
#else
  return v + __shfl_xor(v, 32);
#endif
}

// ---------------- fused preprocess: prep + all weight transposes ------------
// blocks [0,4096): x->bf16, x+pos->bf16 (HBM-bound, vectorized)
// blocks [4096,4864): WQ/WK/WV per-head transpose (z = idx>>4)
// blocks [4864,5120): WO 1024x1024 transpose
__global__ __launch_bounds__(256) void preprocess(const float* __restrict__ x,
                                                  const float* __restrict__ pos,
                                                  bf16* __restrict__ xb,
                                                  bf16* __restrict__ aib,
                                                  const float* __restrict__ wq,
                                                  const float* __restrict__ wk,
                                                  const float* __restrict__ wv,
                                                  const float* __restrict__ wo,
                                                  bf16* __restrict__ oq,
                                                  bf16* __restrict__ ok,
                                                  bf16* __restrict__ ov,
                                                  bf16* __restrict__ owo) {
  const int bid = blockIdx.x;
  if (bid < 4096) {
    int i = bid * 256 + threadIdx.x;
    f32x4 xv = ((const f32x4*)x)[i];
    f32x4 pv = ((const f32x4*)pos)[i];
    short4v xo, ao;
#pragma unroll
    for (int j = 0; j < 4; ++j) {
      xo[j] = f2b(xv[j]);
      ao[j] = f2b(xv[j] + pv[j]);
    }
    ((short4v*)xb)[i] = xo;
    ((short4v*)aib)[i] = ao;
    return;
  }
  __shared__ float t[64][65];
  const float* in;
  bf16* out;
  int C, rt, ct;
  if (bid < 4864) {
    int idx = bid - 4096;
    int z = idx >> 4;
    rt = idx & 15; ct = 0; C = 64;
    const float* w = (z < 16) ? wq : (z < 32) ? wk : wv;
    bf16* o = (z < 16) ? oq : (z < 32) ? ok : ov;
    int zz = z & 15;
    in = w + (size_t)zz * 1024 * 64;
    out = o + (size_t)zz * 1024 * 64;
  } else {
    int idx = bid - 4864;
    ct = idx & 15; rt = idx >> 4; C = 1024;
    in = wo; out = owo;
  }
  int c = threadIdx.x & 63, g = threadIdx.x >> 6;
#pragma unroll
  for (int j = 0; j < 16; ++j) {
    int r = g * 16 + j;
    t[r][c] = in[(size_t)(rt * 64 + r) * C + (ct * 64 + c)];
  }
  __syncthreads();
#pragma unroll
  for (int j = 0; j < 16; ++j) {
    int rr = g * 16 + j;
    out[(size_t)(ct * 64 + rr) * 1024 + (rt * 64 + c)] = __float2bfloat16(t[c][rr]);
  }
}

// ---------------- 128x128 GEMM body, BK=32 (round-9 proven config) ----------
// MODE 3: bf16 fragment-major FQ/FK. MODE 4: fragment-major FV.
template <int MODE>
__device__ __forceinline__ void gemm128_body(const bf16* __restrict__ A,
                                             const bf16* __restrict__ Bt,
                                             const float* __restrict__ bias,
                                             bf16* __restrict__ C, int mt, int nt,
                                             float scale) {
  __shared__ alignas(16) bf16 Al[128 * 32];
  __shared__ alignas(16) bf16 Bl[128 * 32];
  const int lane = threadIdx.x & 63, wv = threadIdx.x >> 6;
  const int wr = wv >> 1, wc = wv & 1;
  const bf16* Ab = A + (size_t)mt * 128 * DM;
  const bf16* Bb = Bt + (size_t)nt * 128 * DM;

  f32x4 acc[4][4];
#pragma unroll
  for (int i = 0; i < 4; ++i)
#pragma unroll
    for (int j = 0; j < 4; ++j) acc[i][j] = (f32x4){0.f, 0.f, 0.f, 0.f};

  for (int kt = 0; kt < DM / 32; ++kt) {
    int k0 = kt * 32;
#pragma unroll
    for (int c = 0; c < 2; ++c) {
      int li0 = wv * 64 + c * 256;
      int li = li0 + lane;
      int row = li >> 2, sl = li & 3;
      int gs = sl ^ ((row >> 1) & 3);
      __builtin_amdgcn_global_load_lds((const AS1 void*)(Ab + (size_t)row * DM + k0 + gs * 8),
                                       (AS3 void*)(&Al[li0 * 8]), 16, 0, 0);
    }
#pragma unroll
    for (int c = 0; c < 2; ++c) {
      int li0 = wv * 64 + c * 256;
      int li = li0 + lane;
      int row = li >> 2, sl = li & 3;
      int gs = sl ^ ((row >> 1) & 3);
      __builtin_amdgcn_global_load_lds((const AS1 void*)(Bb + (size_t)row * DM + k0 + gs * 8),
                                       (AS3 void*)(&Bl[li0 * 8]), 16, 0, 0);
    }
    __syncthreads();

    short8 af[4], bfr[4];
    const int kb = lane >> 4;
#pragma unroll
    for (int mi = 0; mi < 4; ++mi) {
      int r = wr * 64 + mi * 16 + (lane & 15);
      af[mi] = *(const short8*)(&Al[r * 32 + ((kb ^ ((r >> 1) & 3)) << 3)]);
    }
#pragma unroll
    for (int ni = 0; ni < 4; ++ni) {
      int r = wc * 64 + ni * 16 + (lane & 15);
      bfr[ni] = *(const short8*)(&Bl[r * 32 + ((kb ^ ((r >> 1) & 3)) << 3)]);
    }
#pragma unroll
    for (int mi = 0; mi < 4; ++mi)
#pragma unroll
      for (int ni = 0; ni < 4; ++ni)
        acc[mi][ni] = __builtin_amdgcn_mfma_f32_16x16x32_bf16(af[mi], bfr[ni], acc[mi][ni], 0, 0, 0);
    __syncthreads();
  }

#pragma unroll
  for (int mi = 0; mi < 4; ++mi) {
#pragma unroll
    for (int ni = 0; ni < 4; ++ni) {
      int row0 = mt * 128 + wr * 64 + mi * 16 + (lane >> 4) * 4;
      int col = nt * 128 + wc * 64 + ni * 16 + (lane & 15);
      float bv = bias[col];
      int bb = row0 >> 11, s0 = row0 & 2047;
      int hh = col >> 6, d0 = col & 63;
      size_t bhb = (size_t)(bb * 16 + hh) * 131072;
      if constexpr (MODE == 3) {
        // FQ/FK[bh][g][kc]: slot (r32+32*hi)*8 + e, from row s, col d0
        int kc = d0 >> 4, hi = (d0 >> 3) & 1, e = d0 & 7;
        int g = s0 >> 5, r0 = s0 & 31;
        size_t bbase = bhb + g * 2048 + kc * 512 + e;
#pragma unroll
        for (int j = 0; j < 4; ++j)
          C[bbase + (size_t)(r0 + j + 32 * hi) * 8] =
              __float2bfloat16((acc[mi][ni][j] + bv) * scale);
      } else {  // MODE 4
        // FV[bh][dj][ks]: slot (d32+32*((s>>3)&1))*8 + (s&7), d on slot axis
        int dj = d0 >> 5, d32 = d0 & 31;
        int ks = s0 >> 4, hi2 = (s0 >> 3) & 1, e0 = s0 & 7;
        short4v o;
#pragma unroll
        for (int j = 0; j < 4; ++j) o[j] = f2b(acc[mi][ni][j] + bv);
        *(short4v*)(C + bhb + dj * 65536 + ks * 512 + (size_t)(d32 + 32 * hi2) * 8 + e0) = o;
      }
    }
  }
}

// Q prescale: (1/sqrt(64)) * log2(e) so attention uses exp2
static constexpr float QSCALE = 0.125f * 1.4426950408889634f;

__global__ __launch_bounds__(256) void qkv_gemm(const bf16* __restrict__ aib,
                                                const bf16* __restrict__ xb,
                                                const bf16* __restrict__ wqt,
                                                const bf16* __restrict__ wkt,
                                                const bf16* __restrict__ wvt,
                                                const float* __restrict__ bq,
                                                const float* __restrict__ bk,
                                                const float* __restrict__ bv,
                                                bf16* __restrict__ FQ, bf16* __restrict__ FK,
                                                bf16* __restrict__ FV) {
  int mt = blockIdx.x & 31;
  int nt = (blockIdx.x >> 5) & 7;
  int mat = blockIdx.x >> 8;
  if (mat == 0) {
    gemm128_body<3>(aib, wqt, bq, FQ, mt, nt, QSCALE);
  } else if (mat == 1) {
    gemm128_body<3>(aib, wkt, bk, FK, mt, nt, 1.0f);
  } else {
    gemm128_body<4>(xb, wvt, bv, FV, mt, nt, 1.0f);
  }
}

// ---------------- o_gemm: 64x128 tiles, BK=128 -> 512 blocks (2/CU) ---------
// Grid-capped at 2 blocks/CU so 48KB LDS is free; BK=128 gives 32 MFMA per
// barrier pair (8 K-iterations total). Bank-balanced: each of 8 bank-groups
// gets exactly 8 lanes per ds_read_b128 wave -> throughput floor.
__global__ __launch_bounds__(256) void o_gemm64(const bf16* __restrict__ A,
                                                const bf16* __restrict__ Bt,
                                                const float* __restrict__ bias,
                                                float* __restrict__ out) {
  __shared__ alignas(16) bf16 Al[64 * 128];    // 16 KB
  __shared__ alignas(16) bf16 Bl[128 * 128];   // 32 KB
  const int mt = blockIdx.x & 63, nt = blockIdx.x >> 6;
  const int lane = threadIdx.x & 63, wv = threadIdx.x >> 6;
  const int wr = wv >> 1, wc = wv & 1;  // wave: 32 rows x 64 cols quadrant
  const bf16* Ab = A + (size_t)mt * 64 * DM;
  const bf16* Bb = Bt + (size_t)nt * 128 * DM;

  f32x4 acc[2][4];
#pragma unroll
  for (int i = 0; i < 2; ++i)
#pragma unroll
    for (int j = 0; j < 4; ++j) acc[i][j] = (f32x4){0.f, 0.f, 0.f, 0.f};

  for (int kt = 0; kt < DM / 128; ++kt) {
    int k0 = kt * 128;
#pragma unroll
    for (int c = 0; c < 4; ++c) {  // A: 64x128 = 16KB, four passes
      int li0 = wv * 64 + c * 256;
      int li = li0 + lane;
      int row = li >> 4, sl = li & 15;
      int gs = sl ^ (row & 7);
      __builtin_amdgcn_global_load_lds((const AS1 void*)(Ab + (size_t)row * DM + k0 + gs * 8),
                                       (AS3 void*)(&Al[li0 * 8]), 16, 0, 0);
    }
#pragma unroll
    for (int c = 0; c < 8; ++c) {  // B: 128x128 = 32KB, eight passes
      int li0 = wv * 64 + c * 256;
      int li = li0 + lane;
      int row = li >> 4, sl = li & 15;
      int gs = sl ^ (row & 7);
      __builtin_amdgcn_global_load_lds((const AS1 void*)(Bb + (size_t)row * DM + k0 + gs * 8),
                                       (AS3 void*)(&Bl[li0 * 8]), 16, 0, 0);
    }
    __syncthreads();

    const int kb = lane >> 4;
#pragma unroll
    for (int kk = 0; kk < 4; ++kk) {
      short8 af[2], bfr[4];
#pragma unroll
      for (int mi = 0; mi < 2; ++mi) {
        int r = wr * 32 + mi * 16 + (lane & 15);
        af[mi] = *(const short8*)(&Al[r * 128 + (((kb + 4 * kk) ^ (r & 7)) << 3)]);
      }
#pragma unroll
      for (int ni = 0; ni < 4; ++ni) {
        int r = wc * 64 + ni * 16 + (lane & 15);
        bfr[ni] = *(const short8*)(&Bl[r * 128 + (((kb + 4 * kk) ^ (r & 7)) << 3)]);
      }
#pragma unroll
      for (int mi = 0; mi < 2; ++mi)
#pragma unroll
        for (int ni = 0; ni < 4; ++ni)
          acc[mi][ni] = __builtin_amdgcn_mfma_f32_16x16x32_bf16(af[mi], bfr[ni], acc[mi][ni], 0, 0, 0);
    }
    __syncthreads();
  }

#pragma unroll
  for (int mi = 0; mi < 2; ++mi) {
#pragma unroll
    for (int ni = 0; ni < 4; ++ni) {
      int row0 = mt * 64 + wr * 32 + mi * 16 + (lane >> 4) * 4;
      int col = nt * 128 + wc * 64 + ni * 16 + (lane & 15);
      float bv = bias[col];
#pragma unroll
      for (int j = 0; j < 4; ++j)
        out[(size_t)(row0 + j) * DM + col] = acc[mi][ni][j] + bv;
    }
  }
}

// ---------------- flash attention: split-KV x2, swapped-QK^T ----------------
// 128-thread block = 2 waves on one (bh, q-tile); wave0 tiles [0,hsp), wave1
// [hsp,nt); exact merge via LDS. Fragment-major operands -> coalesced 1KB
// loads. K(t+1) issued after QK^T; V(t+1) issued after PV into the same vf
// buffer. Counted vmcnt: drain K at 8, V at 8.
__global__ __launch_bounds__(128, 2) void flash_attn(const bf16* __restrict__ FQ,
                                                     const bf16* __restrict__ FK,
                                                     const bf16* __restrict__ FV,
                                                     bf16* __restrict__ Zb) {
  __shared__ float Zm[64][33];   // wave1 partial Z^T (padded)
  __shared__ float Ml[64], Ll[64];
  __shared__ unsigned Zl[32 * 32];  // wave0 final ZT->Z transpose

  const int lane = threadIdx.x & 63;
  const int wvi = threadIdx.x >> 6;
  const int qln = lane & 31;
  const bool hib = lane >= 32;
  const int bh = blockIdx.x & 31;           // bh%8 -> XCD affinity
  const int wq = 63 - (blockIdx.x >> 5);    // heavy blocks dispatch first
  const int bb = bh >> 4, h = bh & 15;
  const int q0 = wq * 32;
  const int nt = wq / 2 + 1;
  const int hsp = (nt + 1) >> 1;
  const int t0 = wvi ? hsp : 0;
  const int t1 = wvi ? nt : hsp;

  const size_t fb = (size_t)bh * 131072;
  const bf16* qp = FQ + fb + wq * 2048 + lane * 8;
  const bf16* kpt = FK + fb + (size_t)t0 * 4096 + lane * 8;
  const bf16* vp0 = FV + fb + (size_t)t0 * 2048 + lane * 8;
  const bf16* vp1 = vp0 + 65536;

  f32x16 zacc[2];
#pragma unroll
  for (int i = 0; i < 16; ++i) { zacc[0][i] = 0.f; zacc[1][i] = 0.f; }
  float mrun = -1e30f, lrun = 0.f;

  short8 qf[4];
  short8 kfA[2][4], kfB[2][4];
  short8 vf[2][4];  // single V buffer, prefetched one tile ahead

  if (t0 < t1) {
    // prologue: Q (4), K(t0) (8), V(t0) (8) — issue order matters for vmcnt
    GL16(qf[0], qp, 0); GL16(qf[1], qp, 1024); GL16(qf[2], qp, 2048); GL16(qf[3], qp, 3072);
    {
      const bf16* k1 = kpt + 2048;
      GL16(kfA[0][0], kpt, 0); GL16(kfA[0][1], kpt, 1024); GL16(kfA[0][2], kpt, 2048); GL16(kfA[0][3], kpt, 3072);
      GL16(kfA[1][0], k1, 0);  GL16(kfA[1][1], k1, 1024);  GL16(kfA[1][2], k1, 2048);  GL16(kfA[1][3], k1, 3072);
      kpt += 4096;
    }
    GL16(vf[0][0], vp0, 0); GL16(vf[0][1], vp0, 1024); GL16(vf[0][2], vp0, 2048); GL16(vf[0][3], vp0, 3072);
    GL16(vf[1][0], vp1, 0); GL16(vf[1][1], vp1, 1024); GL16(vf[1][2], vp1, 2048); GL16(vf[1][3], vp1, 3072);
    vp0 += 2048; vp1 += 2048;

    auto computeT = [&](short8(&kf)[2][4], short8(&kfn)[2][4], int t) {
      const int kv0 = t * 64;
      const bool pref = (t + 1 < t1);

      WAITV(8);  // drain K(t) (+Q on first tile); V(t)'s 8 stay in flight

      f32x16 s[2];
#pragma unroll
      for (int i = 0; i < 16; ++i) { s[0][i] = 0.f; s[1][i] = 0.f; }
      __builtin_amdgcn_s_setprio(1);
#pragma unroll
      for (int kc = 0; kc < 4; ++kc) {
        s[0] = __builtin_amdgcn_mfma_f32_32x32x16_bf16(kf[0][kc], qf[kc], s[0], 0, 0, 0);
        s[1] = __builtin_amdgcn_mfma_f32_32x32x16_bf16(kf[1][kc], qf[kc], s[1], 0, 0, 0);
      }
      __builtin_amdgcn_s_setprio(0);

      if (pref) {  // issue K(t+1) — covered by softmax + PV + next QK
        const bf16* k1 = kpt + 2048;
        GL16(kfn[0][0], kpt, 0); GL16(kfn[0][1], kpt, 1024); GL16(kfn[0][2], kpt, 2048); GL16(kfn[0][3], kpt, 3072);
        GL16(kfn[1][0], k1, 0);  GL16(kfn[1][1], k1, 1024);  GL16(kfn[1][2], k1, 2048);  GL16(kfn[1][3], k1, 3072);
        kpt += 4096;
      }

      if (t == nt - 1) {  // causal mask, diagonal tile only
        const int qg = q0 + qln;
#pragma unroll
        for (int ni = 0; ni < 2; ++ni)
#pragma unroll
          for (int rr = 0; rr < 16; ++rr) {
            int kv = kv0 + 32 * ni + (rr & 3) + 8 * (rr >> 2) + (hib ? 4 : 0);
            if (kv > qg) s[ni][rr] = -1e30f;
          }
      }

      // row max: in-register tree + cross-half swap
      float t8[8];
#pragma unroll
      for (int i = 0; i < 8; ++i)
        t8[i] = fmaxf(fmaxf(s[0][i], s[0][i + 8]), fmaxf(s[1][i], s[1][i + 8]));
      float tm = fmaxf(fmaxf(fmaxf(t8[0], t8[1]), fmaxf(t8[2], t8[3])),
                       fmaxf(fmaxf(t8[4], t8[5]), fmaxf(t8[6], t8[7])));
      tm = xmax32(tm);

      // defer-max (T13): rescale only when max grew by >8; P bounded by 2^8.
      if (__ballot(tm > mrun + 8.0f)) {
        float mn = fmaxf(mrun, tm);
        float al = fexp2(mrun - mn);
        mrun = mn;
        lrun *= al;
#pragma unroll
        for (int i = 0; i < 16; ++i) { zacc[0][i] *= al; zacc[1][i] *= al; }
      }

      float pacc[4] = {0.f, 0.f, 0.f, 0.f};
#pragma unroll
      for (int ni = 0; ni < 2; ++ni)
#pragma unroll
        for (int rr = 0; rr < 16; ++rr) {
          float p = fexp2(s[ni][rr] - mrun);
          s[ni][rr] = p;
          pacc[rr & 3] += p;
        }
      lrun += xsum32((pacc[0] + pacc[1]) + (pacc[2] + pacc[3]));

      // P -> bf16 B-fragments: pack pairs, permlane32_swap fills both halves
      unsigned su32[2][8];
#pragma unroll
      for (int ni = 0; ni < 2; ++ni)
#pragma unroll
        for (int tt = 0; tt < 8; ++tt)
          su32[ni][tt] = pack2(s[ni][2 * tt], s[ni][2 * tt + 1]);

      short8 pa[4];
#if __has_builtin(__builtin_amdgcn_permlane32_swap)
#pragma unroll
      for (int c = 0; c < 4; ++c) {
        int ni = c >> 1, b4 = 4 * (c & 1);
        uint2v r0 = __builtin_amdgcn_permlane32_swap(su32[ni][b4 + 0], su32[ni][b4 + 2], false, false);
        uint2v r1 = __builtin_amdgcn_permlane32_swap(su32[ni][b4 + 1], su32[ni][b4 + 3], false, false);
        U8 w;
        w.u[0] = r0[0]; w.u[1] = r1[0]; w.u[2] = r0[1]; w.u[3] = r1[1];
        pa[c] = w.s;
      }
#else
      unsigned X[2][8];
#pragma unroll
      for (int ni = 0; ni < 2; ++ni)
#pragma unroll
        for (int tt = 0; tt < 8; ++tt)
          X[ni][tt] = (unsigned)__shfl_xor((int)su32[ni][tt], 32);
#pragma unroll
      for (int c = 0; c < 4; ++c) {
        int ni = c >> 1, b4 = 4 * (c & 1);
        U8 w;
        w.u[0] = hib ? X[ni][b4 + 2] : su32[ni][b4 + 0];
        w.u[1] = hib ? X[ni][b4 + 3] : su32[ni][b4 + 1];
        w.u[2] = hib ? su32[ni][b4 + 2] : X[ni][b4 + 0];
        w.u[3] = hib ? su32[ni][b4 + 3] : X[ni][b4 + 1];
        pa[c] = w.s;
      }
#endif

      if (pref) { WAITV(8); } else { WAITV(0); }  // drain V(t); K(t+1) in flight

      __builtin_amdgcn_s_setprio(1);
#pragma unroll
      for (int c = 0; c < 4; ++c) {
        zacc[0] = __builtin_amdgcn_mfma_f32_32x32x16_bf16(vf[0][c], pa[c], zacc[0], 0, 0, 0);
        zacc[1] = __builtin_amdgcn_mfma_f32_32x32x16_bf16(vf[1][c], pa[c], zacc[1], 0, 0, 0);
      }
      __builtin_amdgcn_s_setprio(0);
      __builtin_amdgcn_sched_barrier(0);  // keep V(t+1) issue below the PV MFMAs

      if (pref) {  // issue V(t+1) into vf (dead after PV issue) — full-tile cover
        GL16(vf[0][0], vp0, 0); GL16(vf[0][1], vp0, 1024); GL16(vf[0][2], vp0, 2048); GL16(vf[0][3], vp0, 3072);
        GL16(vf[1][0], vp1, 0); GL16(vf[1][1], vp1, 1024); GL16(vf[1][2], vp1, 2048); GL16(vf[1][3], vp1, 3072);
        vp0 += 2048; vp1 += 2048;
      }
    };

    int t = t0;
    while (true) {
      computeT(kfA, kfB, t);
      if (++t >= t1) break;
      computeT(kfB, kfA, t);
      if (++t >= t1) break;
    }
  }

  // ---- merge wave1 into wave0 (exact online-softmax combine) ----
  if (wvi == 1) {
#pragma unroll
    for (int i = 0; i < 16; ++i) {
      Zm[lane][i] = zacc[0][i];
      Zm[lane][16 + i] = zacc[1][i];
    }
    Ml[lane] = mrun;
    Ll[lane] = lrun;
  }
  __syncthreads();
  if (wvi == 0) {
    float m1 = Ml[lane], l1 = Ll[lane];
    float mn = fmaxf(mrun, m1);
    float a0 = fexp2(mrun - mn);
    float a1 = fexp2(m1 - mn);
    float lm = lrun * a0 + l1 * a1;
#pragma unroll
    for (int i = 0; i < 16; ++i) {
      zacc[0][i] = zacc[0][i] * a0 + Zm[lane][i] * a1;
      zacc[1][i] = zacc[1][i] * a0 + Zm[lane][16 + i] * a1;
    }

    // normalize + transpose Z^T -> Z via swizzled LDS, coalesced store
    const float rl = 1.0f / lm;
    const int W8[8] = {0, 1, 4, 5, 8, 9, 12, 13};
#pragma unroll
    for (int dj = 0; dj < 2; ++dj)
#pragma unroll
      for (int tt = 0; tt < 8; ++tt) {
        unsigned v = pack2(zacc[dj][2 * tt] * rl, zacc[dj][2 * tt + 1] * rl);
        int x = 16 * dj + (hib ? 2 : 0) + W8[tt];
        Zl[qln * 32 + (((x >> 2) ^ (qln & 7)) << 2) + (x & 3)] = v;
      }
    asm volatile("s_waitcnt lgkmcnt(0)" ::: "memory");
    __builtin_amdgcn_sched_barrier(0);
    const size_t base = ((size_t)bb * SEQ) * DM + h * DHD;
    int q2 = lane >> 1, hf = lane & 1;
#pragma unroll
    for (int u = 0; u < 4; ++u) {
      int sl = (hf * 4 + u) ^ (q2 & 7);
      U8 w;
      w.u = *(const uint4v*)&Zl[q2 * 32 + sl * 4];
      *(short8*)(Zb + base + (size_t)(q0 + q2) * DM + hf * 32 + u * 8) = w.s;
    }
  }
}

extern "C" void kernel_launch(void* const* d_in, const int* in_sizes, int n_in,
                              void* d_out, int out_size, void* d_ws, size_t ws_size,
                              hipStream_t stream) {
  (void)in_sizes; (void)n_in; (void)out_size; (void)ws_size;
  const float* x = (const float*)d_in[0];
  const float* pos = (const float*)d_in[1];
  const float* WQ = (const float*)d_in[2];
  const float* bQ = (const float*)d_in[3];
  const float* WK = (const float*)d_in[4];
  const float* bK = (const float*)d_in[5];
  const float* WV = (const float*)d_in[6];
  const float* bV = (const float*)d_in[7];
  const float* WO = (const float*)d_in[8];
  const float* bO = (const float*)d_in[9];
  float* out = (float*)d_out;

  bf16* ws = (bf16*)d_ws;
  size_t off = 0;
  bf16* aib = ws + off; off += (size_t)MROWS * DM;
  bf16* xb  = ws + off; off += (size_t)MROWS * DM;
  bf16* wqt = ws + off; off += (size_t)DM * DM;
  bf16* wkt = ws + off; off += (size_t)DM * DM;
  bf16* wvt = ws + off; off += (size_t)DM * DM;
  bf16* wot = ws + off; off += (size_t)DM * DM;
  bf16* FQ  = ws + off; off += (size_t)MROWS * DM;  // fragment-major [bh][g][kc]
  bf16* FK  = ws + off; off += (size_t)MROWS * DM;
  bf16* FV  = ws + off; off += (size_t)MROWS * DM;  // fragment-major [bh][dj][ks]
  bf16* Zb  = ws + off; off += (size_t)MROWS * DM;

  preprocess<<<5120, 256, 0, stream>>>(x, pos, xb, aib, WQ, WK, WV, WO,
                                       wqt, wkt, wvt, wot);
  qkv_gemm<<<768, 256, 0, stream>>>(aib, xb, wqt, wkt, wvt, bQ, bK, bV, FQ, FK, FV);
  flash_attn<<<2048, 128, 0, stream>>>(FQ, FK, FV, Zb);
  o_gemm64<<<512, 256, 0, stream>>>(Zb, wot, bO, out);
}

// Round 16
// 99.316 us; speedup vs baseline: 1.2014x; 1.0427x over previous
//
#include <hip/hip_runtime.h>
#include <hip/hip_bf16.h>
#include <stdint.h>

typedef __hip_bfloat16 bf16;
typedef __attribute__((ext_vector_type(8))) short short8;
typedef __attribute__((ext_vector_type(4))) short short4v;
typedef __attribute__((ext_vector_type(4))) float f32x4;
typedef __attribute__((ext_vector_type(16))) float f32x16;
typedef __attribute__((ext_vector_type(4))) unsigned uint4v;
typedef __attribute__((ext_vector_type(2))) unsigned uint2v;

#define AS1 __attribute__((address_space(1)))
#define AS3 __attribute__((address_space(3)))

static constexpr int SEQ = 2048, DM = 1024, DHD = 64;
static constexpr int MROWS = 2 * SEQ;  // 4096

__device__ __forceinline__ short f2b(float f) {
  __hip_bfloat16 h = __float2bfloat16(f);
  return *reinterpret_cast<short*>(&h);
}

__device__ __forceinline__ unsigned pack2(float lo, float hi) {
  float2 fv; fv.x = lo; fv.y = hi;
  union { __hip_bfloat162 h; unsigned u; } cv;
  cv.h = __float22bfloat162_rn(fv);
  return cv.u;
}

// raw v_exp_f32 (1-inst exp2) — libm exp2f carries range-check bloat
__device__ __forceinline__ float fexp2(float x) {
#if __has_builtin(__builtin_amdgcn_exp2f)
  return __builtin_amdgcn_exp2f(x);
#else
  return exp2f(x);
#endif
}

union U8 { uint4v u; short8 s; };

// volatile asm 16B global load with literal byte offset — cannot be sunk/reordered
#define GL16(dst, ptr, off) \
  asm volatile("global_load_dwordx4 %0, %1, off offset:" #off : "=v"(dst) : "v"(ptr))
// counted wait + scheduling fence (rule #18)
#define WAITV(n) do { asm volatile("s_waitcnt vmcnt(" #n ")"); __builtin_amdgcn_sched_barrier(0); } while (0)

__device__ __forceinline__ float xmax32(float v) {
#if __has_builtin(__builtin_amdgcn_permlane32_swap)
  uint2v r = __builtin_amdgcn_permlane32_swap(__float_as_uint(v), __float_as_uint(v), false, false);
  return fmaxf(__uint_as_float(r[0]), __uint_as_float(r[1]));
#else
  return fmaxf(v, __shfl_xor(v, 32));
#endif
}
__device__ __forceinline__ float xsum32(float v) {
#if __has_builtin(__builtin_amdgcn_permlane32_swap)
  uint2v r = __builtin_amdgcn_permlane32_swap(__float_as_uint(v), __float_as_uint(v), false, false);
  return __uint_as_float(r[0]) + __uint_as_float(r[1]);
#else
  return v + __shfl_xor(v, 32);
#endif
}

// ---------------- fused preprocess: prep + all weight transposes ------------
__global__ __launch_bounds__(256) void preprocess(const float* __restrict__ x,
                                                  const float* __restrict__ pos,
                                                  bf16* __restrict__ xb,
                                                  bf16* __restrict__ aib,
                                                  const float* __restrict__ wq,
                                                  const float* __restrict__ wk,
                                                  const float* __restrict__ wv,
                                                  const float* __restrict__ wo,
                                                  bf16* __restrict__ oq,
                                                  bf16* __restrict__ ok,
                                                  bf16* __restrict__ ov,
                                                  bf16* __restrict__ owo) {
  const int bid = blockIdx.x;
  if (bid < 4096) {
    int i = bid * 256 + threadIdx.x;
    f32x4 xv = ((const f32x4*)x)[i];
    f32x4 pv = ((const f32x4*)pos)[i];
    short4v xo, ao;
#pragma unroll
    for (int j = 0; j < 4; ++j) {
      xo[j] = f2b(xv[j]);
      ao[j] = f2b(xv[j] + pv[j]);
    }
    ((short4v*)xb)[i] = xo;
    ((short4v*)aib)[i] = ao;
    return;
  }
  __shared__ float t[64][65];
  const float* in;
  bf16* out;
  int C, rt, ct;
  if (bid < 4864) {
    int idx = bid - 4096;
    int z = idx >> 4;
    rt = idx & 15; ct = 0; C = 64;
    const float* w = (z < 16) ? wq : (z < 32) ? wk : wv;
    bf16* o = (z < 16) ? oq : (z < 32) ? ok : ov;
    int zz = z & 15;
    in = w + (size_t)zz * 1024 * 64;
    out = o + (size_t)zz * 1024 * 64;
  } else {
    int idx = bid - 4864;
    ct = idx & 15; rt = idx >> 4; C = 1024;
    in = wo; out = owo;
  }
  int c = threadIdx.x & 63, g = threadIdx.x >> 6;
#pragma unroll
  for (int j = 0; j < 16; ++j) {
    int r = g * 16 + j;
    t[r][c] = in[(size_t)(rt * 64 + r) * C + (ct * 64 + c)];
  }
  __syncthreads();
#pragma unroll
  for (int j = 0; j < 16; ++j) {
    int rr = g * 16 + j;
    out[(size_t)(ct * 64 + rr) * 1024 + (rt * 64 + c)] = __float2bfloat16(t[c][rr]);
  }
}

// ---------------- 128x128 GEMM body, BK=32 (round-9 proven config) ----------
template <int MODE>
__device__ __forceinline__ void gemm128_body(const bf16* __restrict__ A,
                                             const bf16* __restrict__ Bt,
                                             const float* __restrict__ bias,
                                             bf16* __restrict__ C, int mt, int nt,
                                             float scale) {
  __shared__ alignas(16) bf16 Al[128 * 32];
  __shared__ alignas(16) bf16 Bl[128 * 32];
  const int lane = threadIdx.x & 63, wv = threadIdx.x >> 6;
  const int wr = wv >> 1, wc = wv & 1;
  const bf16* Ab = A + (size_t)mt * 128 * DM;
  const bf16* Bb = Bt + (size_t)nt * 128 * DM;

  f32x4 acc[4][4];
#pragma unroll
  for (int i = 0; i < 4; ++i)
#pragma unroll
    for (int j = 0; j < 4; ++j) acc[i][j] = (f32x4){0.f, 0.f, 0.f, 0.f};

  for (int kt = 0; kt < DM / 32; ++kt) {
    int k0 = kt * 32;
#pragma unroll
    for (int c = 0; c < 2; ++c) {
      int li0 = wv * 64 + c * 256;
      int li = li0 + lane;
      int row = li >> 2, sl = li & 3;
      int gs = sl ^ ((row >> 1) & 3);
      __builtin_amdgcn_global_load_lds((const AS1 void*)(Ab + (size_t)row * DM + k0 + gs * 8),
                                       (AS3 void*)(&Al[li0 * 8]), 16, 0, 0);
    }
#pragma unroll
    for (int c = 0; c < 2; ++c) {
      int li0 = wv * 64 + c * 256;
      int li = li0 + lane;
      int row = li >> 2, sl = li & 3;
      int gs = sl ^ ((row >> 1) & 3);
      __builtin_amdgcn_global_load_lds((const AS1 void*)(Bb + (size_t)row * DM + k0 + gs * 8),
                                       (AS3 void*)(&Bl[li0 * 8]), 16, 0, 0);
    }
    __syncthreads();

    short8 af[4], bfr[4];
    const int kb = lane >> 4;
#pragma unroll
    for (int mi = 0; mi < 4; ++mi) {
      int r = wr * 64 + mi * 16 + (lane & 15);
      af[mi] = *(const short8*)(&Al[r * 32 + ((kb ^ ((r >> 1) & 3)) << 3)]);
    }
#pragma unroll
    for (int ni = 0; ni < 4; ++ni) {
      int r = wc * 64 + ni * 16 + (lane & 15);
      bfr[ni] = *(const short8*)(&Bl[r * 32 + ((kb ^ ((r >> 1) & 3)) << 3)]);
    }
#pragma unroll
    for (int mi = 0; mi < 4; ++mi)
#pragma unroll
      for (int ni = 0; ni < 4; ++ni)
        acc[mi][ni] = __builtin_amdgcn_mfma_f32_16x16x32_bf16(af[mi], bfr[ni], acc[mi][ni], 0, 0, 0);
    __syncthreads();
  }

#pragma unroll
  for (int mi = 0; mi < 4; ++mi) {
#pragma unroll
    for (int ni = 0; ni < 4; ++ni) {
      int row0 = mt * 128 + wr * 64 + mi * 16 + (lane >> 4) * 4;
      int col = nt * 128 + wc * 64 + ni * 16 + (lane & 15);
      float bv = bias[col];
      int bb = row0 >> 11, s0 = row0 & 2047;
      int hh = col >> 6, d0 = col & 63;
      size_t bhb = (size_t)(bb * 16 + hh) * 131072;
      if constexpr (MODE == 3) {
        int kc = d0 >> 4, hi = (d0 >> 3) & 1, e = d0 & 7;
        int g = s0 >> 5, r0 = s0 & 31;
        size_t bbase = bhb + g * 2048 + kc * 512 + e;
#pragma unroll
        for (int j = 0; j < 4; ++j)
          C[bbase + (size_t)(r0 + j + 32 * hi) * 8] =
              __float2bfloat16((acc[mi][ni][j] + bv) * scale);
      } else {  // MODE 4
        int dj = d0 >> 5, d32 = d0 & 31;
        int ks = s0 >> 4, hi2 = (s0 >> 3) & 1, e0 = s0 & 7;
        short4v o;
#pragma unroll
        for (int j = 0; j < 4; ++j) o[j] = f2b(acc[mi][ni][j] + bv);
        *(short4v*)(C + bhb + dj * 65536 + ks * 512 + (size_t)(d32 + 32 * hi2) * 8 + e0) = o;
      }
    }
  }
}

// Q prescale: (1/sqrt(64)) * log2(e) so attention uses exp2
static constexpr float QSCALE = 0.125f * 1.4426950408889634f;

__global__ __launch_bounds__(256) void qkv_gemm(const bf16* __restrict__ aib,
                                                const bf16* __restrict__ xb,
                                                const bf16* __restrict__ wqt,
                                                const bf16* __restrict__ wkt,
                                                const bf16* __restrict__ wvt,
                                                const float* __restrict__ bq,
                                                const float* __restrict__ bk,
                                                const float* __restrict__ bv,
                                                bf16* __restrict__ FQ, bf16* __restrict__ FK,
                                                bf16* __restrict__ FV) {
  int mt = blockIdx.x & 31;
  int nt = (blockIdx.x >> 5) & 7;
  int mat = blockIdx.x >> 8;
  if (mat == 0) {
    gemm128_body<3>(aib, wqt, bq, FQ, mt, nt, QSCALE);
  } else if (mat == 1) {
    gemm128_body<3>(aib, wkt, bk, FK, mt, nt, 1.0f);
  } else {
    gemm128_body<4>(xb, wvt, bv, FV, mt, nt, 1.0f);
  }
}

// ---------------- o_gemm: 64x128 tiles, BK=128 -> 512 blocks (2/CU) ---------
__global__ __launch_bounds__(256) void o_gemm64(const bf16* __restrict__ A,
                                                const bf16* __restrict__ Bt,
                                                const float* __restrict__ bias,
                                                float* __restrict__ out) {
  __shared__ alignas(16) bf16 Al[64 * 128];    // 16 KB
  __shared__ alignas(16) bf16 Bl[128 * 128];   // 32 KB
  const int mt = blockIdx.x & 63, nt = blockIdx.x >> 6;
  const int lane = threadIdx.x & 63, wv = threadIdx.x >> 6;
  const int wr = wv >> 1, wc = wv & 1;
  const bf16* Ab = A + (size_t)mt * 64 * DM;
  const bf16* Bb = Bt + (size_t)nt * 128 * DM;

  f32x4 acc[2][4];
#pragma unroll
  for (int i = 0; i < 2; ++i)
#pragma unroll
    for (int j = 0; j < 4; ++j) acc[i][j] = (f32x4){0.f, 0.f, 0.f, 0.f};

  for (int kt = 0; kt < DM / 128; ++kt) {
    int k0 = kt * 128;
#pragma unroll
    for (int c = 0; c < 4; ++c) {
      int li0 = wv * 64 + c * 256;
      int li = li0 + lane;
      int row = li >> 4, sl = li & 15;
      int gs = sl ^ (row & 7);
      __builtin_amdgcn_global_load_lds((const AS1 void*)(Ab + (size_t)row * DM + k0 + gs * 8),
                                       (AS3 void*)(&Al[li0 * 8]), 16, 0, 0);
    }
#pragma unroll
    for (int c = 0; c < 8; ++c) {
      int li0 = wv * 64 + c * 256;
      int li = li0 + lane;
      int row = li >> 4, sl = li & 15;
      int gs = sl ^ (row & 7);
      __builtin_amdgcn_global_load_lds((const AS1 void*)(Bb + (size_t)row * DM + k0 + gs * 8),
                                       (AS3 void*)(&Bl[li0 * 8]), 16, 0, 0);
    }
    __syncthreads();

    const int kb = lane >> 4;
#pragma unroll
    for (int kk = 0; kk < 4; ++kk) {
      short8 af[2], bfr[4];
#pragma unroll
      for (int mi = 0; mi < 2; ++mi) {
        int r = wr * 32 + mi * 16 + (lane & 15);
        af[mi] = *(const short8*)(&Al[r * 128 + (((kb + 4 * kk) ^ (r & 7)) << 3)]);
      }
#pragma unroll
      for (int ni = 0; ni < 4; ++ni) {
        int r = wc * 64 + ni * 16 + (lane & 15);
        bfr[ni] = *(const short8*)(&Bl[r * 128 + (((kb + 4 * kk) ^ (r & 7)) << 3)]);
      }
#pragma unroll
      for (int mi = 0; mi < 2; ++mi)
#pragma unroll
        for (int ni = 0; ni < 4; ++ni)
          acc[mi][ni] = __builtin_amdgcn_mfma_f32_16x16x32_bf16(af[mi], bfr[ni], acc[mi][ni], 0, 0, 0);
    }
    __syncthreads();
  }

#pragma unroll
  for (int mi = 0; mi < 2; ++mi) {
#pragma unroll
    for (int ni = 0; ni < 4; ++ni) {
      int row0 = mt * 64 + wr * 32 + mi * 16 + (lane >> 4) * 4;
      int col = nt * 128 + wc * 64 + ni * 16 + (lane & 15);
      float bv = bias[col];
#pragma unroll
      for (int j = 0; j < 4; ++j)
        out[(size_t)(row0 + j) * DM + col] = acc[mi][ni][j] + bv;
    }
  }
}

// ---------------- flash attention: pair-balanced blocks, swapped-QK^T -------
// 1024 blocks x 128 thr: block (bh, p) owns q-tile pair A=63-p (heavy) and
// B=p (light); nA+nB ~= 33 for every p -> all blocks equal duration (no tail).
// wave0: A tiles [0,h); wave1: A tiles [h,nA) then all of B (both ~17 tiles).
// wave1 stores A-partial to LDS pre-barrier; post-barrier wave0 merges+writes
// A, wave1 writes B. Inner pipeline identical to round-13 (asm loads, counted
// vmcnt, defer-max, permlane pack, setprio).
__global__ __launch_bounds__(128, 2) void flash_attn(const bf16* __restrict__ FQ,
                                                     const bf16* __restrict__ FK,
                                                     const bf16* __restrict__ FV,
                                                     bf16* __restrict__ Zb) {
  __shared__ float Zm[64][33];      // wave1 A-partial Z^T (padded)
  __shared__ float Ml[64], Ll[64];
  __shared__ unsigned Zl[2][32 * 32];  // per-wave ZT->Z transpose buffers

  const int lane = threadIdx.x & 63;
  const int wvi = threadIdx.x >> 6;
  const int qln = lane & 31;
  const bool hib = lane >= 32;
  const int bh = blockIdx.x & 31;      // bh%8 -> XCD affinity
  const int p = blockIdx.x >> 5;       // 0..31
  const int wqA = 63 - p, wqB = p;
  const int nA = wqA / 2 + 1, nB = wqB / 2 + 1;
  int h = (nA + nB + 1) >> 1;
  if (h > nA) h = nA;
  const int bb = bh >> 4, hd = bh & 15;
  const size_t fb = (size_t)bh * 131072;
  const size_t base = ((size_t)bb * SEQ) * DM + hd * DHD;

  f32x16 zacc[2];
  float mrun, lrun;
  short8 qf[4];
  short8 kfA[2][4], kfB[2][4];
  short8 vf[2][4];

  // ---- one KV-tile (identical pipeline to round-13) ----
  auto computeT = [&](short8(&kf)[2][4], short8(&kfn)[2][4], int t, int q0,
                      int ntq, int te, const bf16*& kpt, const bf16*& vp0,
                      const bf16*& vp1) {
    const int kv0 = t * 64;
    const bool pref = (t + 1 < te);

    WAITV(8);  // drain K(t) (+Q on first tile); V(t)'s 8 stay in flight

    f32x16 s[2];
#pragma unroll
    for (int i = 0; i < 16; ++i) { s[0][i] = 0.f; s[1][i] = 0.f; }
    __builtin_amdgcn_s_setprio(1);
#pragma unroll
    for (int kc = 0; kc < 4; ++kc) {
      s[0] = __builtin_amdgcn_mfma_f32_32x32x16_bf16(kf[0][kc], qf[kc], s[0], 0, 0, 0);
      s[1] = __builtin_amdgcn_mfma_f32_32x32x16_bf16(kf[1][kc], qf[kc], s[1], 0, 0, 0);
    }
    __builtin_amdgcn_s_setprio(0);

    if (pref) {  // issue K(t+1)
      const bf16* k1 = kpt + 2048;
      GL16(kfn[0][0], kpt, 0); GL16(kfn[0][1], kpt, 1024); GL16(kfn[0][2], kpt, 2048); GL16(kfn[0][3], kpt, 3072);
      GL16(kfn[1][0], k1, 0);  GL16(kfn[1][1], k1, 1024);  GL16(kfn[1][2], k1, 2048);  GL16(kfn[1][3], k1, 3072);
      kpt += 4096;
    }

    if (t == ntq - 1) {  // causal mask, diagonal tile only
      const int qg = q0 + qln;
#pragma unroll
      for (int ni = 0; ni < 2; ++ni)
#pragma unroll
        for (int rr = 0; rr < 16; ++rr) {
          int kv = kv0 + 32 * ni + (rr & 3) + 8 * (rr >> 2) + (hib ? 4 : 0);
          if (kv > qg) s[ni][rr] = -1e30f;
        }
    }

    float t8[8];
#pragma unroll
    for (int i = 0; i < 8; ++i)
      t8[i] = fmaxf(fmaxf(s[0][i], s[0][i + 8]), fmaxf(s[1][i], s[1][i + 8]));
    float tm = fmaxf(fmaxf(fmaxf(t8[0], t8[1]), fmaxf(t8[2], t8[3])),
                     fmaxf(fmaxf(t8[4], t8[5]), fmaxf(t8[6], t8[7])));
    tm = xmax32(tm);

    if (__ballot(tm > mrun + 8.0f)) {  // defer-max (T13)
      float mn = fmaxf(mrun, tm);
      float al = fexp2(mrun - mn);
      mrun = mn;
      lrun *= al;
#pragma unroll
      for (int i = 0; i < 16; ++i) { zacc[0][i] *= al; zacc[1][i] *= al; }
    }

    float pacc[4] = {0.f, 0.f, 0.f, 0.f};
#pragma unroll
    for (int ni = 0; ni < 2; ++ni)
#pragma unroll
      for (int rr = 0; rr < 16; ++rr) {
        float pw = fexp2(s[ni][rr] - mrun);
        s[ni][rr] = pw;
        pacc[rr & 3] += pw;
      }
    lrun += xsum32((pacc[0] + pacc[1]) + (pacc[2] + pacc[3]));

    unsigned su32[2][8];
#pragma unroll
    for (int ni = 0; ni < 2; ++ni)
#pragma unroll
      for (int tt = 0; tt < 8; ++tt)
        su32[ni][tt] = pack2(s[ni][2 * tt], s[ni][2 * tt + 1]);

    short8 pa[4];
#if __has_builtin(__builtin_amdgcn_permlane32_swap)
#pragma unroll
    for (int c = 0; c < 4; ++c) {
      int ni = c >> 1, b4 = 4 * (c & 1);
      uint2v r0 = __builtin_amdgcn_permlane32_swap(su32[ni][b4 + 0], su32[ni][b4 + 2], false, false);
      uint2v r1 = __builtin_amdgcn_permlane32_swap(su32[ni][b4 + 1], su32[ni][b4 + 3], false, false);
      U8 w;
      w.u[0] = r0[0]; w.u[1] = r1[0]; w.u[2] = r0[1]; w.u[3] = r1[1];
      pa[c] = w.s;
    }
#else
    unsigned X[2][8];
#pragma unroll
    for (int ni = 0; ni < 2; ++ni)
#pragma unroll
      for (int tt = 0; tt < 8; ++tt)
        X[ni][tt] = (unsigned)__shfl_xor((int)su32[ni][tt], 32);
#pragma unroll
    for (int c = 0; c < 4; ++c) {
      int ni = c >> 1, b4 = 4 * (c & 1);
      U8 w;
      w.u[0] = hib ? X[ni][b4 + 2] : su32[ni][b4 + 0];
      w.u[1] = hib ? X[ni][b4 + 3] : su32[ni][b4 + 1];
      w.u[2] = hib ? su32[ni][b4 + 2] : X[ni][b4 + 0];
      w.u[3] = hib ? su32[ni][b4 + 3] : X[ni][b4 + 1];
      pa[c] = w.s;
    }
#endif

    if (pref) { WAITV(8); } else { WAITV(0); }  // drain V(t); K(t+1) in flight

    __builtin_amdgcn_s_setprio(1);
#pragma unroll
    for (int c = 0; c < 4; ++c) {
      zacc[0] = __builtin_amdgcn_mfma_f32_32x32x16_bf16(vf[0][c], pa[c], zacc[0], 0, 0, 0);
      zacc[1] = __builtin_amdgcn_mfma_f32_32x32x16_bf16(vf[1][c], pa[c], zacc[1], 0, 0, 0);
    }
    __builtin_amdgcn_s_setprio(0);
    __builtin_amdgcn_sched_barrier(0);

    if (pref) {  // issue V(t+1) into vf (dead after PV issue)
      GL16(vf[0][0], vp0, 0); GL16(vf[0][1], vp0, 1024); GL16(vf[0][2], vp0, 2048); GL16(vf[0][3], vp0, 3072);
      GL16(vf[1][0], vp1, 0); GL16(vf[1][1], vp1, 1024); GL16(vf[1][2], vp1, 2048); GL16(vf[1][3], vp1, 3072);
      vp0 += 2048; vp1 += 2048;
    }
  };

  // ---- run tiles [ts,te) of q-tile qt; state (mrun,lrun,zacc) accumulates --
  auto runSeg = [&](int qt, int ntq, int ts, int te) {
    if (ts >= te) return;
    const int q0 = qt * 32;
    const bf16* qp = FQ + fb + qt * 2048 + lane * 8;
    const bf16* kpt = FK + fb + (size_t)ts * 4096 + lane * 8;
    const bf16* vp0 = FV + fb + (size_t)ts * 2048 + lane * 8;
    const bf16* vp1 = vp0 + 65536;
    GL16(qf[0], qp, 0); GL16(qf[1], qp, 1024); GL16(qf[2], qp, 2048); GL16(qf[3], qp, 3072);
    {
      const bf16* k1 = kpt + 2048;
      GL16(kfA[0][0], kpt, 0); GL16(kfA[0][1], kpt, 1024); GL16(kfA[0][2], kpt, 2048); GL16(kfA[0][3], kpt, 3072);
      GL16(kfA[1][0], k1, 0);  GL16(kfA[1][1], k1, 1024);  GL16(kfA[1][2], k1, 2048);  GL16(kfA[1][3], k1, 3072);
      kpt += 4096;
    }
    GL16(vf[0][0], vp0, 0); GL16(vf[0][1], vp0, 1024); GL16(vf[0][2], vp0, 2048); GL16(vf[0][3], vp0, 3072);
    GL16(vf[1][0], vp1, 0); GL16(vf[1][1], vp1, 1024); GL16(vf[1][2], vp1, 2048); GL16(vf[1][3], vp1, 3072);
    vp0 += 2048; vp1 += 2048;

    int t = ts;
    while (true) {
      computeT(kfA, kfB, t, q0, ntq, te, kpt, vp0, vp1);
      if (++t >= te) break;
      computeT(kfB, kfA, t, q0, ntq, te, kpt, vp0, vp1);
      if (++t >= te) break;
    }
  };

  auto resetState = [&]() {
#pragma unroll
    for (int i = 0; i < 16; ++i) { zacc[0][i] = 0.f; zacc[1][i] = 0.f; }
    mrun = -1e30f; lrun = 0.f;
  };

  // normalize + transpose Z^T -> Z via swizzled LDS, coalesced store
  auto writeOut = [&](int qt, float lm, unsigned* Zbuf) {
    const float rl = 1.0f / lm;
    const int W8[8] = {0, 1, 4, 5, 8, 9, 12, 13};
#pragma unroll
    for (int dj = 0; dj < 2; ++dj)
#pragma unroll
      for (int tt = 0; tt < 8; ++tt) {
        unsigned v = pack2(zacc[dj][2 * tt] * rl, zacc[dj][2 * tt + 1] * rl);
        int x = 16 * dj + (hib ? 2 : 0) + W8[tt];
        Zbuf[qln * 32 + (((x >> 2) ^ (qln & 7)) << 2) + (x & 3)] = v;
      }
    asm volatile("s_waitcnt lgkmcnt(0)" ::: "memory");
    __builtin_amdgcn_sched_barrier(0);
    int q2 = lane >> 1, hf = lane & 1;
#pragma unroll
    for (int u = 0; u < 4; ++u) {
      int sl = (hf * 4 + u) ^ (q2 & 7);
      U8 w;
      w.u = *(const uint4v*)&Zbuf[q2 * 32 + sl * 4];
      *(short8*)(Zb + base + (size_t)(qt * 32 + q2) * DM + hf * 32 + u * 8) = w.s;
    }
  };

  if (wvi == 0) {
    resetState();
    runSeg(wqA, nA, 0, h);
  } else {
    resetState();
    runSeg(wqA, nA, h, nA);    // may be empty -> identity partial
#pragma unroll
    for (int i = 0; i < 16; ++i) {
      Zm[lane][i] = zacc[0][i];
      Zm[lane][16 + i] = zacc[1][i];
    }
    Ml[lane] = mrun;
    Ll[lane] = lrun;
    resetState();
    runSeg(wqB, nB, 0, nB);    // B computed fully by wave1
  }
  __syncthreads();

  if (wvi == 0) {
    // merge wave1's A-partial (exact online-softmax combine)
    float m1 = Ml[lane], l1 = Ll[lane];
    float mn = fmaxf(mrun, m1);
    float a0 = fexp2(mrun - mn);
    float a1 = fexp2(m1 - mn);
    float lm = lrun * a0 + l1 * a1;
#pragma unroll
    for (int i = 0; i < 16; ++i) {
      zacc[0][i] = zacc[0][i] * a0 + Zm[lane][i] * a1;
      zacc[1][i] = zacc[1][i] * a0 + Zm[lane][16 + i] * a1;
    }
    writeOut(wqA, lm, Zl[0]);
  } else {
    writeOut(wqB, lrun, Zl[1]);
  }
}

extern "C" void kernel_launch(void* const* d_in, const int* in_sizes, int n_in,
                              void* d_out, int out_size, void* d_ws, size_t ws_size,
                              hipStream_t stream) {
  (void)in_sizes; (void)n_in; (void)out_size; (void)ws_size;
  const float* x = (const float*)d_in[0];
  const float* pos = (const float*)d_in[1];
  const float* WQ = (const float*)d_in[2];
  const float* bQ = (const float*)d_in[3];
  const float* WK = (const float*)d_in[4];
  const float* bK = (const float*)d_in[5];
  const float* WV = (const float*)d_in[6];
  const float* bV = (const float*)d_in[7];
  const float* WO = (const float*)d_in[8];
  const float* bO = (const float*)d_in[9];
  float* out = (float*)d_out;

  bf16* ws = (bf16*)d_ws;
  size_t off = 0;
  bf16* aib = ws + off; off += (size_t)MROWS * DM;
  bf16* xb  = ws + off; off += (size_t)MROWS * DM;
  bf16* wqt = ws + off; off += (size_t)DM * DM;
  bf16* wkt = ws + off; off += (size_t)DM * DM;
  bf16* wvt = ws + off; off += (size_t)DM * DM;
  bf16* wot = ws + off; off += (size_t)DM * DM;
  bf16* FQ  = ws + off; off += (size_t)MROWS * DM;  // fragment-major [bh][g][kc]
  bf16* FK  = ws + off; off += (size_t)MROWS * DM;
  bf16* FV  = ws + off; off += (size_t)MROWS * DM;  // fragment-major [bh][dj][ks]
  bf16* Zb  = ws + off; off += (size_t)MROWS * DM;

  preprocess<<<5120, 256, 0, stream>>>(x, pos, xb, aib, WQ, WK, WV, WO,
                                       wqt, wkt, wvt, wot);
  qkv_gemm<<<768, 256, 0, stream>>>(aib, xb, wqt, wkt, wvt, bQ, bK, bV, FQ, FK, FV);
  flash_attn<<<1024, 128, 0, stream>>>(FQ, FK, FV, Zb);
  o_gemm64<<<512, 256, 0, stream>>>(Zb, wot, bO, out);
}